// Round 23
// baseline (857.547 us; speedup 1.0000x reference)
//
#include <hip/hip_runtime.h>
#include <math.h>

#define NPTS  32768
#define NB    2
#define NQ    (NB*NPTS)
#define KK    16
#define EPS   1e-6f
#define G     16
#define G3    (G*G*G)
#define HB    2048
#define SLOP  0.05f
#define TEPS  1e-3f
#define CAPC  512
#define INVQK (1.f/(float)((size_t)NQ*KK))
#define INVN  (1.f/(float)NQ)

// stats element offsets
#define S_L1 0
#define S_L2 32
#define S_P1 64
#define S_P2 96
#define S_SC 160

// workspace element offsets (4-byte units)
#define WS_X1     (NQ*16)
#define WS_T2     (NQ*32)
#define WS_T4     (NQ*48)
#define WS_STAT   (NQ*80)
#define WS_COEF   (WS_STAT + 512)
#define WS_GCNT   (WS_STAT + 1024)
#define WS_GSTART (WS_GCNT + 2*G3)
#define WS_CELLID (WS_GSTART + 2*G3)
#define WS_SORTID (WS_CELLID + NQ)
#define WS_CSORT  (WS_SORTID + NQ)      /* float4 x NQ (16B-aligned) */
#define WS_BBOX   (WS_CSORT + 4*NQ)
#define WS_HIST   (WS_BBOX + 16)
#define WS_EDGE   (WS_HIST + 6*HB)
#define WS_STARTS WS_HIST               /* starts aliases hist (dead after k_edges) */
#define WS_FAIL   WS_CELLID             /* fail list aliases cellid (dead after scatter) */
#define WS_PART   WS_CSORT              /* lsestats/att partials alias csort (dead after k_knn_fb) */
#define WS_PARTA  WS_T2                 /* mlp1 partials alias t2 (dead until k_att1) */

#define FB_BAD    (1 << 30)             /* faillist tag: bad -> unseeded full-batch scan */

__device__ __forceinline__ float wred64(float v) {
#pragma unroll
  for (int m = 32; m > 0; m >>= 1) v += __shfl_xor(v, m, 64);
  return v;
}

// order-preserving float <-> uint encoding for atomic min/max
__device__ __forceinline__ unsigned int encf(float f) {
  unsigned int u = __float_as_uint(f);
  return (u & 0x80000000u) ? ~u : (u | 0x80000000u);
}
__device__ __forceinline__ float decf(unsigned int u) {
  return (u & 0x80000000u) ? __uint_as_float(u & 0x7fffffffu) : __uint_as_float(~u);
}

// 4-step binary search over G=16 quantile edges; e[0] <= x guaranteed
__device__ __forceinline__ int bs16(const float* e, float x) {
  int c = (x >= e[8]) ? 8 : 0;
  c += (x >= e[c+4]) ? 4 : 0;
  c += (x >= e[c+2]) ? 2 : 0;
  c += (x >= e[c+1]) ? 1 : 0;
  return c;
}

// ---------------- zero stats + counters + hist + bbox + failcnt ----------------
__global__ void k_zero_all(float* __restrict__ stats, int* __restrict__ gcnt,
                           int* __restrict__ hist, unsigned int* __restrict__ bbox,
                           int* __restrict__ failcnt) {
  int i = blockIdx.x*256 + threadIdx.x;       // grid covers 12288
  if (i < 2*G3) gcnt[i] = 0;
  if (i < 6*HB) hist[i] = 0;
  if (i < 320)  stats[i] = 0.f;
  if (i < 12)   bbox[i] = ((i % 6) < 3) ? 0xFFFFFFFFu : 0u;
  if (i == 0)   failcnt[0] = 0;
}

// ---------------- deterministic partial reduction: stats[soff+c] = sum_blk part[blk][c] ----
__global__ void k_pred(const float* __restrict__ part, int nblk, int nch,
                       float* __restrict__ stats, int soff) {
  __shared__ float red[256];
  int c = blockIdx.x, tid = threadIdx.x;
  float s = 0.f;
  for (int i = tid; i < nblk; i += 256) s += part[(size_t)i*nch + c];
  red[tid] = s;
  __syncthreads();
  for (int off2 = 128; off2 > 0; off2 >>= 1) {
    if (tid < off2) red[tid] += red[tid + off2];
    __syncthreads();
  }
  if (tid == 0) stats[soff + c] = red[0];
}

// ---------------- fused dual partial reduction: SC (128ch from pa) + L1/L2 (64ch from pb) ----
__global__ void k_pred2(const float* __restrict__ pa, const float* __restrict__ pb,
                        float* __restrict__ stats) {
  __shared__ float red[256];
  int cb = blockIdx.x, tid = threadIdx.x;
  const float* part; int nblk, nch, soff, c;
  if (cb < 128) { part = pa; nblk = 256;  nch = 128; soff = S_SC; c = cb; }
  else          { part = pb; nblk = 4096; nch = 64;  soff = S_L1; c = cb - 128; }
  float s = 0.f;
  for (int i = tid; i < nblk; i += 256) s += part[(size_t)i*nch + c];
  red[tid] = s;
  __syncthreads();
  for (int off2 = 128; off2 > 0; off2 >>= 1) {
    if (tid < off2) red[tid] += red[tid + off2];
    __syncthreads();
  }
  if (tid == 0) stats[soff + c] = red[0];
}

// ---------------- per-batch exact bounding box ----------------
__global__ void k_bbox(const float* __restrict__ coords, unsigned int* __restrict__ bbox) {
  __shared__ unsigned int rmn[3][4], rmx[3][4];
  int tid = threadIdx.x;
  int t = blockIdx.x*256 + tid;
  int b = t >> 15, n = t & (NPTS-1);
  const float* cb = coords + (size_t)b*(NPTS*3);
  unsigned int e[3] = { encf(cb[n*3+0]), encf(cb[n*3+1]), encf(cb[n*3+2]) };
  unsigned int mn[3] = { e[0], e[1], e[2] }, mx[3] = { e[0], e[1], e[2] };
#pragma unroll
  for (int s = 32; s > 0; s >>= 1) {
#pragma unroll
    for (int a = 0; a < 3; ++a) {
      unsigned int o1 = (unsigned int)__shfl_xor((int)mn[a], s, 64);
      unsigned int o2 = (unsigned int)__shfl_xor((int)mx[a], s, 64);
      mn[a] = mn[a] < o1 ? mn[a] : o1;
      mx[a] = mx[a] > o2 ? mx[a] : o2;
    }
  }
  int wave = tid >> 6, lane = tid & 63;
  if (lane == 0) {
#pragma unroll
    for (int a = 0; a < 3; ++a) { rmn[a][wave] = mn[a]; rmx[a][wave] = mx[a]; }
  }
  __syncthreads();
  if (tid < 3) {
    unsigned int a0 = min(min(rmn[tid][0], rmn[tid][1]), min(rmn[tid][2], rmn[tid][3]));
    unsigned int A0 = max(max(rmx[tid][0], rmx[tid][1]), max(rmx[tid][2], rmx[tid][3]));
    atomicMin(&bbox[b*6 + tid], a0);
    atomicMax(&bbox[b*6 + 3 + tid], A0);
  }
}

// ---------------- per-axis fine histogram ----------------
__global__ void k_hist(const float* __restrict__ coords, const unsigned int* __restrict__ bbox,
                       int* __restrict__ hist) {
  int t = blockIdx.x*256 + threadIdx.x;
  int b = t >> 15, n = t & (NPTS-1);
  const float* cb = coords + (size_t)b*(NPTS*3);
#pragma unroll
  for (int a = 0; a < 3; ++a) {
    float l = decf(bbox[b*6+a]), h = decf(bbox[b*6+3+a]);
    float ex = (h - l)*(1.f + 4e-7f) + 1e-30f;
    float inv = (float)HB/ex;
    int bin = (int)((cb[n*3+a] - l)*inv);
    bin = min(HB-1, max(0, bin));
    atomicAdd(&hist[(b*3+a)*HB + bin], 1);
  }
}

// ---------------- equal-frequency edges from histogram cdf ----------------
__global__ void k_edges(const int* __restrict__ hist, const unsigned int* __restrict__ bbox,
                        float* __restrict__ edges) {
  __shared__ int part[256];
  int p = blockIdx.x;                 // pair = b*3 + a, 6 blocks
  int b = p/3, a = p - b*3;
  int tid = threadIdx.x;
  const int* h = hist + p*HB;
  int v[8]; int s = 0;
#pragma unroll
  for (int i = 0; i < 8; ++i) { v[i] = h[tid*8 + i]; s += v[i]; }
  part[tid] = s;
  __syncthreads();
  for (int off = 1; off < 256; off <<= 1) {
    int x = part[tid];
    int y = (tid >= off) ? part[tid-off] : 0;
    __syncthreads();
    part[tid] = x + y;
    __syncthreads();
  }
  float l = decf(bbox[b*6+a]), hi = decf(bbox[b*6+3+a]);
  float ex = (hi - l)*(1.f + 4e-7f) + 1e-30f;
  float bw = ex*(1.f/(float)HB);
  int c = part[tid] - s;              // exclusive base
#pragma unroll
  for (int i = 0; i < 8; ++i) {
    int lo_c = c; c += v[i];
#pragma unroll
    for (int g = 1; g < G; ++g) {
      int tq = g*(NPTS/G);
      if (lo_c < tq && c >= tq) edges[p*(G+1) + g] = l + bw*(float)(tid*8 + i + 1);
    }
  }
  if (tid == 0) { edges[p*(G+1)] = l; edges[p*(G+1) + G] = hi + fabsf(hi)*1e-6f + 1e-20f; }
}

// ---------------- bin points into quantile cells ----------------
__global__ void k_bin(const float* __restrict__ coords, const float* __restrict__ edges,
                      int* __restrict__ cellid, int* __restrict__ gcnt) {
  __shared__ float se[3][G+1];
  int tid = threadIdx.x;
  int t = blockIdx.x*256 + tid;
  int b = t >> 15, n = t & (NPTS-1);
  if (tid < 3*(G+1)) se[tid/(G+1)][tid%(G+1)] = edges[b*3*(G+1) + tid];
  __syncthreads();
  const float* cb = coords + (size_t)b*(NPTS*3);
  int c0 = bs16(se[0], cb[n*3+0]);
  int c1 = bs16(se[1], cb[n*3+1]);
  int c2 = bs16(se[2], cb[n*3+2]);
  int cid = b*G3 + (c2*G + c1)*G + c0;
  cellid[t] = cid;
  atomicAdd(&gcnt[cid], 1);
}

// ---------------- deterministic global scan over all 8192 cells ----------------
__global__ void k_alloc(const int* __restrict__ gcnt, int* __restrict__ gstart,
                        int* __restrict__ starts) {
  __shared__ int part[1024];
  int tid = threadIdx.x;
  int v[8]; int s = 0;
#pragma unroll
  for (int i = 0; i < 8; ++i) { v[i] = gcnt[tid*8 + i]; s += v[i]; }
  part[tid] = s;
  __syncthreads();
  for (int off = 1; off < 1024; off <<= 1) {
    int x = part[tid];
    int y = (tid >= off) ? part[tid-off] : 0;
    __syncthreads();
    part[tid] = x + y;
    __syncthreads();
  }
  int base = part[tid] - s;
#pragma unroll
  for (int i = 0; i < 8; ++i) { gstart[tid*8 + i] = base; starts[tid*8 + i] = base; base += v[i]; }
  if (tid == 1023) starts[2*G3] = NQ;
}

// ---------------- scatter: packed float4 + original id, cell-sorted ----------------
__global__ void k_scatter(const float* __restrict__ coords, const int* __restrict__ cellid,
                          int* __restrict__ gstart, float4* __restrict__ csort,
                          int* __restrict__ sortid) {
  int t = blockIdx.x*256 + threadIdx.x;
  int b = t >> 15, n = t & (NPTS-1);
  const float* cb = coords + (size_t)b*(NPTS*3);
  int cid = cellid[t];
  int pos = atomicAdd(&gstart[cid], 1);
  float x = cb[n*3+0], y = cb[n*3+1], z = cb[n*3+2];
  csort[pos] = make_float4(x, y, z, x*x + y*y + z*z);
  sortid[pos] = n;
}

// ---------------- cell-centric KNN: 3x3x3 LDS phase + phase-2 direct-from-L2 ----------------
// LDS ~11 KB (big[512] only): 8 blocks/CU (wave-capped) vs 6 at 25.6 KB.
// Phase 2 scans the 5x5x5 region row-by-row straight from csort (L2-resident, rare path).
__launch_bounds__(256)
__global__ void k_cellknn(const float4* __restrict__ csort, const int* __restrict__ sortid,
                          const int* __restrict__ starts, const float* __restrict__ edges,
                          int* __restrict__ oidx, int* __restrict__ faillist,
                          int* __restrict__ failcnt) {
  __shared__ float4 big[CAPC];        // phase1 candidate staging (8 KB)
  __shared__ float  sbdA[4][64];      // per-wave compact dists (1 KB)
  __shared__ int    sbiA[4][64];      // per-wave compact indices (1 KB)
  __shared__ int    rs[9], rl[9], pre[10];
  __shared__ int    rs2[25], rl2[25];
  __shared__ int    nfl[4];
  __shared__ int    flq[4][16];
  __shared__ float  flT[4][16];
  int tid = threadIdx.x, lane = tid & 63, w = tid >> 6;
  int blk = blockIdx.x;
  int b = blk >> 12;                  // G3 = 4096 cells per batch
  int c = blk & (G3-1);
  int cxi = c & 15, cyi = (c >> 4) & 15, czi = c >> 8;
  const int* st = starts + b*G3;
  float* sbd = &sbdA[w][0];
  int*   sbi = &sbiA[w][0];
  if (tid < 4) nfl[tid] = 0;
  if (tid < 9) {
    int dz = tid/3 - 1, dy = tid%3 - 1;
    int z = czi + dz, y = cyi + dy;
    if (z < 0 || z > G-1 || y < 0 || y > G-1) { rs[tid] = 0; rl[tid] = 0; }
    else {
      int xa = max(cxi-1, 0), xb = min(cxi+1, G-1);
      int c0 = (z*G + y)*G + xa;
      int s0 = st[c0], e0 = st[c0 + (xb - xa) + 1];
      rs[tid] = s0; rl[tid] = e0 - s0;
    }
  }
  __syncthreads();
  if (tid == 0) {
    int acc = 0;
#pragma unroll
    for (int i = 0; i < 9; ++i) { pre[i] = acc; acc += rl[i]; }
    pre[9] = acc;
  }
  __syncthreads();
  int total = pre[9];
  int hs = st[c], he = st[c+1];
  int nq = he - hs;
  if (nq == 0) return;                           // uniform across block
  bool bad = (total > CAPC) || (total < KK);
  if (!bad) {
    for (int i = tid; i < total; i += 256) {
      int row = 0;
#pragma unroll
      for (int rr = 1; rr < 9; ++rr) row += (i >= pre[rr]);
      int gp = rs[row] + (i - pre[row]);
      big[i] = csort[gp];
    }
  }
  __syncthreads();
  int hoff = pre[4] + (hs - rs[4]);              // home cell offset inside big[]
  // 3x3x3 region boundary edges
  float blo[3], bhi[3]; bool blok[3], bhik[3];
  int cc3[3] = {cxi, cyi, czi};
#pragma unroll
  for (int a = 0; a < 3; ++a) {
    const float* e = edges + (b*3 + a)*(G+1);
    blok[a] = cc3[a] > 0;     blo[a] = blok[a] ? e[cc3[a]-1] : 0.f;
    bhik[a] = cc3[a] < G-1;   bhi[a] = bhik[a] ? e[cc3[a]+2] : 0.f;
  }
  for (int q0 = 0; q0 < nq; q0 += 4) {
    int qi = q0 + w;
    if (qi >= nq) continue;                      // uniform per wave
    int t = hs + qi;
    if (bad) {
      if (lane == 0) { int pos = atomicAdd(failcnt, 1); faillist[pos] = t | FB_BAD; }
      continue;
    }
    float4 qv = big[hoff + qi];
    float qx = qv.x, qy = qv.y, qz = qv.z, qsq = qv.w;
    // distances into registers (8 static slots), per-lane min
    float dreg[8];
#pragma unroll
    for (int s = 0; s < 8; ++s) {
      int i = s*64 + lane;
      float d = 1e30f;
      if (i < total) {
        float4 p = big[i];
        d = qsq + p.w - 2.f*(qx*p.x + qy*p.y + qz*p.z);  // == reference formula
      }
      dreg[s] = d;
    }
    float mnl = fminf(fminf(fminf(dreg[0],dreg[1]), fminf(dreg[2],dreg[3])),
                      fminf(fminf(dreg[4],dreg[5]), fminf(dreg[6],dreg[7])));
    // T' = 16th smallest of 64 lane minima (16 distinct candidates => d16_true <= T')
    float v = mnl;
#pragma unroll
    for (int k2 = 2; k2 <= 64; k2 <<= 1) {
#pragma unroll
      for (int j = k2 >> 1; j > 0; j >>= 1) {
        float o = __shfl_xor(v, j, 64);
        bool keepmin = (((lane & j) == 0) == ((lane & k2) == 0));
        v = keepmin ? fminf(v, o) : fmaxf(v, o);
      }
    }
    float Tp = __shfl(v, 15, 64);
    // compact d <= T' into sbd/sbi
    int cnt = 0;
#pragma unroll
    for (int s = 0; s < 8; ++s) {
      bool take = dreg[s] <= Tp;
      unsigned long long bal = __ballot(take);
      int pos = cnt + __popcll(bal & ((1ull << lane) - 1ull));
      if (take && pos < 64) { sbd[pos] = dreg[s]; sbi[pos] = s*64 + lane; }
      cnt += __popcll(bal);
    }
    if (cnt > 64) {                              // ~never (E[cnt]~18): exact BAD fallback
      if (lane == 0) { int pos = atomicAdd(failcnt, 1); faillist[pos] = t | FB_BAD; }
      continue;
    }
    float dv = (lane < cnt) ? sbd[lane] : 1e30f;
    int   iv = (lane < cnt) ? sbi[lane] : 0x7fffffff;
#pragma unroll
    for (int kk = 2; kk <= 64; kk <<= 1) {       // bitonic sort (d, cand idx)
#pragma unroll
      for (int j = kk >> 1; j > 0; j >>= 1) {
        float od = __shfl_xor(dv, j, 64);
        int   oi = __shfl_xor(iv, j, 64);
        bool keepmin = (((lane & j) == 0) == ((lane & kk) == 0));
        bool less = (od < dv) || (od == dv && oi < iv);
        bool take2 = keepmin ? less : !less;
        dv = take2 ? od : dv;
        iv = take2 ? oi : iv;
      }
    }
    float d16v = __shfl(dv, 15, 64);
    int resid = iv;                              // lane r holds r-th NN cand index
    float m = 1e30f;
    if (blok[0]) m = fminf(m, qx - blo[0]);
    if (bhik[0]) m = fminf(m, bhi[0] - qx);
    if (blok[1]) m = fminf(m, qy - blo[1]);
    if (bhik[1]) m = fminf(m, bhi[1] - qy);
    if (blok[2]) m = fminf(m, qz - blo[2]);
    if (bhik[2]) m = fminf(m, bhi[2] - qz);
    bool ok = (m > 0.f) && (m*m > d16v + SLOP);
    if (ok) {
      int qn = sortid[t];
      size_t row = ((size_t)(b*NPTS + qn))*KK;
      if (lane < KK) {
        int rowi = 0;                            // reconstruct csort position
#pragma unroll
        for (int rr = 1; rr < 9; ++rr) rowi += (resid >= pre[rr]);
        int gp = rs[rowi] + (resid - pre[rowi]);
        oidx[row + lane] = sortid[gp];
      }
    } else {
      if (lane == 0) {
        int k2 = nfl[w];
        if (k2 < 16) { flq[w][k2] = t; flT[w][k2] = d16v; nfl[w] = k2 + 1; }
        else { int pos = atomicAdd(failcnt, 1); faillist[pos] = t | FB_BAD; }
      }
    }
  }
  __syncthreads();
  if (bad) return;
  if (nfl[0] + nfl[1] + nfl[2] + nfl[3] == 0) return;

  // ---- phase 2: resolve failed queries scanning 5x5x5 region DIRECTLY from csort (L2) ----
  if (tid < 25) {
    int dz = tid/5 - 2, dy = tid%5 - 2;
    int z = czi + dz, y = cyi + dy;
    if (z < 0 || z > G-1 || y < 0 || y > G-1) { rs2[tid] = 0; rl2[tid] = 0; }
    else {
      int xa = max(cxi-2, 0), xb = min(cxi+2, G-1);
      int c0 = (z*G + y)*G + xa;
      int s0 = st[c0], e0 = st[c0 + (xb - xa) + 1];
      rs2[tid] = s0; rl2[tid] = e0 - s0;
    }
  }
  __syncthreads();
  // 5x5x5 region boundary edges
  float blo2[3], bhi2[3]; bool blok2[3], bhik2[3];
#pragma unroll
  for (int a = 0; a < 3; ++a) {
    const float* e = edges + (b*3 + a)*(G+1);
    blok2[a] = cc3[a] > 1;     blo2[a] = blok2[a] ? e[cc3[a]-2] : 0.f;
    bhik2[a] = cc3[a] < G-2;   bhi2[a] = bhik2[a] ? e[cc3[a]+3] : 0.f;
  }
  for (int k2 = 0; k2 < nfl[w]; ++k2) {          // wave-serial, no barriers
    int t = flq[w][k2];
    float T0 = flT[w][k2] + TEPS;                // T0 >= true d16 (3x3x3 superset bound)
    float4 qv = csort[t];
    float qx = qv.x, qy = qv.y, qz = qv.z, qsq = qv.w;
    // rows ascend in (z,y) -> cell id -> csort pos: compacted gp strictly ascending,
    // so sort key (d, gp) is order-identical to the old (d, region-index).
    int cnt = 0;
    for (int r = 0; r < 25; ++r) {
      int s0 = rs2[r], len = rl2[r];
      for (int base2 = 0; base2 < len; base2 += 64) {
        int i = base2 + lane;
        bool valid = i < len;
        int gp = s0 + i;
        float d = 1e30f;
        if (valid) {
          float4 p = csort[gp];
          d = qsq + p.w - 2.f*(qx*p.x + qy*p.y + qz*p.z);
        }
        bool take = valid && (d <= T0);
        unsigned long long bal = __ballot(take);
        int pos = cnt + __popcll(bal & ((1ull << lane) - 1ull));
        if (take && pos < 64) { sbd[pos] = d; sbi[pos] = gp; }
        cnt += __popcll(bal);
      }
    }
    if (cnt > 64) {                              // ~never
      if (lane == 0) { int pos = atomicAdd(failcnt, 1); faillist[pos] = t | FB_BAD; }
      continue;
    }
    float dv = (lane < cnt) ? sbd[lane] : 1e30f;
    int   iv = (lane < cnt) ? sbi[lane] : 0x7fffffff;
#pragma unroll
    for (int kk = 2; kk <= 64; kk <<= 1) {       // bitonic sort (d, csort pos)
#pragma unroll
      for (int j = kk >> 1; j > 0; j >>= 1) {
        float od = __shfl_xor(dv, j, 64);
        int   oi = __shfl_xor(iv, j, 64);
        bool keepmin = (((lane & j) == 0) == ((lane & kk) == 0));
        bool less = (od < dv) || (od == dv && oi < iv);
        bool take2 = keepmin ? less : !less;
        dv = take2 ? od : dv;
        iv = take2 ? oi : iv;
      }
    }
    float d16b = __shfl(dv, 15, 64);
    float m = 1e30f;
    if (blok2[0]) m = fminf(m, qx - blo2[0]);
    if (bhik2[0]) m = fminf(m, bhi2[0] - qx);
    if (blok2[1]) m = fminf(m, qy - blo2[1]);
    if (bhik2[1]) m = fminf(m, bhi2[1] - qy);
    if (blok2[2]) m = fminf(m, qz - blo2[2]);
    if (bhik2[2]) m = fminf(m, bhi2[2] - qz);
    bool ok = (m > 0.f) && (m*m > d16b + SLOP);
    int qn = sortid[t];
    size_t row = ((size_t)(b*NPTS + qn))*KK;
    if (lane < KK) oidx[row + lane] = ok ? sortid[iv] : iv;  // result, or seed positions
    if (!ok && lane == 0) { int pos = atomicAdd(failcnt, 1); faillist[pos] = t; }
  }
}

// ---------------- residual fallback: ONE WAVE PER QUERY, contiguous superset scan ----
__launch_bounds__(256)
__global__ void k_knn_fb(const float4* __restrict__ csort, const int* __restrict__ sortid,
                         const int* __restrict__ starts, const float* __restrict__ edges,
                         const int* __restrict__ faillist, const int* __restrict__ failcnt,
                         int* __restrict__ oidx) {
  int tid = threadIdx.x, lane = tid & 63, w = tid >> 6;
  int gw = blockIdx.x*4 + w, nw = gridDim.x*4;
  int nf = failcnt[0];
  for (int f = gw; f < nf; f += nw) {
    int fv = faillist[f];                        // uniform per wave
    bool seeded = (fv & FB_BAD) == 0;
    int t = fv & (FB_BAD - 1);
    int b = t >> 15;
    const int* st = starts + b*G3;
    const float* ex = edges + (b*3+0)*(G+1);
    const float* ey = edges + (b*3+1)*(G+1);
    const float* ez = edges + (b*3+2)*(G+1);
    float4 qv = csort[t];
    const float qx = qv.x, qy = qv.y, qz = qv.z, qsq = qv.w;
    int qn = sortid[t];
    size_t row = ((size_t)(b*NPTS + qn))*KK;
    float T;
    int lo_pos, hi_pos;
    if (seeded) {
      // T = max seed distance (= d16 of 5x5x5 superset) >= true d16
      float sd = -1e30f;
      if (lane < KK) {
        int pos = oidx[row + lane];
        float4 p = csort[pos];
        sd = qsq + p.w - 2.f*(qx*p.x + qy*p.y + qz*p.z);
      }
      T = sd;
#pragma unroll
      for (int m = 32; m > 0; m >>= 1) T = fmaxf(T, __shfl_xor(T, m, 64));
      T += TEPS;
      float R = sqrtf(T)*1.0001f + 1e-12f;
      // ballot-parallel per-axis cell ranges covering the ball
      bool tk = (lane < G-1) && (ex[lane+1] < qx - R);
      int xl = __popcll(__ballot(tk));
      tk = (lane >= 1 && lane <= G-1) && (ex[lane] > qx + R);
      int xh = (G-1) - __popcll(__ballot(tk));
      tk = (lane < G-1) && (ey[lane+1] < qy - R);
      int yl = __popcll(__ballot(tk));
      tk = (lane >= 1 && lane <= G-1) && (ey[lane] > qy + R);
      int yh = (G-1) - __popcll(__ballot(tk));
      tk = (lane < G-1) && (ez[lane+1] < qz - R);
      int zl = __popcll(__ballot(tk));
      tk = (lane >= 1 && lane <= G-1) && (ez[lane] > qz + R);
      int zh = (G-1) - __popcll(__ballot(tk));
      // contiguous superset range: [first box cell, last box cell]
      lo_pos = st[(zl*G + yl)*G + xl];
      hi_pos = st[(zh*G + yh)*G + xh + 1];
    } else {
      // ~never: two-pass full-batch scan; T = 16th smallest of 64 lane minima
      float mn = 1e30f;
      for (int i = b*NPTS + lane; i < b*NPTS + NPTS; i += 64) {
        float4 p = csort[i];
        float d = qsq + p.w - 2.f*(qx*p.x + qy*p.y + qz*p.z);
        mn = fminf(mn, d);
      }
      float v = mn;
#pragma unroll
      for (int k2 = 2; k2 <= 64; k2 <<= 1) {
#pragma unroll
        for (int j = k2 >> 1; j > 0; j >>= 1) {
          float o = __shfl_xor(v, j, 64);
          bool keepmin = (((lane & j) == 0) == ((lane & k2) == 0));
          v = keepmin ? fminf(v, o) : fmaxf(v, o);
        }
      }
      T = __shfl(v, 15, 64) + TEPS;              // >= true d16 (16 distinct candidates)
      lo_pos = b*NPTS;
      hi_pos = b*NPTS + NPTS;
    }
    // streaming threshold scan + per-lane top-16 insert (contiguous, pipelined loads)
    float dl[KK]; int il[KK];
#pragma unroll
    for (int i = 0; i < KK; ++i) { dl[i] = 1e30f; il[i] = 0x7fffffff; }
    for (int i = lo_pos + lane; i < hi_pos; i += 64) {
      float4 p = csort[i];
      float d = qsq + p.w - 2.f*(qx*p.x + qy*p.y + qz*p.z);
      if (d <= T && d < dl[KK-1]) {              // rare insert
        float cd = d; int ci = i;
#pragma unroll
        for (int i2 = 0; i2 < KK; ++i2) {
          bool sw = cd < dl[i2];
          float td = dl[i2]; int ti = il[i2];
          dl[i2] = sw ? cd : td; il[i2] = sw ? ci : ti;
          cd = sw ? td : cd;    ci = sw ? ti : ci;
        }
      }
    }
    // exact union top-16: 16 argmin rounds by (d, csort pos); winner pops
    int res = 0;
#pragma unroll
    for (int r = 0; r < KK; ++r) {
      float v = dl[0]; int pi = il[0]; int l = lane;
#pragma unroll
      for (int m = 1; m < 64; m <<= 1) {
        float ov = __shfl_xor(v, m, 64);
        int   op = __shfl_xor(pi, m, 64);
        int   ol = __shfl_xor(l, m, 64);
        bool take = (ov < v) || (ov == v && op < pi);
        v = take ? ov : v; pi = take ? op : pi; l = take ? ol : l;
      }
      if (lane == r) res = pi;
      bool win = (lane == l);
#pragma unroll
      for (int i = 0; i < KK-1; ++i) {
        dl[i] = win ? dl[i+1] : dl[i];
        il[i] = win ? il[i+1] : il[i];
      }
      dl[KK-1] = win ? 1e30f : dl[KK-1];
      il[KK-1] = win ? 0x7fffffff : il[KK-1];
    }
    if (lane < KK) oidx[row + lane] = sortid[res];
  }
}

// ---------------- FUSED: mlp1 (blocks 0..255) + lsestats (blocks 256..4351) ----------------
__global__ void k_stats(const float* __restrict__ features,
                        const float* __restrict__ W1, const float* __restrict__ b1,
                        const float* __restrict__ Wsc, const float* __restrict__ bsc,
                        float* __restrict__ x1, float* __restrict__ ppa,
                        const float* __restrict__ coords, const int* __restrict__ idx,
                        const float* __restrict__ Wl1, const float* __restrict__ bl1,
                        const float* __restrict__ Wl2, const float* __restrict__ bl2,
                        float* __restrict__ ppb) {
  int tid = threadIdx.x;
  if (blockIdx.x < 256) {
    // ---- mlp1 (leaky 0.2) + shortcut BN partial sums ----
    __shared__ float sW1[128], sb1[16], sWsc[512], sbsc[64];
    __shared__ float part[128];
    if (tid < 128) { sW1[tid] = W1[tid]; part[tid] = 0.f; }
    if (tid < 16)  sb1[tid] = b1[tid];
    if (tid < 64)  sbsc[tid] = bsc[tid];
    for (int i = tid; i < 512; i += 256) sWsc[i] = Wsc[i];
    __syncthreads();
    int q = blockIdx.x*256 + tid;
    int b = q >> 15, n = q & (NPTS-1);
    float f[8];
#pragma unroll
    for (int c = 0; c < 8; ++c) f[c] = features[((size_t)b*8 + c)*NPTS + n];
#pragma unroll
    for (int co = 0; co < 16; ++co) {
      float a = sb1[co];
#pragma unroll
      for (int c = 0; c < 8; ++c) a += f[c]*sW1[co*8+c];
      x1[(size_t)q*16 + co] = a > 0.f ? a : 0.2f*a;
    }
    int lane = tid & 63;
#pragma unroll
    for (int co = 0; co < 64; ++co) {
      float a = sbsc[co];
#pragma unroll
      for (int c = 0; c < 8; ++c) a += f[c]*sWsc[co*8+c];
      float s = wred64(a), ss = wred64(a*a);
      if (lane == 0) { atomicAdd(&part[co], s); atomicAdd(&part[64+co], ss); }
    }
    __syncthreads();
    if (tid < 128) ppa[(size_t)blockIdx.x*128 + tid] = part[tid];
  } else {
    // ---- BN partial sums for BOTH LSE geometric encodings ----
    __shared__ float sW1[160], sb1[16], sW2[160], sb2[16];
    __shared__ float red[4][64];
    int blk = blockIdx.x - 256;
    for (int i = tid; i < 160; i += 256) { sW1[i] = Wl1[i]; sW2[i] = Wl2[i]; }
    if (tid < 16) { sb1[tid] = bl1[tid]; sb2[tid] = bl2[tid]; }
    __syncthreads();
    int t = blk*256 + tid;              // (b,n,k) flat
    int q = t >> 4;
    int b = q >> 15, n = q & (NPTS-1);
    const float* cb = coords + (size_t)b*(NPTS*3);
    int j = idx[t];
    float cx = cb[n*3], cy = cb[n*3+1], cz = cb[n*3+2];
    float px = cb[j*3], py = cb[j*3+1], pz = cb[j*3+2];
    float cat[10] = {cx,cy,cz,px,py,pz,cx-px,cy-py,cz-pz,1.f};
    int wave = tid >> 6, lane = tid & 63;
#pragma unroll
    for (int co = 0; co < 16; ++co) {
      float a1 = sb1[co], a2 = sb2[co];
#pragma unroll
      for (int d0 = 0; d0 < 10; ++d0) { a1 += cat[d0]*sW1[co*10+d0]; a2 += cat[d0]*sW2[co*10+d0]; }
      float s1 = wred64(a1), q1 = wred64(a1*a1);
      float s2 = wred64(a2), q2 = wred64(a2*a2);
      if (lane == 0) { red[wave][co]=s1; red[wave][16+co]=q1; red[wave][32+co]=s2; red[wave][48+co]=q2; }
    }
    __syncthreads();
    if (tid < 64) {
      float v = red[0][tid] + red[1][tid] + red[2][tid] + red[3][tid];
      ppb[(size_t)blk*64 + tid] = v;    // layout matches stats[S_L1..S_L2+32)
    }
  }
}

// ---------------- LSE1 + attentive pooling 1 (BN-L1 coefs computed inline) ----------------
__launch_bounds__(256)
__global__ void k_att1(const float* __restrict__ coords, const int* __restrict__ idx,
                       const float* __restrict__ x1ws,
                       const float* __restrict__ Wl1, const float* __restrict__ bl1,
                       const float* __restrict__ Ws1, const float* __restrict__ Wp1,
                       const float* __restrict__ bp1, const float* __restrict__ stats,
                       const float* __restrict__ gl1, const float* __restrict__ bl1b,
                       float* __restrict__ t2, float* __restrict__ ppart) {
  __shared__ float saL[16], scL[16];
  __shared__ float sWl[160], sbl[16];
  __shared__ float sWs[1024];
  __shared__ float sWpT[512], sbp[16];
  __shared__ float lsum[16], lsq[16];
  int tid = threadIdx.x;
  if (tid < 16) {
    float m = stats[S_L1 + tid]*INVQK;
    float v = stats[S_L1 + 16 + tid]*INVQK - m*m;
    float a = gl1[tid]*rsqrtf(v + EPS);
    saL[tid] = a; scL[tid] = bl1b[tid] - m*a;
  }
  __syncthreads();
  for (int i = tid; i < 160; i += 256) { int c = i/10; sWl[i] = Wl1[i]*saL[c]; }
  if (tid < 16) sbl[tid] = bl1[tid]*saL[tid] + scL[tid];
  for (int i = tid; i < 1024; i += 256) sWs[i] = Ws1[i];
  for (int i = tid; i < 512; i += 256) { int co = i >> 4, cp = i & 15; sWpT[i] = Wp1[cp*32 + co]; }
  if (tid < 16) { sbp[tid] = bp1[tid]; lsum[tid] = 0.f; lsq[tid] = 0.f; }
  __syncthreads();
  int gp = blockIdx.x*16 + (tid >> 4);
  int k  = tid & 15;
  int b = gp >> 15, n = gp & (NPTS-1);
  const float* cb = coords + (size_t)b*(NPTS*3);
  int j = idx[(size_t)gp*KK + k];
  float cx = cb[n*3], cy = cb[n*3+1], cz = cb[n*3+2];
  float px = cb[j*3], py = cb[j*3+1], pz = cb[j*3+2];
  float cat[10] = {cx,cy,cz,px,py,pz,cx-px,cy-py,cz-pz,1.f};
  float x[32];
#pragma unroll
  for (int co = 0; co < 16; ++co) {
    float a = sbl[co];
#pragma unroll
    for (int d0 = 0; d0 < 10; ++d0) a += cat[d0]*sWl[co*10+d0];
    x[co] = a > 0.f ? a : 0.f;
  }
  {
    const float4* xp = (const float4*)(x1ws + (size_t)gp*16);
    float4 u0 = xp[0], u1 = xp[1], u2 = xp[2], u3 = xp[3];
    x[16]=u0.x; x[17]=u0.y; x[18]=u0.z; x[19]=u0.w;
    x[20]=u1.x; x[21]=u1.y; x[22]=u1.z; x[23]=u1.w;
    x[24]=u2.x; x[25]=u2.y; x[26]=u2.z; x[27]=u2.w;
    x[28]=u3.x; x[29]=u3.y; x[30]=u3.z; x[31]=u3.w;
  }
  float tacc = sbp[k];
#pragma unroll
  for (int co = 0; co < 32; ++co) {
    float s = 0.f;
#pragma unroll
    for (int ci = 0; ci < 32; ++ci) s += x[ci]*sWs[co*32+ci];
    float m = s;
#pragma unroll
    for (int msk = 8; msk > 0; msk >>= 1) m = fmaxf(m, __shfl_xor(m, msk, 16));
    float e = __expf(s - m);
    float se = e;
#pragma unroll
    for (int msk = 8; msk > 0; msk >>= 1) se += __shfl_xor(se, msk, 16);
    float w = e/se;
    float fv = w*x[co];
#pragma unroll
    for (int msk = 8; msk > 0; msk >>= 1) fv += __shfl_xor(fv, msk, 16);
    tacc += fv*sWpT[co*16+k];
  }
  t2[(size_t)gp*16 + k] = tacc;
  atomicAdd(&lsum[k], tacc);
  atomicAdd(&lsq[k], tacc*tacc);
  __syncthreads();
  if (tid < 16) {
    ppart[(size_t)blockIdx.x*32 + tid]      = lsum[tid];
    ppart[(size_t)blockIdx.x*32 + 16 + tid] = lsq[tid];
  }
}

// ---------------- LSE2 + attentive pooling 2 (BN-L2 + BN-P1 coefs computed inline) ----------------
__launch_bounds__(256)
__global__ void k_att2(const float* __restrict__ coords, const int* __restrict__ idx,
                       const float* __restrict__ t2ws,
                       const float* __restrict__ Wl2, const float* __restrict__ bl2,
                       const float* __restrict__ Ws2, const float* __restrict__ Wp2,
                       const float* __restrict__ bp2, const float* __restrict__ stats,
                       const float* __restrict__ gl2, const float* __restrict__ bl2b,
                       const float* __restrict__ gp1, const float* __restrict__ bp1b,
                       float* __restrict__ t4, float* __restrict__ ppart) {
  __shared__ float saL[16], scL[16];
  __shared__ float sWl[160], sbl[16];
  __shared__ float sWs[1024];
  __shared__ float sWpT[1024], sbp[32];
  __shared__ float sa1[16], sc1[16];
  __shared__ float lsum[32], lsq[32];
  int tid = threadIdx.x;
  if (tid < 16) {
    float m = stats[S_L2 + tid]*INVQK;
    float v = stats[S_L2 + 16 + tid]*INVQK - m*m;
    float a = gl2[tid]*rsqrtf(v + EPS);
    saL[tid] = a; scL[tid] = bl2b[tid] - m*a;
    float m1 = stats[S_P1 + tid]*INVN;
    float v1 = stats[S_P1 + 16 + tid]*INVN - m1*m1;
    float a1 = gp1[tid]*rsqrtf(v1 + EPS);
    sa1[tid] = a1; sc1[tid] = bp1b[tid] - m1*a1;
  }
  __syncthreads();
  for (int i = tid; i < 160; i += 256) { int c = i/10; sWl[i] = Wl2[i]*saL[c]; }
  if (tid < 16) sbl[tid] = bl2[tid]*saL[tid] + scL[tid];
  for (int i = tid; i < 1024; i += 256) {
    sWs[i] = Ws2[i];
    int co = i >> 5, cp = i & 31; sWpT[i] = Wp2[cp*32 + co];
  }
  if (tid < 32) { sbp[tid] = bp2[tid]; lsum[tid]=0.f; lsq[tid]=0.f; }
  __syncthreads();
  int gp = blockIdx.x*16 + (tid >> 4);
  int k  = tid & 15;
  int b = gp >> 15, n = gp & (NPTS-1);
  const float* cb = coords + (size_t)b*(NPTS*3);
  int j = idx[(size_t)gp*KK + k];
  float cx = cb[n*3], cy = cb[n*3+1], cz = cb[n*3+2];
  float px = cb[j*3], py = cb[j*3+1], pz = cb[j*3+2];
  float cat[10] = {cx,cy,cz,px,py,pz,cx-px,cy-py,cz-pz,1.f};
  float x[32];
#pragma unroll
  for (int co = 0; co < 16; ++co) {
    float a = sbl[co];
#pragma unroll
    for (int d0 = 0; d0 < 10; ++d0) a += cat[d0]*sWl[co*10+d0];
    x[co] = a > 0.f ? a : 0.f;
  }
  {
    const float4* xp = (const float4*)(t2ws + (size_t)gp*16);
    float4 u0 = xp[0], u1 = xp[1], u2 = xp[2], u3 = xp[3];
    float xv[16] = {u0.x,u0.y,u0.z,u0.w, u1.x,u1.y,u1.z,u1.w,
                    u2.x,u2.y,u2.z,u2.w, u3.x,u3.y,u3.z,u3.w};
#pragma unroll
    for (int c = 0; c < 16; ++c) {
      float v = xv[c]*sa1[c] + sc1[c];
      x[16+c] = v > 0.f ? v : 0.f;
    }
  }
  float tacc0 = sbp[k], tacc1 = sbp[k+16];
#pragma unroll
  for (int co = 0; co < 32; ++co) {
    float s = 0.f;
#pragma unroll
    for (int ci = 0; ci < 32; ++ci) s += x[ci]*sWs[co*32+ci];
    float m = s;
#pragma unroll
    for (int msk = 8; msk > 0; msk >>= 1) m = fmaxf(m, __shfl_xor(m, msk, 16));
    float e = __expf(s - m);
    float se = e;
#pragma unroll
    for (int msk = 8; msk > 0; msk >>= 1) se += __shfl_xor(se, msk, 16);
    float w = e/se;
    float fv = w*x[co];
#pragma unroll
    for (int msk = 8; msk > 0; msk >>= 1) fv += __shfl_xor(fv, msk, 16);
    tacc0 += fv*sWpT[co*32+k];
    tacc1 += fv*sWpT[co*32+k+16];
  }
  t4[(size_t)gp*32 + k]      = tacc0;
  t4[(size_t)gp*32 + k + 16] = tacc1;
  atomicAdd(&lsum[k], tacc0);      atomicAdd(&lsq[k], tacc0*tacc0);
  atomicAdd(&lsum[k+16], tacc1);   atomicAdd(&lsq[k+16], tacc1*tacc1);
  __syncthreads();
  if (tid < 32) {
    ppart[(size_t)blockIdx.x*64 + tid]      = lsum[tid];
    ppart[(size_t)blockIdx.x*64 + 32 + tid] = lsq[tid];
  }
}

// ---------------- final: mlp2 + BN'd shortcut + leaky 0.01 (BN-SC + BN-P2 inline) ----------------
__global__ void k_final(const float* __restrict__ t4ws, const float* __restrict__ features,
                        const float* __restrict__ W2, const float* __restrict__ b2,
                        const float* __restrict__ Wsc, const float* __restrict__ bsc,
                        const float* __restrict__ stats,
                        const float* __restrict__ gsc, const float* __restrict__ bscb,
                        const float* __restrict__ gp2, const float* __restrict__ bp2b,
                        float* __restrict__ out) {
  __shared__ float saS[64], scS[64];
  __shared__ float sW2[2048], sb2[64], sWscF[512], sbscF[64], sa[32], scc[32];
  int tid = threadIdx.x;
  if (tid < 64) {
    float m = stats[S_SC + tid]*INVN;
    float v = stats[S_SC + 64 + tid]*INVN - m*m;
    float a = gsc[tid]*rsqrtf(v + EPS);
    saS[tid] = a; scS[tid] = bscb[tid] - m*a;
  }
  if (tid < 32) {
    float m = stats[S_P2 + tid]*INVN;
    float v = stats[S_P2 + 32 + tid]*INVN - m*m;
    float a = gp2[tid]*rsqrtf(v + EPS);
    sa[tid] = a; scc[tid] = bp2b[tid] - m*a;
  }
  __syncthreads();
  for (int i = tid; i < 2048; i += 256) sW2[i] = W2[i];
  if (tid < 64) sb2[tid] = b2[tid];
  for (int i = tid; i < 512; i += 256) { int c2 = i >> 3; sWscF[i] = Wsc[i]*saS[c2]; }
  if (tid < 64) sbscF[tid] = bsc[tid]*saS[tid] + scS[tid];
  __syncthreads();
  int q = blockIdx.x*256 + tid;
  int b = q >> 15, n = q & (NPTS-1);
  float x3[32];
  const float4* tp = (const float4*)(t4ws + (size_t)q*32);
#pragma unroll
  for (int i = 0; i < 8; ++i) {
    float4 u = tp[i];
    float v0 = u.x*sa[4*i+0] + scc[4*i+0];
    float v1 = u.y*sa[4*i+1] + scc[4*i+1];
    float v2 = u.z*sa[4*i+2] + scc[4*i+2];
    float v3 = u.w*sa[4*i+3] + scc[4*i+3];
    x3[4*i+0] = v0 > 0.f ? v0 : 0.f;
    x3[4*i+1] = v1 > 0.f ? v1 : 0.f;
    x3[4*i+2] = v2 > 0.f ? v2 : 0.f;
    x3[4*i+3] = v3 > 0.f ? v3 : 0.f;
  }
  float f[8];
#pragma unroll
  for (int c = 0; c < 8; ++c) f[c] = features[((size_t)b*8+c)*NPTS + n];
  for (int c2 = 0; c2 < 64; ++c2) {
    float acc = sb2[c2];
#pragma unroll
    for (int co = 0; co < 32; ++co) acc += x3[co]*sW2[c2*32+co];
    float sv = sbscF[c2];
#pragma unroll
    for (int c = 0; c < 8; ++c) sv += f[c]*sWscF[c2*8+c];
    float o = acc + sv;
    out[((size_t)b*64 + c2)*NPTS + n] = o > 0.f ? o : 0.01f*o;
  }
}

extern "C" void kernel_launch(void* const* d_in, const int* in_sizes, int n_in,
                              void* d_out, int out_size, void* d_ws, size_t ws_size,
                              hipStream_t stream) {
  const float* coords   = (const float*)d_in[0];
  const float* features = (const float*)d_in[1];
  const float* W1  = (const float*)d_in[2];
  const float* b1  = (const float*)d_in[3];
  const float* Wl1 = (const float*)d_in[4];
  const float* bl1 = (const float*)d_in[5];
  const float* gl1 = (const float*)d_in[6];
  const float* bl1b= (const float*)d_in[7];
  const float* Ws1 = (const float*)d_in[8];
  const float* Wp1 = (const float*)d_in[9];
  const float* bp1 = (const float*)d_in[10];
  const float* gp1 = (const float*)d_in[11];
  const float* bp1b= (const float*)d_in[12];
  const float* Wl2 = (const float*)d_in[13];
  const float* bl2 = (const float*)d_in[14];
  const float* gl2 = (const float*)d_in[15];
  const float* bl2b= (const float*)d_in[16];
  const float* Ws2 = (const float*)d_in[17];
  const float* Wp2 = (const float*)d_in[18];
  const float* bp2 = (const float*)d_in[19];
  const float* gp2 = (const float*)d_in[20];
  const float* bp2b= (const float*)d_in[21];
  const float* W2  = (const float*)d_in[22];
  const float* b2  = (const float*)d_in[23];
  const float* Wsc = (const float*)d_in[24];
  const float* bsc = (const float*)d_in[25];
  const float* gsc = (const float*)d_in[26];
  const float* bscb= (const float*)d_in[27];

  float* wsF  = (float*)d_ws;
  int*   wsI  = (int*)d_ws;
  int*   idxp = wsI;
  float* x1p  = wsF + WS_X1;
  float* t2p  = wsF + WS_T2;
  float* t4p  = wsF + WS_T4;
  float* stat = wsF + WS_STAT;
  int*   gcnt = wsI + WS_GCNT;
  int*   gsta = wsI + WS_GSTART;
  int*   gcel = wsI + WS_CELLID;
  int*   sid  = wsI + WS_SORTID;
  float4* csrt = (float4*)(wsF + WS_CSORT);
  unsigned int* bbox = (unsigned int*)(wsI + WS_BBOX);
  int*   fcnt = wsI + WS_BBOX + 12;       // within bbox's 16-slot region
  int*   flist= wsI + WS_FAIL;            // aliases cellid (dead after scatter)
  int*   hist = wsI + WS_HIST;
  int*   strt = wsI + WS_STARTS;          // aliases hist (dead after k_edges)
  float* edge = wsF + WS_EDGE;
  float* prt  = wsF + WS_PART;            // lsestats/att partials alias csort (dead after k_knn_fb)
  float* prtA = wsF + WS_PARTA;           // mlp1 partials alias t2 (dead until k_att1)
  float* outp = (float*)d_out;

  hipLaunchKernelGGL(k_zero_all, dim3(48), dim3(256), 0, stream, stat, gcnt, hist, bbox, fcnt);
  hipLaunchKernelGGL(k_bbox,    dim3(NQ/256), dim3(256), 0, stream, coords, bbox);
  hipLaunchKernelGGL(k_hist,    dim3(NQ/256), dim3(256), 0, stream, coords, bbox, hist);
  hipLaunchKernelGGL(k_edges,   dim3(6), dim3(256), 0, stream, hist, bbox, edge);
  hipLaunchKernelGGL(k_bin,     dim3(NQ/256), dim3(256), 0, stream, coords, edge, gcel, gcnt);
  hipLaunchKernelGGL(k_alloc,   dim3(1), dim3(1024), 0, stream, gcnt, gsta, strt);
  hipLaunchKernelGGL(k_scatter, dim3(NQ/256), dim3(256), 0, stream, coords, gcel, gsta, csrt, sid);
  hipLaunchKernelGGL(k_cellknn, dim3(2*G3), dim3(256), 0, stream,
                     csrt, sid, strt, edge, idxp, flist, fcnt);
  hipLaunchKernelGGL(k_knn_fb,  dim3(2048), dim3(256), 0, stream,
                     csrt, sid, strt, edge, flist, fcnt, idxp);
  hipLaunchKernelGGL(k_stats, dim3(256 + (NQ*KK)/256), dim3(256), 0, stream,
                     features, W1, b1, Wsc, bsc, x1p, prtA,
                     coords, idxp, Wl1, bl1, Wl2, bl2, prt);
  hipLaunchKernelGGL(k_pred2, dim3(192), dim3(256), 0, stream, prtA, prt, stat);
  hipLaunchKernelGGL(k_att1, dim3(NQ/16), dim3(256), 0, stream,
                     coords, idxp, x1p, Wl1, bl1, Ws1, Wp1, bp1, stat, gl1, bl1b, t2p, prt);
  hipLaunchKernelGGL(k_pred, dim3(32), dim3(256), 0, stream, prt, NQ/16, 32, stat, S_P1);
  hipLaunchKernelGGL(k_att2, dim3(NQ/16), dim3(256), 0, stream,
                     coords, idxp, t2p, Wl2, bl2, Ws2, Wp2, bp2, stat,
                     gl2, bl2b, gp1, bp1b, t4p, prt);
  hipLaunchKernelGGL(k_pred, dim3(64), dim3(256), 0, stream, prt, NQ/16, 64, stat, S_P2);
  hipLaunchKernelGGL(k_final, dim3(NQ/256), dim3(256), 0, stream,
                     t4p, features, W2, b2, Wsc, bsc, stat, gsc, bscb, gp2, bp2b, outp);
}

// Round 24
// 762.693 us; speedup vs baseline: 1.1244x; 1.1244x over previous
//
#include <hip/hip_runtime.h>
#include <math.h>

#define NPTS  32768
#define NB    2
#define NQ    (NB*NPTS)
#define KK    16
#define EPS   1e-6f
#define G     16
#define G3    (G*G*G)
#define HB    2048
#define SLOP  0.05f
#define TEPS  1e-3f
#define CAPC  512
#define CAP2  1408
#define INVQK (1.f/(float)((size_t)NQ*KK))
#define INVN  (1.f/(float)NQ)

// stats element offsets
#define S_L1 0
#define S_L2 32
#define S_P1 64
#define S_P2 96
#define S_SC 160

// workspace element offsets (4-byte units)
#define WS_X1     (NQ*16)
#define WS_T2     (NQ*32)
#define WS_T4     (NQ*48)
#define WS_STAT   (NQ*80)
#define WS_COEF   (WS_STAT + 512)
#define WS_GCNT   (WS_STAT + 1024)
#define WS_GSTART (WS_GCNT + 2*G3)
#define WS_CELLID (WS_GSTART + 2*G3)
#define WS_SORTID (WS_CELLID + NQ)
#define WS_CSORT  (WS_SORTID + NQ)      /* float4 x NQ (16B-aligned) */
#define WS_BBOX   (WS_CSORT + 4*NQ)
#define WS_HIST   (WS_BBOX + 16)
#define WS_EDGE   (WS_HIST + 6*HB)
#define WS_STARTS WS_HIST               /* starts aliases hist (dead after k_edges) */
#define WS_FAIL   WS_CELLID             /* fail list aliases cellid (dead after scatter) */
#define WS_PART   WS_CSORT              /* lsestats/att partials alias csort (dead after k_knn_fb) */
#define WS_PARTA  WS_T2                 /* mlp1 partials alias t2 (dead until k_att1) */

#define FB_BAD    (1 << 30)             /* faillist tag: bad -> unseeded full-batch scan */

__device__ __forceinline__ float wred64(float v) {
#pragma unroll
  for (int m = 32; m > 0; m >>= 1) v += __shfl_xor(v, m, 64);
  return v;
}

// order-preserving float <-> uint encoding for atomic min/max
__device__ __forceinline__ unsigned int encf(float f) {
  unsigned int u = __float_as_uint(f);
  return (u & 0x80000000u) ? ~u : (u | 0x80000000u);
}
__device__ __forceinline__ float decf(unsigned int u) {
  return (u & 0x80000000u) ? __uint_as_float(u & 0x7fffffffu) : __uint_as_float(~u);
}

// 4-step binary search over G=16 quantile edges; e[0] <= x guaranteed
__device__ __forceinline__ int bs16(const float* e, float x) {
  int c = (x >= e[8]) ? 8 : 0;
  c += (x >= e[c+4]) ? 4 : 0;
  c += (x >= e[c+2]) ? 2 : 0;
  c += (x >= e[c+1]) ? 1 : 0;
  return c;
}

// ---------------- zero stats + counters + hist + bbox + failcnt ----------------
__global__ void k_zero_all(float* __restrict__ stats, int* __restrict__ gcnt,
                           int* __restrict__ hist, unsigned int* __restrict__ bbox,
                           int* __restrict__ failcnt) {
  int i = blockIdx.x*256 + threadIdx.x;       // grid covers 12288
  if (i < 2*G3) gcnt[i] = 0;
  if (i < 6*HB) hist[i] = 0;
  if (i < 320)  stats[i] = 0.f;
  if (i < 12)   bbox[i] = ((i % 6) < 3) ? 0xFFFFFFFFu : 0u;
  if (i == 0)   failcnt[0] = 0;
}

// ---------------- deterministic partial reduction: stats[soff+c] = sum_blk part[blk][c] ----
__global__ void k_pred(const float* __restrict__ part, int nblk, int nch,
                       float* __restrict__ stats, int soff) {
  __shared__ float red[256];
  int c = blockIdx.x, tid = threadIdx.x;
  float s = 0.f;
  for (int i = tid; i < nblk; i += 256) s += part[(size_t)i*nch + c];
  red[tid] = s;
  __syncthreads();
  for (int off2 = 128; off2 > 0; off2 >>= 1) {
    if (tid < off2) red[tid] += red[tid + off2];
    __syncthreads();
  }
  if (tid == 0) stats[soff + c] = red[0];
}

// ---------------- fused dual partial reduction: SC (128ch from pa) + L1/L2 (64ch from pb) ----
__global__ void k_pred2(const float* __restrict__ pa, const float* __restrict__ pb,
                        float* __restrict__ stats) {
  __shared__ float red[256];
  int cb = blockIdx.x, tid = threadIdx.x;
  const float* part; int nblk, nch, soff, c;
  if (cb < 128) { part = pa; nblk = 256;  nch = 128; soff = S_SC; c = cb; }
  else          { part = pb; nblk = 4096; nch = 64;  soff = S_L1; c = cb - 128; }
  float s = 0.f;
  for (int i = tid; i < nblk; i += 256) s += part[(size_t)i*nch + c];
  red[tid] = s;
  __syncthreads();
  for (int off2 = 128; off2 > 0; off2 >>= 1) {
    if (tid < off2) red[tid] += red[tid + off2];
    __syncthreads();
  }
  if (tid == 0) stats[soff + c] = red[0];
}

// ---------------- per-batch exact bounding box ----------------
__global__ void k_bbox(const float* __restrict__ coords, unsigned int* __restrict__ bbox) {
  __shared__ unsigned int rmn[3][4], rmx[3][4];
  int tid = threadIdx.x;
  int t = blockIdx.x*256 + tid;
  int b = t >> 15, n = t & (NPTS-1);
  const float* cb = coords + (size_t)b*(NPTS*3);
  unsigned int e[3] = { encf(cb[n*3+0]), encf(cb[n*3+1]), encf(cb[n*3+2]) };
  unsigned int mn[3] = { e[0], e[1], e[2] }, mx[3] = { e[0], e[1], e[2] };
#pragma unroll
  for (int s = 32; s > 0; s >>= 1) {
#pragma unroll
    for (int a = 0; a < 3; ++a) {
      unsigned int o1 = (unsigned int)__shfl_xor((int)mn[a], s, 64);
      unsigned int o2 = (unsigned int)__shfl_xor((int)mx[a], s, 64);
      mn[a] = mn[a] < o1 ? mn[a] : o1;
      mx[a] = mx[a] > o2 ? mx[a] : o2;
    }
  }
  int wave = tid >> 6, lane = tid & 63;
  if (lane == 0) {
#pragma unroll
    for (int a = 0; a < 3; ++a) { rmn[a][wave] = mn[a]; rmx[a][wave] = mx[a]; }
  }
  __syncthreads();
  if (tid < 3) {
    unsigned int a0 = min(min(rmn[tid][0], rmn[tid][1]), min(rmn[tid][2], rmn[tid][3]));
    unsigned int A0 = max(max(rmx[tid][0], rmx[tid][1]), max(rmx[tid][2], rmx[tid][3]));
    atomicMin(&bbox[b*6 + tid], a0);
    atomicMax(&bbox[b*6 + 3 + tid], A0);
  }
}

// ---------------- per-axis fine histogram ----------------
__global__ void k_hist(const float* __restrict__ coords, const unsigned int* __restrict__ bbox,
                       int* __restrict__ hist) {
  int t = blockIdx.x*256 + threadIdx.x;
  int b = t >> 15, n = t & (NPTS-1);
  const float* cb = coords + (size_t)b*(NPTS*3);
#pragma unroll
  for (int a = 0; a < 3; ++a) {
    float l = decf(bbox[b*6+a]), h = decf(bbox[b*6+3+a]);
    float ex = (h - l)*(1.f + 4e-7f) + 1e-30f;
    float inv = (float)HB/ex;
    int bin = (int)((cb[n*3+a] - l)*inv);
    bin = min(HB-1, max(0, bin));
    atomicAdd(&hist[(b*3+a)*HB + bin], 1);
  }
}

// ---------------- equal-frequency edges from histogram cdf ----------------
__global__ void k_edges(const int* __restrict__ hist, const unsigned int* __restrict__ bbox,
                        float* __restrict__ edges) {
  __shared__ int part[256];
  int p = blockIdx.x;                 // pair = b*3 + a, 6 blocks
  int b = p/3, a = p - b*3;
  int tid = threadIdx.x;
  const int* h = hist + p*HB;
  int v[8]; int s = 0;
#pragma unroll
  for (int i = 0; i < 8; ++i) { v[i] = h[tid*8 + i]; s += v[i]; }
  part[tid] = s;
  __syncthreads();
  for (int off = 1; off < 256; off <<= 1) {
    int x = part[tid];
    int y = (tid >= off) ? part[tid-off] : 0;
    __syncthreads();
    part[tid] = x + y;
    __syncthreads();
  }
  float l = decf(bbox[b*6+a]), hi = decf(bbox[b*6+3+a]);
  float ex = (hi - l)*(1.f + 4e-7f) + 1e-30f;
  float bw = ex*(1.f/(float)HB);
  int c = part[tid] - s;              // exclusive base
#pragma unroll
  for (int i = 0; i < 8; ++i) {
    int lo_c = c; c += v[i];
#pragma unroll
    for (int g = 1; g < G; ++g) {
      int tq = g*(NPTS/G);
      if (lo_c < tq && c >= tq) edges[p*(G+1) + g] = l + bw*(float)(tid*8 + i + 1);
    }
  }
  if (tid == 0) { edges[p*(G+1)] = l; edges[p*(G+1) + G] = hi + fabsf(hi)*1e-6f + 1e-20f; }
}

// ---------------- bin points into quantile cells ----------------
__global__ void k_bin(const float* __restrict__ coords, const float* __restrict__ edges,
                      int* __restrict__ cellid, int* __restrict__ gcnt) {
  __shared__ float se[3][G+1];
  int tid = threadIdx.x;
  int t = blockIdx.x*256 + tid;
  int b = t >> 15, n = t & (NPTS-1);
  if (tid < 3*(G+1)) se[tid/(G+1)][tid%(G+1)] = edges[b*3*(G+1) + tid];
  __syncthreads();
  const float* cb = coords + (size_t)b*(NPTS*3);
  int c0 = bs16(se[0], cb[n*3+0]);
  int c1 = bs16(se[1], cb[n*3+1]);
  int c2 = bs16(se[2], cb[n*3+2]);
  int cid = b*G3 + (c2*G + c1)*G + c0;
  cellid[t] = cid;
  atomicAdd(&gcnt[cid], 1);
}

// ---------------- deterministic global scan over all 8192 cells ----------------
__global__ void k_alloc(const int* __restrict__ gcnt, int* __restrict__ gstart,
                        int* __restrict__ starts) {
  __shared__ int part[1024];
  int tid = threadIdx.x;
  int v[8]; int s = 0;
#pragma unroll
  for (int i = 0; i < 8; ++i) { v[i] = gcnt[tid*8 + i]; s += v[i]; }
  part[tid] = s;
  __syncthreads();
  for (int off = 1; off < 1024; off <<= 1) {
    int x = part[tid];
    int y = (tid >= off) ? part[tid-off] : 0;
    __syncthreads();
    part[tid] = x + y;
    __syncthreads();
  }
  int base = part[tid] - s;
#pragma unroll
  for (int i = 0; i < 8; ++i) { gstart[tid*8 + i] = base; starts[tid*8 + i] = base; base += v[i]; }
  if (tid == 1023) starts[2*G3] = NQ;
}

// ---------------- scatter: packed float4 + original id, cell-sorted ----------------
__global__ void k_scatter(const float* __restrict__ coords, const int* __restrict__ cellid,
                          int* __restrict__ gstart, float4* __restrict__ csort,
                          int* __restrict__ sortid) {
  int t = blockIdx.x*256 + threadIdx.x;
  int b = t >> 15, n = t & (NPTS-1);
  const float* cb = coords + (size_t)b*(NPTS*3);
  int cid = cellid[t];
  int pos = atomicAdd(&gstart[cid], 1);
  float x = cb[n*3+0], y = cb[n*3+1], z = cb[n*3+2];
  csort[pos] = make_float4(x, y, z, x*x + y*y + z*z);
  sortid[pos] = n;
}

// ---------------- cell-centric KNN: 3x3x3 phase + in-block 5x5x5 extension ----------------
// r21-proven config: LDS-slim (no bigid), 64-entry compact buffers, phase-2 staged in LDS.
__launch_bounds__(256)
__global__ void k_cellknn(const float4* __restrict__ csort, const int* __restrict__ sortid,
                          const int* __restrict__ starts, const float* __restrict__ edges,
                          int* __restrict__ oidx, int* __restrict__ faillist,
                          int* __restrict__ failcnt) {
  __shared__ float4 big[CAP2];        // phase1: region 3x3x3; phase2: region 5x5x5 (22.5 KB)
  __shared__ float  sbdA[4][64];      // per-wave compact dists (1 KB)
  __shared__ int    sbiA[4][64];      // per-wave compact cand indices (1 KB)
  __shared__ int    rs[9], rl[9], pre[10];
  __shared__ int    rs2[25], rl2[25], pre2[26];
  __shared__ int    nfl[4];
  __shared__ int    flq[4][16];
  __shared__ float  flT[4][16];
  int tid = threadIdx.x, lane = tid & 63, w = tid >> 6;
  int blk = blockIdx.x;
  int b = blk >> 12;                  // G3 = 4096 cells per batch
  int c = blk & (G3-1);
  int cxi = c & 15, cyi = (c >> 4) & 15, czi = c >> 8;
  const int* st = starts + b*G3;
  float* sbd = &sbdA[w][0];
  int*   sbi = &sbiA[w][0];
  if (tid < 4) nfl[tid] = 0;
  if (tid < 9) {
    int dz = tid/3 - 1, dy = tid%3 - 1;
    int z = czi + dz, y = cyi + dy;
    if (z < 0 || z > G-1 || y < 0 || y > G-1) { rs[tid] = 0; rl[tid] = 0; }
    else {
      int xa = max(cxi-1, 0), xb = min(cxi+1, G-1);
      int c0 = (z*G + y)*G + xa;
      int s0 = st[c0], e0 = st[c0 + (xb - xa) + 1];
      rs[tid] = s0; rl[tid] = e0 - s0;
    }
  }
  __syncthreads();
  if (tid == 0) {
    int acc = 0;
#pragma unroll
    for (int i = 0; i < 9; ++i) { pre[i] = acc; acc += rl[i]; }
    pre[9] = acc;
  }
  __syncthreads();
  int total = pre[9];
  int hs = st[c], he = st[c+1];
  int nq = he - hs;
  if (nq == 0) return;                           // uniform across block
  bool bad = (total > CAPC) || (total < KK);
  if (!bad) {
    for (int i = tid; i < total; i += 256) {
      int row = 0;
#pragma unroll
      for (int rr = 1; rr < 9; ++rr) row += (i >= pre[rr]);
      int gp = rs[row] + (i - pre[row]);
      big[i] = csort[gp];
    }
  }
  __syncthreads();
  int hoff = pre[4] + (hs - rs[4]);              // home cell offset inside big[]
  // 3x3x3 region boundary edges
  float blo[3], bhi[3]; bool blok[3], bhik[3];
  int cc3[3] = {cxi, cyi, czi};
#pragma unroll
  for (int a = 0; a < 3; ++a) {
    const float* e = edges + (b*3 + a)*(G+1);
    blok[a] = cc3[a] > 0;     blo[a] = blok[a] ? e[cc3[a]-1] : 0.f;
    bhik[a] = cc3[a] < G-1;   bhi[a] = bhik[a] ? e[cc3[a]+2] : 0.f;
  }
  for (int q0 = 0; q0 < nq; q0 += 4) {
    int qi = q0 + w;
    if (qi >= nq) continue;                      // uniform per wave
    int t = hs + qi;
    if (bad) {
      if (lane == 0) { int pos = atomicAdd(failcnt, 1); faillist[pos] = t | FB_BAD; }
      continue;
    }
    float4 qv = big[hoff + qi];
    float qx = qv.x, qy = qv.y, qz = qv.z, qsq = qv.w;
    // distances into registers (8 static slots), per-lane min
    float dreg[8];
#pragma unroll
    for (int s = 0; s < 8; ++s) {
      int i = s*64 + lane;
      float d = 1e30f;
      if (i < total) {
        float4 p = big[i];
        d = qsq + p.w - 2.f*(qx*p.x + qy*p.y + qz*p.z);  // == reference formula
      }
      dreg[s] = d;
    }
    float mnl = fminf(fminf(fminf(dreg[0],dreg[1]), fminf(dreg[2],dreg[3])),
                      fminf(fminf(dreg[4],dreg[5]), fminf(dreg[6],dreg[7])));
    // T' = 16th smallest of 64 lane minima (16 distinct candidates => d16_true <= T')
    float v = mnl;
#pragma unroll
    for (int k2 = 2; k2 <= 64; k2 <<= 1) {
#pragma unroll
      for (int j = k2 >> 1; j > 0; j >>= 1) {
        float o = __shfl_xor(v, j, 64);
        bool keepmin = (((lane & j) == 0) == ((lane & k2) == 0));
        v = keepmin ? fminf(v, o) : fmaxf(v, o);
      }
    }
    float Tp = __shfl(v, 15, 64);
    // compact d <= T' into sbd/sbi
    int cnt = 0;
#pragma unroll
    for (int s = 0; s < 8; ++s) {
      bool take = dreg[s] <= Tp;
      unsigned long long bal = __ballot(take);
      int pos = cnt + __popcll(bal & ((1ull << lane) - 1ull));
      if (take && pos < 64) { sbd[pos] = dreg[s]; sbi[pos] = s*64 + lane; }
      cnt += __popcll(bal);
    }
    if (cnt > 64) {                              // ~never (E[cnt]~18): exact BAD fallback
      if (lane == 0) { int pos = atomicAdd(failcnt, 1); faillist[pos] = t | FB_BAD; }
      continue;
    }
    float dv = (lane < cnt) ? sbd[lane] : 1e30f;
    int   iv = (lane < cnt) ? sbi[lane] : 0x7fffffff;
#pragma unroll
    for (int kk = 2; kk <= 64; kk <<= 1) {       // bitonic sort (d, cand idx)
#pragma unroll
      for (int j = kk >> 1; j > 0; j >>= 1) {
        float od = __shfl_xor(dv, j, 64);
        int   oi = __shfl_xor(iv, j, 64);
        bool keepmin = (((lane & j) == 0) == ((lane & kk) == 0));
        bool less = (od < dv) || (od == dv && oi < iv);
        bool take2 = keepmin ? less : !less;
        dv = take2 ? od : dv;
        iv = take2 ? oi : iv;
      }
    }
    float d16v = __shfl(dv, 15, 64);
    int resid = iv;                              // lane r holds r-th NN cand index
    float m = 1e30f;
    if (blok[0]) m = fminf(m, qx - blo[0]);
    if (bhik[0]) m = fminf(m, bhi[0] - qx);
    if (blok[1]) m = fminf(m, qy - blo[1]);
    if (bhik[1]) m = fminf(m, bhi[1] - qy);
    if (blok[2]) m = fminf(m, qz - blo[2]);
    if (bhik[2]) m = fminf(m, bhi[2] - qz);
    bool ok = (m > 0.f) && (m*m > d16v + SLOP);
    if (ok) {
      int qn = sortid[t];
      size_t row = ((size_t)(b*NPTS + qn))*KK;
      if (lane < KK) {
        int rowi = 0;                            // reconstruct csort position
#pragma unroll
        for (int rr = 1; rr < 9; ++rr) rowi += (resid >= pre[rr]);
        int gp = rs[rowi] + (resid - pre[rowi]);
        oidx[row + lane] = sortid[gp];
      }
    } else {
      if (lane == 0) {
        int k2 = nfl[w];
        if (k2 < 16) { flq[w][k2] = t; flT[w][k2] = d16v; nfl[w] = k2 + 1; }
        else { int pos = atomicAdd(failcnt, 1); faillist[pos] = t | FB_BAD; }
      }
    }
  }
  __syncthreads();
  if (bad) return;
  if (nfl[0] + nfl[1] + nfl[2] + nfl[3] == 0) return;

  // ---- phase 2: load 5x5x5 region once, resolve failed queries in LDS ----
  if (tid < 25) {
    int dz = tid/5 - 2, dy = tid%5 - 2;
    int z = czi + dz, y = cyi + dy;
    if (z < 0 || z > G-1 || y < 0 || y > G-1) { rs2[tid] = 0; rl2[tid] = 0; }
    else {
      int xa = max(cxi-2, 0), xb = min(cxi+2, G-1);
      int c0 = (z*G + y)*G + xa;
      int s0 = st[c0], e0 = st[c0 + (xb - xa) + 1];
      rs2[tid] = s0; rl2[tid] = e0 - s0;
    }
  }
  __syncthreads();
  if (tid == 0) {
    int acc = 0;
#pragma unroll
    for (int i = 0; i < 25; ++i) { pre2[i] = acc; acc += rl2[i]; }
    pre2[25] = acc;
  }
  __syncthreads();
  int total2 = pre2[25];
  if (total2 > CAP2) {                           // ~never: dump fails as BAD
    if (lane == 0) {
      for (int k2 = 0; k2 < nfl[w]; ++k2) {
        int pos = atomicAdd(failcnt, 1); faillist[pos] = flq[w][k2] | FB_BAD;
      }
    }
    return;
  }
  for (int i = tid; i < total2; i += 256) {
    int rowi = 0;
#pragma unroll
    for (int rr = 1; rr < 25; ++rr) rowi += (i >= pre2[rr]);
    int gp = rs2[rowi] + (i - pre2[rowi]);
    big[i] = csort[gp];
  }
  __syncthreads();
  // 5x5x5 region boundary edges
  float blo2[3], bhi2[3]; bool blok2[3], bhik2[3];
#pragma unroll
  for (int a = 0; a < 3; ++a) {
    const float* e = edges + (b*3 + a)*(G+1);
    blok2[a] = cc3[a] > 1;     blo2[a] = blok2[a] ? e[cc3[a]-2] : 0.f;
    bhik2[a] = cc3[a] < G-2;   bhi2[a] = bhik2[a] ? e[cc3[a]+3] : 0.f;
  }
  for (int k2 = 0; k2 < nfl[w]; ++k2) {          // wave-serial, no barriers
    int t = flq[w][k2];
    float T0 = flT[w][k2] + TEPS;                // T0 >= true d16 (3x3x3 superset bound)
    float4 qv = csort[t];
    float qx = qv.x, qy = qv.y, qz = qv.z, qsq = qv.w;
    int cnt = 0;
    for (int base2 = 0; base2 < total2; base2 += 64) {
      int i = base2 + lane;
      bool valid = i < total2;
      float d = 1e30f;
      if (valid) {
        float4 p = big[i];
        d = qsq + p.w - 2.f*(qx*p.x + qy*p.y + qz*p.z);
      }
      bool take = valid && (d <= T0);
      unsigned long long bal = __ballot(take);
      int pos = cnt + __popcll(bal & ((1ull << lane) - 1ull));
      if (take && pos < 64) { sbd[pos] = d; sbi[pos] = i; }
      cnt += __popcll(bal);
    }
    if (cnt > 64) {                              // ~never
      if (lane == 0) { int pos = atomicAdd(failcnt, 1); faillist[pos] = t | FB_BAD; }
      continue;
    }
    float dv = (lane < cnt) ? sbd[lane] : 1e30f;
    int   iv = (lane < cnt) ? sbi[lane] : 0x7fffffff;
#pragma unroll
    for (int kk = 2; kk <= 64; kk <<= 1) {       // bitonic sort (d, idx)
#pragma unroll
      for (int j = kk >> 1; j > 0; j >>= 1) {
        float od = __shfl_xor(dv, j, 64);
        int   oi = __shfl_xor(iv, j, 64);
        bool keepmin = (((lane & j) == 0) == ((lane & kk) == 0));
        bool less = (od < dv) || (od == dv && oi < iv);
        bool take2 = keepmin ? less : !less;
        dv = take2 ? od : dv;
        iv = take2 ? oi : iv;
      }
    }
    float d16b = __shfl(dv, 15, 64);
    float m = 1e30f;
    if (blok2[0]) m = fminf(m, qx - blo2[0]);
    if (bhik2[0]) m = fminf(m, bhi2[0] - qx);
    if (blok2[1]) m = fminf(m, qy - blo2[1]);
    if (bhik2[1]) m = fminf(m, bhi2[1] - qy);
    if (blok2[2]) m = fminf(m, qz - blo2[2]);
    if (bhik2[2]) m = fminf(m, bhi2[2] - qz);
    bool ok = (m > 0.f) && (m*m > d16b + SLOP);
    int qn = sortid[t];
    size_t row = ((size_t)(b*NPTS + qn))*KK;
    if (lane < KK) {
      int rowi = 0;                              // reconstruct csort position
#pragma unroll
      for (int rr = 1; rr < 25; ++rr) rowi += (iv >= pre2[rr]);
      int gp = rs2[rowi] + (iv - pre2[rowi]);
      oidx[row + lane] = ok ? sortid[gp] : gp;   // result, or seed positions
    }
    if (!ok && lane == 0) { int pos = atomicAdd(failcnt, 1); faillist[pos] = t; }
  }
}

// ---------------- residual fallback: ONE WAVE PER QUERY, contiguous superset scan ----
__launch_bounds__(256)
__global__ void k_knn_fb(const float4* __restrict__ csort, const int* __restrict__ sortid,
                         const int* __restrict__ starts, const float* __restrict__ edges,
                         const int* __restrict__ faillist, const int* __restrict__ failcnt,
                         int* __restrict__ oidx) {
  int tid = threadIdx.x, lane = tid & 63, w = tid >> 6;
  int gw = blockIdx.x*4 + w, nw = gridDim.x*4;
  int nf = failcnt[0];
  for (int f = gw; f < nf; f += nw) {
    int fv = faillist[f];                        // uniform per wave
    bool seeded = (fv & FB_BAD) == 0;
    int t = fv & (FB_BAD - 1);
    int b = t >> 15;
    const int* st = starts + b*G3;
    const float* ex = edges + (b*3+0)*(G+1);
    const float* ey = edges + (b*3+1)*(G+1);
    const float* ez = edges + (b*3+2)*(G+1);
    float4 qv = csort[t];
    const float qx = qv.x, qy = qv.y, qz = qv.z, qsq = qv.w;
    int qn = sortid[t];
    size_t row = ((size_t)(b*NPTS + qn))*KK;
    float T;
    int lo_pos, hi_pos;
    if (seeded) {
      // T = max seed distance (= d16 of 5x5x5 superset) >= true d16
      float sd = -1e30f;
      if (lane < KK) {
        int pos = oidx[row + lane];
        float4 p = csort[pos];
        sd = qsq + p.w - 2.f*(qx*p.x + qy*p.y + qz*p.z);
      }
      T = sd;
#pragma unroll
      for (int m = 32; m > 0; m >>= 1) T = fmaxf(T, __shfl_xor(T, m, 64));
      T += TEPS;
      float R = sqrtf(T)*1.0001f + 1e-12f;
      // ballot-parallel per-axis cell ranges covering the ball
      bool tk = (lane < G-1) && (ex[lane+1] < qx - R);
      int xl = __popcll(__ballot(tk));
      tk = (lane >= 1 && lane <= G-1) && (ex[lane] > qx + R);
      int xh = (G-1) - __popcll(__ballot(tk));
      tk = (lane < G-1) && (ey[lane+1] < qy - R);
      int yl = __popcll(__ballot(tk));
      tk = (lane >= 1 && lane <= G-1) && (ey[lane] > qy + R);
      int yh = (G-1) - __popcll(__ballot(tk));
      tk = (lane < G-1) && (ez[lane+1] < qz - R);
      int zl = __popcll(__ballot(tk));
      tk = (lane >= 1 && lane <= G-1) && (ez[lane] > qz + R);
      int zh = (G-1) - __popcll(__ballot(tk));
      // contiguous superset range: [first box cell, last box cell]
      lo_pos = st[(zl*G + yl)*G + xl];
      hi_pos = st[(zh*G + yh)*G + xh + 1];
    } else {
      // ~never: two-pass full-batch scan; T = 16th smallest of 64 lane minima
      float mn = 1e30f;
      for (int i = b*NPTS + lane; i < b*NPTS + NPTS; i += 64) {
        float4 p = csort[i];
        float d = qsq + p.w - 2.f*(qx*p.x + qy*p.y + qz*p.z);
        mn = fminf(mn, d);
      }
      float v = mn;
#pragma unroll
      for (int k2 = 2; k2 <= 64; k2 <<= 1) {
#pragma unroll
        for (int j = k2 >> 1; j > 0; j >>= 1) {
          float o = __shfl_xor(v, j, 64);
          bool keepmin = (((lane & j) == 0) == ((lane & k2) == 0));
          v = keepmin ? fminf(v, o) : fmaxf(v, o);
        }
      }
      T = __shfl(v, 15, 64) + TEPS;              // >= true d16 (16 distinct candidates)
      lo_pos = b*NPTS;
      hi_pos = b*NPTS + NPTS;
    }
    // streaming threshold scan + per-lane top-16 insert (contiguous, pipelined loads)
    float dl[KK]; int il[KK];
#pragma unroll
    for (int i = 0; i < KK; ++i) { dl[i] = 1e30f; il[i] = 0x7fffffff; }
    for (int i = lo_pos + lane; i < hi_pos; i += 64) {
      float4 p = csort[i];
      float d = qsq + p.w - 2.f*(qx*p.x + qy*p.y + qz*p.z);
      if (d <= T && d < dl[KK-1]) {              // rare insert
        float cd = d; int ci = i;
#pragma unroll
        for (int i2 = 0; i2 < KK; ++i2) {
          bool sw = cd < dl[i2];
          float td = dl[i2]; int ti = il[i2];
          dl[i2] = sw ? cd : td; il[i2] = sw ? ci : ti;
          cd = sw ? td : cd;    ci = sw ? ti : ci;
        }
      }
    }
    // exact union top-16: 16 argmin rounds by (d, csort pos); winner pops
    int res = 0;
#pragma unroll
    for (int r = 0; r < KK; ++r) {
      float v = dl[0]; int pi = il[0]; int l = lane;
#pragma unroll
      for (int m = 1; m < 64; m <<= 1) {
        float ov = __shfl_xor(v, m, 64);
        int   op = __shfl_xor(pi, m, 64);
        int   ol = __shfl_xor(l, m, 64);
        bool take = (ov < v) || (ov == v && op < pi);
        v = take ? ov : v; pi = take ? op : pi; l = take ? ol : l;
      }
      if (lane == r) res = pi;
      bool win = (lane == l);
#pragma unroll
      for (int i = 0; i < KK-1; ++i) {
        dl[i] = win ? dl[i+1] : dl[i];
        il[i] = win ? il[i+1] : il[i];
      }
      dl[KK-1] = win ? 1e30f : dl[KK-1];
      il[KK-1] = win ? 0x7fffffff : il[KK-1];
    }
    if (lane < KK) oidx[row + lane] = sortid[res];
  }
}

// ---------------- FUSED: mlp1 (blocks 0..255) + lsestats (blocks 256..4351) ----------------
__global__ void k_stats(const float* __restrict__ features,
                        const float* __restrict__ W1, const float* __restrict__ b1,
                        const float* __restrict__ Wsc, const float* __restrict__ bsc,
                        float* __restrict__ x1, float* __restrict__ ppa,
                        const float* __restrict__ coords, const int* __restrict__ idx,
                        const float* __restrict__ Wl1, const float* __restrict__ bl1,
                        const float* __restrict__ Wl2, const float* __restrict__ bl2,
                        float* __restrict__ ppb) {
  int tid = threadIdx.x;
  if (blockIdx.x < 256) {
    // ---- mlp1 (leaky 0.2) + shortcut BN partial sums ----
    __shared__ float sW1[128], sb1[16], sWsc[512], sbsc[64];
    __shared__ float part[128];
    if (tid < 128) { sW1[tid] = W1[tid]; part[tid] = 0.f; }
    if (tid < 16)  sb1[tid] = b1[tid];
    if (tid < 64)  sbsc[tid] = bsc[tid];
    for (int i = tid; i < 512; i += 256) sWsc[i] = Wsc[i];
    __syncthreads();
    int q = blockIdx.x*256 + tid;
    int b = q >> 15, n = q & (NPTS-1);
    float f[8];
#pragma unroll
    for (int c = 0; c < 8; ++c) f[c] = features[((size_t)b*8 + c)*NPTS + n];
#pragma unroll
    for (int co = 0; co < 16; ++co) {
      float a = sb1[co];
#pragma unroll
      for (int c = 0; c < 8; ++c) a += f[c]*sW1[co*8+c];
      x1[(size_t)q*16 + co] = a > 0.f ? a : 0.2f*a;
    }
    int lane = tid & 63;
#pragma unroll
    for (int co = 0; co < 64; ++co) {
      float a = sbsc[co];
#pragma unroll
      for (int c = 0; c < 8; ++c) a += f[c]*sWsc[co*8+c];
      float s = wred64(a), ss = wred64(a*a);
      if (lane == 0) { atomicAdd(&part[co], s); atomicAdd(&part[64+co], ss); }
    }
    __syncthreads();
    if (tid < 128) ppa[(size_t)blockIdx.x*128 + tid] = part[tid];
  } else {
    // ---- BN partial sums for BOTH LSE geometric encodings ----
    __shared__ float sW1[160], sb1[16], sW2[160], sb2[16];
    __shared__ float red[4][64];
    int blk = blockIdx.x - 256;
    for (int i = tid; i < 160; i += 256) { sW1[i] = Wl1[i]; sW2[i] = Wl2[i]; }
    if (tid < 16) { sb1[tid] = bl1[tid]; sb2[tid] = bl2[tid]; }
    __syncthreads();
    int t = blk*256 + tid;              // (b,n,k) flat
    int q = t >> 4;
    int b = q >> 15, n = q & (NPTS-1);
    const float* cb = coords + (size_t)b*(NPTS*3);
    int j = idx[t];
    float cx = cb[n*3], cy = cb[n*3+1], cz = cb[n*3+2];
    float px = cb[j*3], py = cb[j*3+1], pz = cb[j*3+2];
    float cat[10] = {cx,cy,cz,px,py,pz,cx-px,cy-py,cz-pz,1.f};
    int wave = tid >> 6, lane = tid & 63;
#pragma unroll
    for (int co = 0; co < 16; ++co) {
      float a1 = sb1[co], a2 = sb2[co];
#pragma unroll
      for (int d0 = 0; d0 < 10; ++d0) { a1 += cat[d0]*sW1[co*10+d0]; a2 += cat[d0]*sW2[co*10+d0]; }
      float s1 = wred64(a1), q1 = wred64(a1*a1);
      float s2 = wred64(a2), q2 = wred64(a2*a2);
      if (lane == 0) { red[wave][co]=s1; red[wave][16+co]=q1; red[wave][32+co]=s2; red[wave][48+co]=q2; }
    }
    __syncthreads();
    if (tid < 64) {
      float v = red[0][tid] + red[1][tid] + red[2][tid] + red[3][tid];
      ppb[(size_t)blk*64 + tid] = v;    // layout matches stats[S_L1..S_L2+32)
    }
  }
}

// ---------------- LSE1 + attentive pooling 1 (BN-L1 inline; softmax w/o max-sub) ----------------
__launch_bounds__(256)
__global__ void k_att1(const float* __restrict__ coords, const int* __restrict__ idx,
                       const float* __restrict__ x1ws,
                       const float* __restrict__ Wl1, const float* __restrict__ bl1,
                       const float* __restrict__ Ws1, const float* __restrict__ Wp1,
                       const float* __restrict__ bp1, const float* __restrict__ stats,
                       const float* __restrict__ gl1, const float* __restrict__ bl1b,
                       float* __restrict__ t2, float* __restrict__ ppart) {
  __shared__ float saL[16], scL[16];
  __shared__ float sWl[160], sbl[16];
  __shared__ float sWs[1024];
  __shared__ float sWpT[512], sbp[16];
  __shared__ float lsum[16], lsq[16];
  int tid = threadIdx.x;
  if (tid < 16) {
    float m = stats[S_L1 + tid]*INVQK;
    float v = stats[S_L1 + 16 + tid]*INVQK - m*m;
    float a = gl1[tid]*rsqrtf(v + EPS);
    saL[tid] = a; scL[tid] = bl1b[tid] - m*a;
  }
  __syncthreads();
  for (int i = tid; i < 160; i += 256) { int c = i/10; sWl[i] = Wl1[i]*saL[c]; }
  if (tid < 16) sbl[tid] = bl1[tid]*saL[tid] + scL[tid];
  for (int i = tid; i < 1024; i += 256) sWs[i] = Ws1[i];
  for (int i = tid; i < 512; i += 256) { int co = i >> 4, cp = i & 15; sWpT[i] = Wp1[cp*32 + co]; }
  if (tid < 16) { sbp[tid] = bp1[tid]; lsum[tid] = 0.f; lsq[tid] = 0.f; }
  __syncthreads();
  int gp = blockIdx.x*16 + (tid >> 4);
  int k  = tid & 15;
  int b = gp >> 15, n = gp & (NPTS-1);
  const float* cb = coords + (size_t)b*(NPTS*3);
  int j = idx[(size_t)gp*KK + k];
  float cx = cb[n*3], cy = cb[n*3+1], cz = cb[n*3+2];
  float px = cb[j*3], py = cb[j*3+1], pz = cb[j*3+2];
  float cat[10] = {cx,cy,cz,px,py,pz,cx-px,cy-py,cz-pz,1.f};
  float x[32];
#pragma unroll
  for (int co = 0; co < 16; ++co) {
    float a = sbl[co];
#pragma unroll
    for (int d0 = 0; d0 < 10; ++d0) a += cat[d0]*sWl[co*10+d0];
    x[co] = a > 0.f ? a : 0.f;
  }
  {
    const float4* xp = (const float4*)(x1ws + (size_t)gp*16);
    float4 u0 = xp[0], u1 = xp[1], u2 = xp[2], u3 = xp[3];
    x[16]=u0.x; x[17]=u0.y; x[18]=u0.z; x[19]=u0.w;
    x[20]=u1.x; x[21]=u1.y; x[22]=u1.z; x[23]=u1.w;
    x[24]=u2.x; x[25]=u2.y; x[26]=u2.z; x[27]=u2.w;
    x[28]=u3.x; x[29]=u3.y; x[30]=u3.z; x[31]=u3.w;
  }
  float tacc = sbp[k];
#pragma unroll
  for (int co = 0; co < 32; ++co) {
    float s = 0.f;
#pragma unroll
    for (int ci = 0; ci < 32; ++ci) s += x[ci]*sWs[co*32+ci];
    float e = __expf(s);                 // scores bounded: softmax w/o max-sub (identical ratio)
    float se = e;
#pragma unroll
    for (int msk = 8; msk > 0; msk >>= 1) se += __shfl_xor(se, msk, 16);
    float w = e/se;
    float fv = w*x[co];
#pragma unroll
    for (int msk = 8; msk > 0; msk >>= 1) fv += __shfl_xor(fv, msk, 16);
    tacc += fv*sWpT[co*16+k];
  }
  t2[(size_t)gp*16 + k] = tacc;
  atomicAdd(&lsum[k], tacc);
  atomicAdd(&lsq[k], tacc*tacc);
  __syncthreads();
  if (tid < 16) {
    ppart[(size_t)blockIdx.x*32 + tid]      = lsum[tid];
    ppart[(size_t)blockIdx.x*32 + 16 + tid] = lsq[tid];
  }
}

// ---------------- LSE2 + attentive pooling 2 (BN-L2 + BN-P1 inline; softmax w/o max-sub) ----
__launch_bounds__(256)
__global__ void k_att2(const float* __restrict__ coords, const int* __restrict__ idx,
                       const float* __restrict__ t2ws,
                       const float* __restrict__ Wl2, const float* __restrict__ bl2,
                       const float* __restrict__ Ws2, const float* __restrict__ Wp2,
                       const float* __restrict__ bp2, const float* __restrict__ stats,
                       const float* __restrict__ gl2, const float* __restrict__ bl2b,
                       const float* __restrict__ gp1, const float* __restrict__ bp1b,
                       float* __restrict__ t4, float* __restrict__ ppart) {
  __shared__ float saL[16], scL[16];
  __shared__ float sWl[160], sbl[16];
  __shared__ float sWs[1024];
  __shared__ float sWpT[1024], sbp[32];
  __shared__ float sa1[16], sc1[16];
  __shared__ float lsum[32], lsq[32];
  int tid = threadIdx.x;
  if (tid < 16) {
    float m = stats[S_L2 + tid]*INVQK;
    float v = stats[S_L2 + 16 + tid]*INVQK - m*m;
    float a = gl2[tid]*rsqrtf(v + EPS);
    saL[tid] = a; scL[tid] = bl2b[tid] - m*a;
    float m1 = stats[S_P1 + tid]*INVN;
    float v1 = stats[S_P1 + 16 + tid]*INVN - m1*m1;
    float a1 = gp1[tid]*rsqrtf(v1 + EPS);
    sa1[tid] = a1; sc1[tid] = bp1b[tid] - m1*a1;
  }
  __syncthreads();
  for (int i = tid; i < 160; i += 256) { int c = i/10; sWl[i] = Wl2[i]*saL[c]; }
  if (tid < 16) sbl[tid] = bl2[tid]*saL[tid] + scL[tid];
  for (int i = tid; i < 1024; i += 256) {
    sWs[i] = Ws2[i];
    int co = i >> 5, cp = i & 31; sWpT[i] = Wp2[cp*32 + co];
  }
  if (tid < 32) { sbp[tid] = bp2[tid]; lsum[tid]=0.f; lsq[tid]=0.f; }
  __syncthreads();
  int gp = blockIdx.x*16 + (tid >> 4);
  int k  = tid & 15;
  int b = gp >> 15, n = gp & (NPTS-1);
  const float* cb = coords + (size_t)b*(NPTS*3);
  int j = idx[(size_t)gp*KK + k];
  float cx = cb[n*3], cy = cb[n*3+1], cz = cb[n*3+2];
  float px = cb[j*3], py = cb[j*3+1], pz = cb[j*3+2];
  float cat[10] = {cx,cy,cz,px,py,pz,cx-px,cy-py,cz-pz,1.f};
  float x[32];
#pragma unroll
  for (int co = 0; co < 16; ++co) {
    float a = sbl[co];
#pragma unroll
    for (int d0 = 0; d0 < 10; ++d0) a += cat[d0]*sWl[co*10+d0];
    x[co] = a > 0.f ? a : 0.f;
  }
  {
    const float4* xp = (const float4*)(t2ws + (size_t)gp*16);
    float4 u0 = xp[0], u1 = xp[1], u2 = xp[2], u3 = xp[3];
    float xv[16] = {u0.x,u0.y,u0.z,u0.w, u1.x,u1.y,u1.z,u1.w,
                    u2.x,u2.y,u2.z,u2.w, u3.x,u3.y,u3.z,u3.w};
#pragma unroll
    for (int c = 0; c < 16; ++c) {
      float v = xv[c]*sa1[c] + sc1[c];
      x[16+c] = v > 0.f ? v : 0.f;
    }
  }
  float tacc0 = sbp[k], tacc1 = sbp[k+16];
#pragma unroll
  for (int co = 0; co < 32; ++co) {
    float s = 0.f;
#pragma unroll
    for (int ci = 0; ci < 32; ++ci) s += x[ci]*sWs[co*32+ci];
    float e = __expf(s);                 // scores bounded: softmax w/o max-sub (identical ratio)
    float se = e;
#pragma unroll
    for (int msk = 8; msk > 0; msk >>= 1) se += __shfl_xor(se, msk, 16);
    float w = e/se;
    float fv = w*x[co];
#pragma unroll
    for (int msk = 8; msk > 0; msk >>= 1) fv += __shfl_xor(fv, msk, 16);
    tacc0 += fv*sWpT[co*32+k];
    tacc1 += fv*sWpT[co*32+k+16];
  }
  t4[(size_t)gp*32 + k]      = tacc0;
  t4[(size_t)gp*32 + k + 16] = tacc1;
  atomicAdd(&lsum[k], tacc0);      atomicAdd(&lsq[k], tacc0*tacc0);
  atomicAdd(&lsum[k+16], tacc1);   atomicAdd(&lsq[k+16], tacc1*tacc1);
  __syncthreads();
  if (tid < 32) {
    ppart[(size_t)blockIdx.x*64 + tid]      = lsum[tid];
    ppart[(size_t)blockIdx.x*64 + 32 + tid] = lsq[tid];
  }
}

// ---------------- final: mlp2 + BN'd shortcut + leaky 0.01 (BN-SC + BN-P2 inline) ----------------
__global__ void k_final(const float* __restrict__ t4ws, const float* __restrict__ features,
                        const float* __restrict__ W2, const float* __restrict__ b2,
                        const float* __restrict__ Wsc, const float* __restrict__ bsc,
                        const float* __restrict__ stats,
                        const float* __restrict__ gsc, const float* __restrict__ bscb,
                        const float* __restrict__ gp2, const float* __restrict__ bp2b,
                        float* __restrict__ out) {
  __shared__ float saS[64], scS[64];
  __shared__ float sW2[2048], sb2[64], sWscF[512], sbscF[64], sa[32], scc[32];
  int tid = threadIdx.x;
  if (tid < 64) {
    float m = stats[S_SC + tid]*INVN;
    float v = stats[S_SC + 64 + tid]*INVN - m*m;
    float a = gsc[tid]*rsqrtf(v + EPS);
    saS[tid] = a; scS[tid] = bscb[tid] - m*a;
  }
  if (tid < 32) {
    float m = stats[S_P2 + tid]*INVN;
    float v = stats[S_P2 + 32 + tid]*INVN - m*m;
    float a = gp2[tid]*rsqrtf(v + EPS);
    sa[tid] = a; scc[tid] = bp2b[tid] - m*a;
  }
  __syncthreads();
  for (int i = tid; i < 2048; i += 256) sW2[i] = W2[i];
  if (tid < 64) sb2[tid] = b2[tid];
  for (int i = tid; i < 512; i += 256) { int c2 = i >> 3; sWscF[i] = Wsc[i]*saS[c2]; }
  if (tid < 64) sbscF[tid] = bsc[tid]*saS[tid] + scS[tid];
  __syncthreads();
  int q = blockIdx.x*256 + tid;
  int b = q >> 15, n = q & (NPTS-1);
  float x3[32];
  const float4* tp = (const float4*)(t4ws + (size_t)q*32);
#pragma unroll
  for (int i = 0; i < 8; ++i) {
    float4 u = tp[i];
    float v0 = u.x*sa[4*i+0] + scc[4*i+0];
    float v1 = u.y*sa[4*i+1] + scc[4*i+1];
    float v2 = u.z*sa[4*i+2] + scc[4*i+2];
    float v3 = u.w*sa[4*i+3] + scc[4*i+3];
    x3[4*i+0] = v0 > 0.f ? v0 : 0.f;
    x3[4*i+1] = v1 > 0.f ? v1 : 0.f;
    x3[4*i+2] = v2 > 0.f ? v2 : 0.f;
    x3[4*i+3] = v3 > 0.f ? v3 : 0.f;
  }
  float f[8];
#pragma unroll
  for (int c = 0; c < 8; ++c) f[c] = features[((size_t)b*8+c)*NPTS + n];
  for (int c2 = 0; c2 < 64; ++c2) {
    float acc = sb2[c2];
#pragma unroll
    for (int co = 0; co < 32; ++co) acc += x3[co]*sW2[c2*32+co];
    float sv = sbscF[c2];
#pragma unroll
    for (int c = 0; c < 8; ++c) sv += f[c]*sWscF[c2*8+c];
    float o = acc + sv;
    out[((size_t)b*64 + c2)*NPTS + n] = o > 0.f ? o : 0.01f*o;
  }
}

extern "C" void kernel_launch(void* const* d_in, const int* in_sizes, int n_in,
                              void* d_out, int out_size, void* d_ws, size_t ws_size,
                              hipStream_t stream) {
  const float* coords   = (const float*)d_in[0];
  const float* features = (const float*)d_in[1];
  const float* W1  = (const float*)d_in[2];
  const float* b1  = (const float*)d_in[3];
  const float* Wl1 = (const float*)d_in[4];
  const float* bl1 = (const float*)d_in[5];
  const float* gl1 = (const float*)d_in[6];
  const float* bl1b= (const float*)d_in[7];
  const float* Ws1 = (const float*)d_in[8];
  const float* Wp1 = (const float*)d_in[9];
  const float* bp1 = (const float*)d_in[10];
  const float* gp1 = (const float*)d_in[11];
  const float* bp1b= (const float*)d_in[12];
  const float* Wl2 = (const float*)d_in[13];
  const float* bl2 = (const float*)d_in[14];
  const float* gl2 = (const float*)d_in[15];
  const float* bl2b= (const float*)d_in[16];
  const float* Ws2 = (const float*)d_in[17];
  const float* Wp2 = (const float*)d_in[18];
  const float* bp2 = (const float*)d_in[19];
  const float* gp2 = (const float*)d_in[20];
  const float* bp2b= (const float*)d_in[21];
  const float* W2  = (const float*)d_in[22];
  const float* b2  = (const float*)d_in[23];
  const float* Wsc = (const float*)d_in[24];
  const float* bsc = (const float*)d_in[25];
  const float* gsc = (const float*)d_in[26];
  const float* bscb= (const float*)d_in[27];

  float* wsF  = (float*)d_ws;
  int*   wsI  = (int*)d_ws;
  int*   idxp = wsI;
  float* x1p  = wsF + WS_X1;
  float* t2p  = wsF + WS_T2;
  float* t4p  = wsF + WS_T4;
  float* stat = wsF + WS_STAT;
  int*   gcnt = wsI + WS_GCNT;
  int*   gsta = wsI + WS_GSTART;
  int*   gcel = wsI + WS_CELLID;
  int*   sid  = wsI + WS_SORTID;
  float4* csrt = (float4*)(wsF + WS_CSORT);
  unsigned int* bbox = (unsigned int*)(wsI + WS_BBOX);
  int*   fcnt = wsI + WS_BBOX + 12;       // within bbox's 16-slot region
  int*   flist= wsI + WS_FAIL;            // aliases cellid (dead after scatter)
  int*   hist = wsI + WS_HIST;
  int*   strt = wsI + WS_STARTS;          // aliases hist (dead after k_edges)
  float* edge = wsF + WS_EDGE;
  float* prt  = wsF + WS_PART;            // lsestats/att partials alias csort (dead after k_knn_fb)
  float* prtA = wsF + WS_PARTA;           // mlp1 partials alias t2 (dead until k_att1)
  float* outp = (float*)d_out;

  hipLaunchKernelGGL(k_zero_all, dim3(48), dim3(256), 0, stream, stat, gcnt, hist, bbox, fcnt);
  hipLaunchKernelGGL(k_bbox,    dim3(NQ/256), dim3(256), 0, stream, coords, bbox);
  hipLaunchKernelGGL(k_hist,    dim3(NQ/256), dim3(256), 0, stream, coords, bbox, hist);
  hipLaunchKernelGGL(k_edges,   dim3(6), dim3(256), 0, stream, hist, bbox, edge);
  hipLaunchKernelGGL(k_bin,     dim3(NQ/256), dim3(256), 0, stream, coords, edge, gcel, gcnt);
  hipLaunchKernelGGL(k_alloc,   dim3(1), dim3(1024), 0, stream, gcnt, gsta, strt);
  hipLaunchKernelGGL(k_scatter, dim3(NQ/256), dim3(256), 0, stream, coords, gcel, gsta, csrt, sid);
  hipLaunchKernelGGL(k_cellknn, dim3(2*G3), dim3(256), 0, stream,
                     csrt, sid, strt, edge, idxp, flist, fcnt);
  hipLaunchKernelGGL(k_knn_fb,  dim3(2048), dim3(256), 0, stream,
                     csrt, sid, strt, edge, flist, fcnt, idxp);
  hipLaunchKernelGGL(k_stats, dim3(256 + (NQ*KK)/256), dim3(256), 0, stream,
                     features, W1, b1, Wsc, bsc, x1p, prtA,
                     coords, idxp, Wl1, bl1, Wl2, bl2, prt);
  hipLaunchKernelGGL(k_pred2, dim3(192), dim3(256), 0, stream, prtA, prt, stat);
  hipLaunchKernelGGL(k_att1, dim3(NQ/16), dim3(256), 0, stream,
                     coords, idxp, x1p, Wl1, bl1, Ws1, Wp1, bp1, stat, gl1, bl1b, t2p, prt);
  hipLaunchKernelGGL(k_pred, dim3(32), dim3(256), 0, stream, prt, NQ/16, 32, stat, S_P1);
  hipLaunchKernelGGL(k_att2, dim3(NQ/16), dim3(256), 0, stream,
                     coords, idxp, t2p, Wl2, bl2, Ws2, Wp2, bp2, stat,
                     gl2, bl2b, gp1, bp1b, t4p, prt);
  hipLaunchKernelGGL(k_pred, dim3(64), dim3(256), 0, stream, prt, NQ/16, 64, stat, S_P2);
  hipLaunchKernelGGL(k_final, dim3(NQ/256), dim3(256), 0, stream,
                     t4p, features, W2, b2, Wsc, bsc, stat, gsc, bscb, gp2, bp2b, outp);
}

// Round 25
// 709.316 us; speedup vs baseline: 1.2090x; 1.0753x over previous
//
#include <hip/hip_runtime.h>
#include <math.h>

#define NPTS  32768
#define NB    2
#define NQ    (NB*NPTS)
#define KK    16
#define EPS   1e-6f
#define G     16
#define G3    (G*G*G)
#define HB    2048
#define SLOP  0.05f
#define TEPS  1e-3f
#define CAPC  512
#define CAP2  1408
#define INVQK (1.f/(float)((size_t)NQ*KK))
#define INVN  (1.f/(float)NQ)

// stats element offsets
#define S_L1 0
#define S_L2 32
#define S_P1 64
#define S_P2 96
#define S_SC 160

// workspace element offsets (4-byte units)
#define WS_X1     (NQ*16)
#define WS_T2     (NQ*32)
#define WS_T4     (NQ*48)
#define WS_STAT   (NQ*80)
#define WS_COEF   (WS_STAT + 512)
#define WS_GCNT   (WS_STAT + 1024)
#define WS_GSTART (WS_GCNT + 2*G3)
#define WS_CELLID (WS_GSTART + 2*G3)
#define WS_SORTID (WS_CELLID + NQ)
#define WS_CSORT  (WS_SORTID + NQ)      /* float4 x NQ (16B-aligned) */
#define WS_BBOX   (WS_CSORT + 4*NQ)
#define WS_HIST   (WS_BBOX + 16)
#define WS_EDGE   (WS_HIST + 6*HB)
#define WS_STARTS WS_HIST               /* starts aliases hist (dead after k_edges) */
#define WS_FAIL   WS_CELLID             /* fail list aliases cellid (dead after scatter) */
#define WS_PART   WS_CSORT              /* lsestats/att partials alias csort (dead after k_knn_fb) */
#define WS_PARTA  WS_T2                 /* mlp1 partials alias t2 (dead until k_att1) */

#define FB_BAD    (1 << 30)             /* faillist tag: bad -> unseeded full-batch scan */

__device__ __forceinline__ float wred64(float v) {
#pragma unroll
  for (int m = 32; m > 0; m >>= 1) v += __shfl_xor(v, m, 64);
  return v;
}

// order-preserving float <-> uint encoding for atomic min/max
__device__ __forceinline__ unsigned int encf(float f) {
  unsigned int u = __float_as_uint(f);
  return (u & 0x80000000u) ? ~u : (u | 0x80000000u);
}
__device__ __forceinline__ float decf(unsigned int u) {
  return (u & 0x80000000u) ? __uint_as_float(u & 0x7fffffffu) : __uint_as_float(~u);
}

// 4-step binary search over G=16 quantile edges; e[0] <= x guaranteed
__device__ __forceinline__ int bs16(const float* e, float x) {
  int c = (x >= e[8]) ? 8 : 0;
  c += (x >= e[c+4]) ? 4 : 0;
  c += (x >= e[c+2]) ? 2 : 0;
  c += (x >= e[c+1]) ? 1 : 0;
  return c;
}

// ---------------- zero stats + counters + hist + bbox + failcnt ----------------
__global__ void k_zero_all(float* __restrict__ stats, int* __restrict__ gcnt,
                           int* __restrict__ hist, unsigned int* __restrict__ bbox,
                           int* __restrict__ failcnt) {
  int i = blockIdx.x*256 + threadIdx.x;       // grid covers 12288
  if (i < 2*G3) gcnt[i] = 0;
  if (i < 6*HB) hist[i] = 0;
  if (i < 320)  stats[i] = 0.f;
  if (i < 12)   bbox[i] = ((i % 6) < 3) ? 0xFFFFFFFFu : 0u;
  if (i == 0)   failcnt[0] = 0;
}

// ---------------- deterministic partial reduction: stats[soff+c] = sum_blk part[blk][c] ----
__global__ void k_pred(const float* __restrict__ part, int nblk, int nch,
                       float* __restrict__ stats, int soff) {
  __shared__ float red[256];
  int c = blockIdx.x, tid = threadIdx.x;
  float s = 0.f;
  for (int i = tid; i < nblk; i += 256) s += part[(size_t)i*nch + c];
  red[tid] = s;
  __syncthreads();
  for (int off2 = 128; off2 > 0; off2 >>= 1) {
    if (tid < off2) red[tid] += red[tid + off2];
    __syncthreads();
  }
  if (tid == 0) stats[soff + c] = red[0];
}

// ---------------- fused dual partial reduction: SC (128ch from pa) + L1/L2 (64ch from pb) ----
__global__ void k_pred2(const float* __restrict__ pa, const float* __restrict__ pb,
                        float* __restrict__ stats) {
  __shared__ float red[256];
  int cb = blockIdx.x, tid = threadIdx.x;
  const float* part; int nblk, nch, soff, c;
  if (cb < 128) { part = pa; nblk = 64;   nch = 128; soff = S_SC; c = cb; }
  else          { part = pb; nblk = 1024; nch = 64;  soff = S_L1; c = cb - 128; }
  float s = 0.f;
  for (int i = tid; i < nblk; i += 256) s += part[(size_t)i*nch + c];
  red[tid] = s;
  __syncthreads();
  for (int off2 = 128; off2 > 0; off2 >>= 1) {
    if (tid < off2) red[tid] += red[tid + off2];
    __syncthreads();
  }
  if (tid == 0) stats[soff + c] = red[0];
}

// ---------------- per-batch exact bounding box ----------------
__global__ void k_bbox(const float* __restrict__ coords, unsigned int* __restrict__ bbox) {
  __shared__ unsigned int rmn[3][4], rmx[3][4];
  int tid = threadIdx.x;
  int t = blockIdx.x*256 + tid;
  int b = t >> 15, n = t & (NPTS-1);
  const float* cb = coords + (size_t)b*(NPTS*3);
  unsigned int e[3] = { encf(cb[n*3+0]), encf(cb[n*3+1]), encf(cb[n*3+2]) };
  unsigned int mn[3] = { e[0], e[1], e[2] }, mx[3] = { e[0], e[1], e[2] };
#pragma unroll
  for (int s = 32; s > 0; s >>= 1) {
#pragma unroll
    for (int a = 0; a < 3; ++a) {
      unsigned int o1 = (unsigned int)__shfl_xor((int)mn[a], s, 64);
      unsigned int o2 = (unsigned int)__shfl_xor((int)mx[a], s, 64);
      mn[a] = mn[a] < o1 ? mn[a] : o1;
      mx[a] = mx[a] > o2 ? mx[a] : o2;
    }
  }
  int wave = tid >> 6, lane = tid & 63;
  if (lane == 0) {
#pragma unroll
    for (int a = 0; a < 3; ++a) { rmn[a][wave] = mn[a]; rmx[a][wave] = mx[a]; }
  }
  __syncthreads();
  if (tid < 3) {
    unsigned int a0 = min(min(rmn[tid][0], rmn[tid][1]), min(rmn[tid][2], rmn[tid][3]));
    unsigned int A0 = max(max(rmx[tid][0], rmx[tid][1]), max(rmx[tid][2], rmx[tid][3]));
    atomicMin(&bbox[b*6 + tid], a0);
    atomicMax(&bbox[b*6 + 3 + tid], A0);
  }
}

// ---------------- per-axis fine histogram ----------------
__global__ void k_hist(const float* __restrict__ coords, const unsigned int* __restrict__ bbox,
                       int* __restrict__ hist) {
  int t = blockIdx.x*256 + threadIdx.x;
  int b = t >> 15, n = t & (NPTS-1);
  const float* cb = coords + (size_t)b*(NPTS*3);
#pragma unroll
  for (int a = 0; a < 3; ++a) {
    float l = decf(bbox[b*6+a]), h = decf(bbox[b*6+3+a]);
    float ex = (h - l)*(1.f + 4e-7f) + 1e-30f;
    float inv = (float)HB/ex;
    int bin = (int)((cb[n*3+a] - l)*inv);
    bin = min(HB-1, max(0, bin));
    atomicAdd(&hist[(b*3+a)*HB + bin], 1);
  }
}

// ---------------- equal-frequency edges from histogram cdf ----------------
__global__ void k_edges(const int* __restrict__ hist, const unsigned int* __restrict__ bbox,
                        float* __restrict__ edges) {
  __shared__ int part[256];
  int p = blockIdx.x;                 // pair = b*3 + a, 6 blocks
  int b = p/3, a = p - b*3;
  int tid = threadIdx.x;
  const int* h = hist + p*HB;
  int v[8]; int s = 0;
#pragma unroll
  for (int i = 0; i < 8; ++i) { v[i] = h[tid*8 + i]; s += v[i]; }
  part[tid] = s;
  __syncthreads();
  for (int off = 1; off < 256; off <<= 1) {
    int x = part[tid];
    int y = (tid >= off) ? part[tid-off] : 0;
    __syncthreads();
    part[tid] = x + y;
    __syncthreads();
  }
  float l = decf(bbox[b*6+a]), hi = decf(bbox[b*6+3+a]);
  float ex = (hi - l)*(1.f + 4e-7f) + 1e-30f;
  float bw = ex*(1.f/(float)HB);
  int c = part[tid] - s;              // exclusive base
#pragma unroll
  for (int i = 0; i < 8; ++i) {
    int lo_c = c; c += v[i];
#pragma unroll
    for (int g = 1; g < G; ++g) {
      int tq = g*(NPTS/G);
      if (lo_c < tq && c >= tq) edges[p*(G+1) + g] = l + bw*(float)(tid*8 + i + 1);
    }
  }
  if (tid == 0) { edges[p*(G+1)] = l; edges[p*(G+1) + G] = hi + fabsf(hi)*1e-6f + 1e-20f; }
}

// ---------------- bin points into quantile cells ----------------
__global__ void k_bin(const float* __restrict__ coords, const float* __restrict__ edges,
                      int* __restrict__ cellid, int* __restrict__ gcnt) {
  __shared__ float se[3][G+1];
  int tid = threadIdx.x;
  int t = blockIdx.x*256 + tid;
  int b = t >> 15, n = t & (NPTS-1);
  if (tid < 3*(G+1)) se[tid/(G+1)][tid%(G+1)] = edges[b*3*(G+1) + tid];
  __syncthreads();
  const float* cb = coords + (size_t)b*(NPTS*3);
  int c0 = bs16(se[0], cb[n*3+0]);
  int c1 = bs16(se[1], cb[n*3+1]);
  int c2 = bs16(se[2], cb[n*3+2]);
  int cid = b*G3 + (c2*G + c1)*G + c0;
  cellid[t] = cid;
  atomicAdd(&gcnt[cid], 1);
}

// ---------------- deterministic global scan over all 8192 cells ----------------
__global__ void k_alloc(const int* __restrict__ gcnt, int* __restrict__ gstart,
                        int* __restrict__ starts) {
  __shared__ int part[1024];
  int tid = threadIdx.x;
  int v[8]; int s = 0;
#pragma unroll
  for (int i = 0; i < 8; ++i) { v[i] = gcnt[tid*8 + i]; s += v[i]; }
  part[tid] = s;
  __syncthreads();
  for (int off = 1; off < 1024; off <<= 1) {
    int x = part[tid];
    int y = (tid >= off) ? part[tid-off] : 0;
    __syncthreads();
    part[tid] = x + y;
    __syncthreads();
  }
  int base = part[tid] - s;
#pragma unroll
  for (int i = 0; i < 8; ++i) { gstart[tid*8 + i] = base; starts[tid*8 + i] = base; base += v[i]; }
  if (tid == 1023) starts[2*G3] = NQ;
}

// ---------------- scatter: packed float4 + original id, cell-sorted ----------------
__global__ void k_scatter(const float* __restrict__ coords, const int* __restrict__ cellid,
                          int* __restrict__ gstart, float4* __restrict__ csort,
                          int* __restrict__ sortid) {
  int t = blockIdx.x*256 + threadIdx.x;
  int b = t >> 15, n = t & (NPTS-1);
  const float* cb = coords + (size_t)b*(NPTS*3);
  int cid = cellid[t];
  int pos = atomicAdd(&gstart[cid], 1);
  float x = cb[n*3+0], y = cb[n*3+1], z = cb[n*3+2];
  csort[pos] = make_float4(x, y, z, x*x + y*y + z*z);
  sortid[pos] = n;
}

// ---------------- cell-centric KNN: 3x3x3 phase + in-block 5x5x5 extension ----------------
// r21-proven config + guarded 32-wide second bitonic when cnt<=32 (E[cnt]~18 -> ~always).
__launch_bounds__(256)
__global__ void k_cellknn(const float4* __restrict__ csort, const int* __restrict__ sortid,
                          const int* __restrict__ starts, const float* __restrict__ edges,
                          int* __restrict__ oidx, int* __restrict__ faillist,
                          int* __restrict__ failcnt) {
  __shared__ float4 big[CAP2];        // phase1: region 3x3x3; phase2: region 5x5x5 (22.5 KB)
  __shared__ float  sbdA[4][64];      // per-wave compact dists (1 KB)
  __shared__ int    sbiA[4][64];      // per-wave compact cand indices (1 KB)
  __shared__ int    rs[9], rl[9], pre[10];
  __shared__ int    rs2[25], rl2[25], pre2[26];
  __shared__ int    nfl[4];
  __shared__ int    flq[4][16];
  __shared__ float  flT[4][16];
  int tid = threadIdx.x, lane = tid & 63, w = tid >> 6;
  int blk = blockIdx.x;
  int b = blk >> 12;                  // G3 = 4096 cells per batch
  int c = blk & (G3-1);
  int cxi = c & 15, cyi = (c >> 4) & 15, czi = c >> 8;
  const int* st = starts + b*G3;
  float* sbd = &sbdA[w][0];
  int*   sbi = &sbiA[w][0];
  if (tid < 4) nfl[tid] = 0;
  if (tid < 9) {
    int dz = tid/3 - 1, dy = tid%3 - 1;
    int z = czi + dz, y = cyi + dy;
    if (z < 0 || z > G-1 || y < 0 || y > G-1) { rs[tid] = 0; rl[tid] = 0; }
    else {
      int xa = max(cxi-1, 0), xb = min(cxi+1, G-1);
      int c0 = (z*G + y)*G + xa;
      int s0 = st[c0], e0 = st[c0 + (xb - xa) + 1];
      rs[tid] = s0; rl[tid] = e0 - s0;
    }
  }
  __syncthreads();
  if (tid == 0) {
    int acc = 0;
#pragma unroll
    for (int i = 0; i < 9; ++i) { pre[i] = acc; acc += rl[i]; }
    pre[9] = acc;
  }
  __syncthreads();
  int total = pre[9];
  int hs = st[c], he = st[c+1];
  int nq = he - hs;
  if (nq == 0) return;                           // uniform across block
  bool bad = (total > CAPC) || (total < KK);
  if (!bad) {
    for (int i = tid; i < total; i += 256) {
      int row = 0;
#pragma unroll
      for (int rr = 1; rr < 9; ++rr) row += (i >= pre[rr]);
      int gp = rs[row] + (i - pre[row]);
      big[i] = csort[gp];
    }
  }
  __syncthreads();
  int hoff = pre[4] + (hs - rs[4]);              // home cell offset inside big[]
  // 3x3x3 region boundary edges
  float blo[3], bhi[3]; bool blok[3], bhik[3];
  int cc3[3] = {cxi, cyi, czi};
#pragma unroll
  for (int a = 0; a < 3; ++a) {
    const float* e = edges + (b*3 + a)*(G+1);
    blok[a] = cc3[a] > 0;     blo[a] = blok[a] ? e[cc3[a]-1] : 0.f;
    bhik[a] = cc3[a] < G-1;   bhi[a] = bhik[a] ? e[cc3[a]+2] : 0.f;
  }
  for (int q0 = 0; q0 < nq; q0 += 4) {
    int qi = q0 + w;
    if (qi >= nq) continue;                      // uniform per wave
    int t = hs + qi;
    if (bad) {
      if (lane == 0) { int pos = atomicAdd(failcnt, 1); faillist[pos] = t | FB_BAD; }
      continue;
    }
    float4 qv = big[hoff + qi];
    float qx = qv.x, qy = qv.y, qz = qv.z, qsq = qv.w;
    // distances into registers (8 static slots), per-lane min
    float dreg[8];
#pragma unroll
    for (int s = 0; s < 8; ++s) {
      int i = s*64 + lane;
      float d = 1e30f;
      if (i < total) {
        float4 p = big[i];
        d = qsq + p.w - 2.f*(qx*p.x + qy*p.y + qz*p.z);  // == reference formula
      }
      dreg[s] = d;
    }
    float mnl = fminf(fminf(fminf(dreg[0],dreg[1]), fminf(dreg[2],dreg[3])),
                      fminf(fminf(dreg[4],dreg[5]), fminf(dreg[6],dreg[7])));
    // T' = 16th smallest of 64 lane minima (16 distinct candidates => d16_true <= T')
    float v = mnl;
#pragma unroll
    for (int k2 = 2; k2 <= 64; k2 <<= 1) {
#pragma unroll
      for (int j = k2 >> 1; j > 0; j >>= 1) {
        float o = __shfl_xor(v, j, 64);
        bool keepmin = (((lane & j) == 0) == ((lane & k2) == 0));
        v = keepmin ? fminf(v, o) : fmaxf(v, o);
      }
    }
    float Tp = __shfl(v, 15, 64);
    // compact d <= T' into sbd/sbi
    int cnt = 0;
#pragma unroll
    for (int s = 0; s < 8; ++s) {
      bool take = dreg[s] <= Tp;
      unsigned long long bal = __ballot(take);
      int pos = cnt + __popcll(bal & ((1ull << lane) - 1ull));
      if (take && pos < 64) { sbd[pos] = dreg[s]; sbi[pos] = s*64 + lane; }
      cnt += __popcll(bal);
    }
    if (cnt > 64) {                              // ~never (E[cnt]~18): exact BAD fallback
      if (lane == 0) { int pos = atomicAdd(failcnt, 1); faillist[pos] = t | FB_BAD; }
      continue;
    }
    float dv = (lane < cnt) ? sbd[lane] : 1e30f;
    int   iv = (lane < cnt) ? sbi[lane] : 0x7fffffff;
    if (cnt <= 32) {                             // 32-wide network (15 stages, ~always)
#pragma unroll
      for (int kk = 2; kk <= 32; kk <<= 1) {
#pragma unroll
        for (int j = kk >> 1; j > 0; j >>= 1) {
          float od = __shfl_xor(dv, j, 64);
          int   oi = __shfl_xor(iv, j, 64);
          bool keepmin = (((lane & j) == 0) == ((lane & kk) == 0));
          bool less = (od < dv) || (od == dv && oi < iv);
          bool take2 = keepmin ? less : !less;
          dv = take2 ? od : dv;
          iv = take2 ? oi : iv;
        }
      }
    } else {                                     // full 64-wide (21 stages)
#pragma unroll
      for (int kk = 2; kk <= 64; kk <<= 1) {
#pragma unroll
        for (int j = kk >> 1; j > 0; j >>= 1) {
          float od = __shfl_xor(dv, j, 64);
          int   oi = __shfl_xor(iv, j, 64);
          bool keepmin = (((lane & j) == 0) == ((lane & kk) == 0));
          bool less = (od < dv) || (od == dv && oi < iv);
          bool take2 = keepmin ? less : !less;
          dv = take2 ? od : dv;
          iv = take2 ? oi : iv;
        }
      }
    }
    float d16v = __shfl(dv, 15, 64);
    int resid = iv;                              // lane r holds r-th NN cand index
    float m = 1e30f;
    if (blok[0]) m = fminf(m, qx - blo[0]);
    if (bhik[0]) m = fminf(m, bhi[0] - qx);
    if (blok[1]) m = fminf(m, qy - blo[1]);
    if (bhik[1]) m = fminf(m, bhi[1] - qy);
    if (blok[2]) m = fminf(m, qz - blo[2]);
    if (bhik[2]) m = fminf(m, bhi[2] - qz);
    bool ok = (m > 0.f) && (m*m > d16v + SLOP);
    if (ok) {
      int qn = sortid[t];
      size_t row = ((size_t)(b*NPTS + qn))*KK;
      if (lane < KK) {
        int rowi = 0;                            // reconstruct csort position
#pragma unroll
        for (int rr = 1; rr < 9; ++rr) rowi += (resid >= pre[rr]);
        int gp = rs[rowi] + (resid - pre[rowi]);
        oidx[row + lane] = sortid[gp];
      }
    } else {
      if (lane == 0) {
        int k2 = nfl[w];
        if (k2 < 16) { flq[w][k2] = t; flT[w][k2] = d16v; nfl[w] = k2 + 1; }
        else { int pos = atomicAdd(failcnt, 1); faillist[pos] = t | FB_BAD; }
      }
    }
  }
  __syncthreads();
  if (bad) return;
  if (nfl[0] + nfl[1] + nfl[2] + nfl[3] == 0) return;

  // ---- phase 2: load 5x5x5 region once, resolve failed queries in LDS ----
  if (tid < 25) {
    int dz = tid/5 - 2, dy = tid%5 - 2;
    int z = czi + dz, y = cyi + dy;
    if (z < 0 || z > G-1 || y < 0 || y > G-1) { rs2[tid] = 0; rl2[tid] = 0; }
    else {
      int xa = max(cxi-2, 0), xb = min(cxi+2, G-1);
      int c0 = (z*G + y)*G + xa;
      int s0 = st[c0], e0 = st[c0 + (xb - xa) + 1];
      rs2[tid] = s0; rl2[tid] = e0 - s0;
    }
  }
  __syncthreads();
  if (tid == 0) {
    int acc = 0;
#pragma unroll
    for (int i = 0; i < 25; ++i) { pre2[i] = acc; acc += rl2[i]; }
    pre2[25] = acc;
  }
  __syncthreads();
  int total2 = pre2[25];
  if (total2 > CAP2) {                           // ~never: dump fails as BAD
    if (lane == 0) {
      for (int k2 = 0; k2 < nfl[w]; ++k2) {
        int pos = atomicAdd(failcnt, 1); faillist[pos] = flq[w][k2] | FB_BAD;
      }
    }
    return;
  }
  for (int i = tid; i < total2; i += 256) {
    int rowi = 0;
#pragma unroll
    for (int rr = 1; rr < 25; ++rr) rowi += (i >= pre2[rr]);
    int gp = rs2[rowi] + (i - pre2[rowi]);
    big[i] = csort[gp];
  }
  __syncthreads();
  // 5x5x5 region boundary edges
  float blo2[3], bhi2[3]; bool blok2[3], bhik2[3];
#pragma unroll
  for (int a = 0; a < 3; ++a) {
    const float* e = edges + (b*3 + a)*(G+1);
    blok2[a] = cc3[a] > 1;     blo2[a] = blok2[a] ? e[cc3[a]-2] : 0.f;
    bhik2[a] = cc3[a] < G-2;   bhi2[a] = bhik2[a] ? e[cc3[a]+3] : 0.f;
  }
  for (int k2 = 0; k2 < nfl[w]; ++k2) {          // wave-serial, no barriers
    int t = flq[w][k2];
    float T0 = flT[w][k2] + TEPS;                // T0 >= true d16 (3x3x3 superset bound)
    float4 qv = csort[t];
    float qx = qv.x, qy = qv.y, qz = qv.z, qsq = qv.w;
    int cnt = 0;
    for (int base2 = 0; base2 < total2; base2 += 64) {
      int i = base2 + lane;
      bool valid = i < total2;
      float d = 1e30f;
      if (valid) {
        float4 p = big[i];
        d = qsq + p.w - 2.f*(qx*p.x + qy*p.y + qz*p.z);
      }
      bool take = valid && (d <= T0);
      unsigned long long bal = __ballot(take);
      int pos = cnt + __popcll(bal & ((1ull << lane) - 1ull));
      if (take && pos < 64) { sbd[pos] = d; sbi[pos] = i; }
      cnt += __popcll(bal);
    }
    if (cnt > 64) {                              // ~never
      if (lane == 0) { int pos = atomicAdd(failcnt, 1); faillist[pos] = t | FB_BAD; }
      continue;
    }
    float dv = (lane < cnt) ? sbd[lane] : 1e30f;
    int   iv = (lane < cnt) ? sbi[lane] : 0x7fffffff;
#pragma unroll
    for (int kk = 2; kk <= 64; kk <<= 1) {       // bitonic sort (d, idx)
#pragma unroll
      for (int j = kk >> 1; j > 0; j >>= 1) {
        float od = __shfl_xor(dv, j, 64);
        int   oi = __shfl_xor(iv, j, 64);
        bool keepmin = (((lane & j) == 0) == ((lane & kk) == 0));
        bool less = (od < dv) || (od == dv && oi < iv);
        bool take2 = keepmin ? less : !less;
        dv = take2 ? od : dv;
        iv = take2 ? oi : iv;
      }
    }
    float d16b = __shfl(dv, 15, 64);
    float m = 1e30f;
    if (blok2[0]) m = fminf(m, qx - blo2[0]);
    if (bhik2[0]) m = fminf(m, bhi2[0] - qx);
    if (blok2[1]) m = fminf(m, qy - blo2[1]);
    if (bhik2[1]) m = fminf(m, bhi2[1] - qy);
    if (blok2[2]) m = fminf(m, qz - blo2[2]);
    if (bhik2[2]) m = fminf(m, bhi2[2] - qz);
    bool ok = (m > 0.f) && (m*m > d16b + SLOP);
    int qn = sortid[t];
    size_t row = ((size_t)(b*NPTS + qn))*KK;
    if (lane < KK) {
      int rowi = 0;                              // reconstruct csort position
#pragma unroll
      for (int rr = 1; rr < 25; ++rr) rowi += (iv >= pre2[rr]);
      int gp = rs2[rowi] + (iv - pre2[rowi]);
      oidx[row + lane] = ok ? sortid[gp] : gp;   // result, or seed positions
    }
    if (!ok && lane == 0) { int pos = atomicAdd(failcnt, 1); faillist[pos] = t; }
  }
}

// ---------------- residual fallback: ONE WAVE PER QUERY, contiguous superset scan ----
__launch_bounds__(256)
__global__ void k_knn_fb(const float4* __restrict__ csort, const int* __restrict__ sortid,
                         const int* __restrict__ starts, const float* __restrict__ edges,
                         const int* __restrict__ faillist, const int* __restrict__ failcnt,
                         int* __restrict__ oidx) {
  int tid = threadIdx.x, lane = tid & 63, w = tid >> 6;
  int gw = blockIdx.x*4 + w, nw = gridDim.x*4;
  int nf = failcnt[0];
  for (int f = gw; f < nf; f += nw) {
    int fv = faillist[f];                        // uniform per wave
    bool seeded = (fv & FB_BAD) == 0;
    int t = fv & (FB_BAD - 1);
    int b = t >> 15;
    const int* st = starts + b*G3;
    const float* ex = edges + (b*3+0)*(G+1);
    const float* ey = edges + (b*3+1)*(G+1);
    const float* ez = edges + (b*3+2)*(G+1);
    float4 qv = csort[t];
    const float qx = qv.x, qy = qv.y, qz = qv.z, qsq = qv.w;
    int qn = sortid[t];
    size_t row = ((size_t)(b*NPTS + qn))*KK;
    float T;
    int lo_pos, hi_pos;
    if (seeded) {
      // T = max seed distance (= d16 of 5x5x5 superset) >= true d16
      float sd = -1e30f;
      if (lane < KK) {
        int pos = oidx[row + lane];
        float4 p = csort[pos];
        sd = qsq + p.w - 2.f*(qx*p.x + qy*p.y + qz*p.z);
      }
      T = sd;
#pragma unroll
      for (int m = 32; m > 0; m >>= 1) T = fmaxf(T, __shfl_xor(T, m, 64));
      T += TEPS;
      float R = sqrtf(T)*1.0001f + 1e-12f;
      // ballot-parallel per-axis cell ranges covering the ball
      bool tk = (lane < G-1) && (ex[lane+1] < qx - R);
      int xl = __popcll(__ballot(tk));
      tk = (lane >= 1 && lane <= G-1) && (ex[lane] > qx + R);
      int xh = (G-1) - __popcll(__ballot(tk));
      tk = (lane < G-1) && (ey[lane+1] < qy - R);
      int yl = __popcll(__ballot(tk));
      tk = (lane >= 1 && lane <= G-1) && (ey[lane] > qy + R);
      int yh = (G-1) - __popcll(__ballot(tk));
      tk = (lane < G-1) && (ez[lane+1] < qz - R);
      int zl = __popcll(__ballot(tk));
      tk = (lane >= 1 && lane <= G-1) && (ez[lane] > qz + R);
      int zh = (G-1) - __popcll(__ballot(tk));
      // contiguous superset range: [first box cell, last box cell]
      lo_pos = st[(zl*G + yl)*G + xl];
      hi_pos = st[(zh*G + yh)*G + xh + 1];
    } else {
      // ~never: two-pass full-batch scan; T = 16th smallest of 64 lane minima
      float mn = 1e30f;
      for (int i = b*NPTS + lane; i < b*NPTS + NPTS; i += 64) {
        float4 p = csort[i];
        float d = qsq + p.w - 2.f*(qx*p.x + qy*p.y + qz*p.z);
        mn = fminf(mn, d);
      }
      float v = mn;
#pragma unroll
      for (int k2 = 2; k2 <= 64; k2 <<= 1) {
#pragma unroll
        for (int j = k2 >> 1; j > 0; j >>= 1) {
          float o = __shfl_xor(v, j, 64);
          bool keepmin = (((lane & j) == 0) == ((lane & k2) == 0));
          v = keepmin ? fminf(v, o) : fmaxf(v, o);
        }
      }
      T = __shfl(v, 15, 64) + TEPS;              // >= true d16 (16 distinct candidates)
      lo_pos = b*NPTS;
      hi_pos = b*NPTS + NPTS;
    }
    // streaming threshold scan + per-lane top-16 insert (contiguous, pipelined loads)
    float dl[KK]; int il[KK];
#pragma unroll
    for (int i = 0; i < KK; ++i) { dl[i] = 1e30f; il[i] = 0x7fffffff; }
    for (int i = lo_pos + lane; i < hi_pos; i += 64) {
      float4 p = csort[i];
      float d = qsq + p.w - 2.f*(qx*p.x + qy*p.y + qz*p.z);
      if (d <= T && d < dl[KK-1]) {              // rare insert
        float cd = d; int ci = i;
#pragma unroll
        for (int i2 = 0; i2 < KK; ++i2) {
          bool sw = cd < dl[i2];
          float td = dl[i2]; int ti = il[i2];
          dl[i2] = sw ? cd : td; il[i2] = sw ? ci : ti;
          cd = sw ? td : cd;    ci = sw ? ti : ci;
        }
      }
    }
    // exact union top-16: 16 argmin rounds by (d, csort pos); winner pops
    int res = 0;
#pragma unroll
    for (int r = 0; r < KK; ++r) {
      float v = dl[0]; int pi = il[0]; int l = lane;
#pragma unroll
      for (int m = 1; m < 64; m <<= 1) {
        float ov = __shfl_xor(v, m, 64);
        int   op = __shfl_xor(pi, m, 64);
        int   ol = __shfl_xor(l, m, 64);
        bool take = (ov < v) || (ov == v && op < pi);
        v = take ? ov : v; pi = take ? op : pi; l = take ? ol : l;
      }
      if (lane == r) res = pi;
      bool win = (lane == l);
#pragma unroll
      for (int i = 0; i < KK-1; ++i) {
        dl[i] = win ? dl[i+1] : dl[i];
        il[i] = win ? il[i+1] : il[i];
      }
      dl[KK-1] = win ? 1e30f : dl[KK-1];
      il[KK-1] = win ? 0x7fffffff : il[KK-1];
    }
    if (lane < KK) oidx[row + lane] = sortid[res];
  }
}

// ---------------- FUSED: mlp1 (blocks 0..63, 4 pts/thread) + lsestats (blocks 64..1087, 4 el/thread) ----
__global__ void k_stats(const float* __restrict__ features,
                        const float* __restrict__ W1, const float* __restrict__ b1,
                        const float* __restrict__ Wsc, const float* __restrict__ bsc,
                        float* __restrict__ x1, float* __restrict__ ppa,
                        const float* __restrict__ coords, const int* __restrict__ idx,
                        const float* __restrict__ Wl1, const float* __restrict__ bl1,
                        const float* __restrict__ Wl2, const float* __restrict__ bl2,
                        float* __restrict__ ppb) {
  int tid = threadIdx.x;
  if (blockIdx.x < 64) {
    // ---- mlp1 (leaky 0.2) + shortcut BN partial sums; 4 points/thread ----
    __shared__ float sW1[128], sb1[16], sWsc[512], sbsc[64];
    __shared__ float part[128];
    if (tid < 128) { sW1[tid] = W1[tid]; part[tid] = 0.f; }
    if (tid < 16)  sb1[tid] = b1[tid];
    if (tid < 64)  sbsc[tid] = bsc[tid];
    for (int i = tid; i < 512; i += 256) sWsc[i] = Wsc[i];
    __syncthreads();
    int q0 = blockIdx.x*1024;
    float f[4][8];
#pragma unroll
    for (int p = 0; p < 4; ++p) {
      int q = q0 + p*256 + tid;
      int b = q >> 15, n = q & (NPTS-1);
#pragma unroll
      for (int c = 0; c < 8; ++c) f[p][c] = features[((size_t)b*8 + c)*NPTS + n];
#pragma unroll
      for (int co = 0; co < 16; ++co) {
        float a = sb1[co];
#pragma unroll
        for (int c = 0; c < 8; ++c) a += f[p][c]*sW1[co*8+c];
        x1[(size_t)q*16 + co] = a > 0.f ? a : 0.2f*a;
      }
    }
    int lane = tid & 63;
#pragma unroll
    for (int co = 0; co < 64; ++co) {
      float s = 0.f, ss = 0.f;
#pragma unroll
      for (int p = 0; p < 4; ++p) {
        float a = sbsc[co];
#pragma unroll
        for (int c = 0; c < 8; ++c) a += f[p][c]*sWsc[co*8+c];
        s += a; ss += a*a;
      }
      s = wred64(s); ss = wred64(ss);
      if (lane == 0) { atomicAdd(&part[co], s); atomicAdd(&part[64+co], ss); }
    }
    __syncthreads();
    if (tid < 128) ppa[(size_t)blockIdx.x*128 + tid] = part[tid];
  } else {
    // ---- BN partial sums for BOTH LSE geometric encodings; 4 elements/thread ----
    __shared__ float sW1[160], sb1[16], sW2[160], sb2[16];
    __shared__ float red[4][64];
    int blk = blockIdx.x - 64;          // 0..1023
    for (int i = tid; i < 160; i += 256) { sW1[i] = Wl1[i]; sW2[i] = Wl2[i]; }
    if (tid < 16) { sb1[tid] = bl1[tid]; sb2[tid] = bl2[tid]; }
    __syncthreads();
    float cat[4][10];
#pragma unroll
    for (int p = 0; p < 4; ++p) {
      int t = blk*1024 + p*256 + tid;   // (b,n,k) flat
      int q = t >> 4;
      int b = q >> 15, n = q & (NPTS-1);
      const float* cb = coords + (size_t)b*(NPTS*3);
      int j = idx[t];
      float cx = cb[n*3], cy = cb[n*3+1], cz = cb[n*3+2];
      float px = cb[j*3], py = cb[j*3+1], pz = cb[j*3+2];
      cat[p][0]=cx; cat[p][1]=cy; cat[p][2]=cz;
      cat[p][3]=px; cat[p][4]=py; cat[p][5]=pz;
      cat[p][6]=cx-px; cat[p][7]=cy-py; cat[p][8]=cz-pz; cat[p][9]=1.f;
    }
    int wave = tid >> 6, lane = tid & 63;
#pragma unroll
    for (int co = 0; co < 16; ++co) {
      float s1 = 0.f, q1 = 0.f, s2 = 0.f, q2 = 0.f;
#pragma unroll
      for (int p = 0; p < 4; ++p) {
        float a1 = sb1[co], a2 = sb2[co];
#pragma unroll
        for (int d0 = 0; d0 < 10; ++d0) { a1 += cat[p][d0]*sW1[co*10+d0]; a2 += cat[p][d0]*sW2[co*10+d0]; }
        s1 += a1; q1 += a1*a1; s2 += a2; q2 += a2*a2;
      }
      s1 = wred64(s1); q1 = wred64(q1);
      s2 = wred64(s2); q2 = wred64(q2);
      if (lane == 0) { red[wave][co]=s1; red[wave][16+co]=q1; red[wave][32+co]=s2; red[wave][48+co]=q2; }
    }
    __syncthreads();
    if (tid < 64) {
      float v = red[0][tid] + red[1][tid] + red[2][tid] + red[3][tid];
      ppb[(size_t)blk*64 + tid] = v;    // layout matches stats[S_L1..S_L2+32)
    }
  }
}

// ---------------- LSE1 + attentive pooling 1 (BN-L1 inline; softmax w/o max-sub) ----------------
__launch_bounds__(256)
__global__ void k_att1(const float* __restrict__ coords, const int* __restrict__ idx,
                       const float* __restrict__ x1ws,
                       const float* __restrict__ Wl1, const float* __restrict__ bl1,
                       const float* __restrict__ Ws1, const float* __restrict__ Wp1,
                       const float* __restrict__ bp1, const float* __restrict__ stats,
                       const float* __restrict__ gl1, const float* __restrict__ bl1b,
                       float* __restrict__ t2, float* __restrict__ ppart) {
  __shared__ float saL[16], scL[16];
  __shared__ float sWl[160], sbl[16];
  __shared__ float sWs[1024];
  __shared__ float sWpT[512], sbp[16];
  __shared__ float lsum[16], lsq[16];
  int tid = threadIdx.x;
  if (tid < 16) {
    float m = stats[S_L1 + tid]*INVQK;
    float v = stats[S_L1 + 16 + tid]*INVQK - m*m;
    float a = gl1[tid]*rsqrtf(v + EPS);
    saL[tid] = a; scL[tid] = bl1b[tid] - m*a;
  }
  __syncthreads();
  for (int i = tid; i < 160; i += 256) { int c = i/10; sWl[i] = Wl1[i]*saL[c]; }
  if (tid < 16) sbl[tid] = bl1[tid]*saL[tid] + scL[tid];
  for (int i = tid; i < 1024; i += 256) sWs[i] = Ws1[i];
  for (int i = tid; i < 512; i += 256) { int co = i >> 4, cp = i & 15; sWpT[i] = Wp1[cp*32 + co]; }
  if (tid < 16) { sbp[tid] = bp1[tid]; lsum[tid] = 0.f; lsq[tid] = 0.f; }
  __syncthreads();
  int gp = blockIdx.x*16 + (tid >> 4);
  int k  = tid & 15;
  int b = gp >> 15, n = gp & (NPTS-1);
  const float* cb = coords + (size_t)b*(NPTS*3);
  int j = idx[(size_t)gp*KK + k];
  float cx = cb[n*3], cy = cb[n*3+1], cz = cb[n*3+2];
  float px = cb[j*3], py = cb[j*3+1], pz = cb[j*3+2];
  float cat[10] = {cx,cy,cz,px,py,pz,cx-px,cy-py,cz-pz,1.f};
  float x[32];
#pragma unroll
  for (int co = 0; co < 16; ++co) {
    float a = sbl[co];
#pragma unroll
    for (int d0 = 0; d0 < 10; ++d0) a += cat[d0]*sWl[co*10+d0];
    x[co] = a > 0.f ? a : 0.f;
  }
  {
    const float4* xp = (const float4*)(x1ws + (size_t)gp*16);
    float4 u0 = xp[0], u1 = xp[1], u2 = xp[2], u3 = xp[3];
    x[16]=u0.x; x[17]=u0.y; x[18]=u0.z; x[19]=u0.w;
    x[20]=u1.x; x[21]=u1.y; x[22]=u1.z; x[23]=u1.w;
    x[24]=u2.x; x[25]=u2.y; x[26]=u2.z; x[27]=u2.w;
    x[28]=u3.x; x[29]=u3.y; x[30]=u3.z; x[31]=u3.w;
  }
  float tacc = sbp[k];
#pragma unroll
  for (int co = 0; co < 32; ++co) {
    float s = 0.f;
#pragma unroll
    for (int ci = 0; ci < 32; ++ci) s += x[ci]*sWs[co*32+ci];
    float e = __expf(s);                 // scores bounded: softmax w/o max-sub (identical ratio)
    float se = e;
#pragma unroll
    for (int msk = 8; msk > 0; msk >>= 1) se += __shfl_xor(se, msk, 16);
    float w = e/se;
    float fv = w*x[co];
#pragma unroll
    for (int msk = 8; msk > 0; msk >>= 1) fv += __shfl_xor(fv, msk, 16);
    tacc += fv*sWpT[co*16+k];
  }
  t2[(size_t)gp*16 + k] = tacc;
  atomicAdd(&lsum[k], tacc);
  atomicAdd(&lsq[k], tacc*tacc);
  __syncthreads();
  if (tid < 16) {
    ppart[(size_t)blockIdx.x*32 + tid]      = lsum[tid];
    ppart[(size_t)blockIdx.x*32 + 16 + tid] = lsq[tid];
  }
}

// ---------------- LSE2 + attentive pooling 2 (BN-L2 + BN-P1 inline; softmax w/o max-sub) ----
__launch_bounds__(256)
__global__ void k_att2(const float* __restrict__ coords, const int* __restrict__ idx,
                       const float* __restrict__ t2ws,
                       const float* __restrict__ Wl2, const float* __restrict__ bl2,
                       const float* __restrict__ Ws2, const float* __restrict__ Wp2,
                       const float* __restrict__ bp2, const float* __restrict__ stats,
                       const float* __restrict__ gl2, const float* __restrict__ bl2b,
                       const float* __restrict__ gp1, const float* __restrict__ bp1b,
                       float* __restrict__ t4, float* __restrict__ ppart) {
  __shared__ float saL[16], scL[16];
  __shared__ float sWl[160], sbl[16];
  __shared__ float sWs[1024];
  __shared__ float sWpT[1024], sbp[32];
  __shared__ float sa1[16], sc1[16];
  __shared__ float lsum[32], lsq[32];
  int tid = threadIdx.x;
  if (tid < 16) {
    float m = stats[S_L2 + tid]*INVQK;
    float v = stats[S_L2 + 16 + tid]*INVQK - m*m;
    float a = gl2[tid]*rsqrtf(v + EPS);
    saL[tid] = a; scL[tid] = bl2b[tid] - m*a;
    float m1 = stats[S_P1 + tid]*INVN;
    float v1 = stats[S_P1 + 16 + tid]*INVN - m1*m1;
    float a1 = gp1[tid]*rsqrtf(v1 + EPS);
    sa1[tid] = a1; sc1[tid] = bp1b[tid] - m1*a1;
  }
  __syncthreads();
  for (int i = tid; i < 160; i += 256) { int c = i/10; sWl[i] = Wl2[i]*saL[c]; }
  if (tid < 16) sbl[tid] = bl2[tid]*saL[tid] + scL[tid];
  for (int i = tid; i < 1024; i += 256) {
    sWs[i] = Ws2[i];
    int co = i >> 5, cp = i & 31; sWpT[i] = Wp2[cp*32 + co];
  }
  if (tid < 32) { sbp[tid] = bp2[tid]; lsum[tid]=0.f; lsq[tid]=0.f; }
  __syncthreads();
  int gp = blockIdx.x*16 + (tid >> 4);
  int k  = tid & 15;
  int b = gp >> 15, n = gp & (NPTS-1);
  const float* cb = coords + (size_t)b*(NPTS*3);
  int j = idx[(size_t)gp*KK + k];
  float cx = cb[n*3], cy = cb[n*3+1], cz = cb[n*3+2];
  float px = cb[j*3], py = cb[j*3+1], pz = cb[j*3+2];
  float cat[10] = {cx,cy,cz,px,py,pz,cx-px,cy-py,cz-pz,1.f};
  float x[32];
#pragma unroll
  for (int co = 0; co < 16; ++co) {
    float a = sbl[co];
#pragma unroll
    for (int d0 = 0; d0 < 10; ++d0) a += cat[d0]*sWl[co*10+d0];
    x[co] = a > 0.f ? a : 0.f;
  }
  {
    const float4* xp = (const float4*)(t2ws + (size_t)gp*16);
    float4 u0 = xp[0], u1 = xp[1], u2 = xp[2], u3 = xp[3];
    float xv[16] = {u0.x,u0.y,u0.z,u0.w, u1.x,u1.y,u1.z,u1.w,
                    u2.x,u2.y,u2.z,u2.w, u3.x,u3.y,u3.z,u3.w};
#pragma unroll
    for (int c = 0; c < 16; ++c) {
      float v = xv[c]*sa1[c] + sc1[c];
      x[16+c] = v > 0.f ? v : 0.f;
    }
  }
  float tacc0 = sbp[k], tacc1 = sbp[k+16];
#pragma unroll
  for (int co = 0; co < 32; ++co) {
    float s = 0.f;
#pragma unroll
    for (int ci = 0; ci < 32; ++ci) s += x[ci]*sWs[co*32+ci];
    float e = __expf(s);                 // scores bounded: softmax w/o max-sub (identical ratio)
    float se = e;
#pragma unroll
    for (int msk = 8; msk > 0; msk >>= 1) se += __shfl_xor(se, msk, 16);
    float w = e/se;
    float fv = w*x[co];
#pragma unroll
    for (int msk = 8; msk > 0; msk >>= 1) fv += __shfl_xor(fv, msk, 16);
    tacc0 += fv*sWpT[co*32+k];
    tacc1 += fv*sWpT[co*32+k+16];
  }
  t4[(size_t)gp*32 + k]      = tacc0;
  t4[(size_t)gp*32 + k + 16] = tacc1;
  atomicAdd(&lsum[k], tacc0);      atomicAdd(&lsq[k], tacc0*tacc0);
  atomicAdd(&lsum[k+16], tacc1);   atomicAdd(&lsq[k+16], tacc1*tacc1);
  __syncthreads();
  if (tid < 32) {
    ppart[(size_t)blockIdx.x*64 + tid]      = lsum[tid];
    ppart[(size_t)blockIdx.x*64 + 32 + tid] = lsq[tid];
  }
}

// ---------------- final: mlp2 + BN'd shortcut + leaky 0.01 (BN-SC + BN-P2 inline) ----------------
__global__ void k_final(const float* __restrict__ t4ws, const float* __restrict__ features,
                        const float* __restrict__ W2, const float* __restrict__ b2,
                        const float* __restrict__ Wsc, const float* __restrict__ bsc,
                        const float* __restrict__ stats,
                        const float* __restrict__ gsc, const float* __restrict__ bscb,
                        const float* __restrict__ gp2, const float* __restrict__ bp2b,
                        float* __restrict__ out) {
  __shared__ float saS[64], scS[64];
  __shared__ float sW2[2048], sb2[64], sWscF[512], sbscF[64], sa[32], scc[32];
  int tid = threadIdx.x;
  if (tid < 64) {
    float m = stats[S_SC + tid]*INVN;
    float v = stats[S_SC + 64 + tid]*INVN - m*m;
    float a = gsc[tid]*rsqrtf(v + EPS);
    saS[tid] = a; scS[tid] = bscb[tid] - m*a;
  }
  if (tid < 32) {
    float m = stats[S_P2 + tid]*INVN;
    float v = stats[S_P2 + 32 + tid]*INVN - m*m;
    float a = gp2[tid]*rsqrtf(v + EPS);
    sa[tid] = a; scc[tid] = bp2b[tid] - m*a;
  }
  __syncthreads();
  for (int i = tid; i < 2048; i += 256) sW2[i] = W2[i];
  if (tid < 64) sb2[tid] = b2[tid];
  for (int i = tid; i < 512; i += 256) { int c2 = i >> 3; sWscF[i] = Wsc[i]*saS[c2]; }
  if (tid < 64) sbscF[tid] = bsc[tid]*saS[tid] + scS[tid];
  __syncthreads();
  int q = blockIdx.x*256 + tid;
  int b = q >> 15, n = q & (NPTS-1);
  float x3[32];
  const float4* tp = (const float4*)(t4ws + (size_t)q*32);
#pragma unroll
  for (int i = 0; i < 8; ++i) {
    float4 u = tp[i];
    float v0 = u.x*sa[4*i+0] + scc[4*i+0];
    float v1 = u.y*sa[4*i+1] + scc[4*i+1];
    float v2 = u.z*sa[4*i+2] + scc[4*i+2];
    float v3 = u.w*sa[4*i+3] + scc[4*i+3];
    x3[4*i+0] = v0 > 0.f ? v0 : 0.f;
    x3[4*i+1] = v1 > 0.f ? v1 : 0.f;
    x3[4*i+2] = v2 > 0.f ? v2 : 0.f;
    x3[4*i+3] = v3 > 0.f ? v3 : 0.f;
  }
  float f[8];
#pragma unroll
  for (int c = 0; c < 8; ++c) f[c] = features[((size_t)b*8+c)*NPTS + n];
  for (int c2 = 0; c2 < 64; ++c2) {
    float acc = sb2[c2];
#pragma unroll
    for (int co = 0; co < 32; ++co) acc += x3[co]*sW2[c2*32+co];
    float sv = sbscF[c2];
#pragma unroll
    for (int c = 0; c < 8; ++c) sv += f[c]*sWscF[c2*8+c];
    float o = acc + sv;
    out[((size_t)b*64 + c2)*NPTS + n] = o > 0.f ? o : 0.01f*o;
  }
}

extern "C" void kernel_launch(void* const* d_in, const int* in_sizes, int n_in,
                              void* d_out, int out_size, void* d_ws, size_t ws_size,
                              hipStream_t stream) {
  const float* coords   = (const float*)d_in[0];
  const float* features = (const float*)d_in[1];
  const float* W1  = (const float*)d_in[2];
  const float* b1  = (const float*)d_in[3];
  const float* Wl1 = (const float*)d_in[4];
  const float* bl1 = (const float*)d_in[5];
  const float* gl1 = (const float*)d_in[6];
  const float* bl1b= (const float*)d_in[7];
  const float* Ws1 = (const float*)d_in[8];
  const float* Wp1 = (const float*)d_in[9];
  const float* bp1 = (const float*)d_in[10];
  const float* gp1 = (const float*)d_in[11];
  const float* bp1b= (const float*)d_in[12];
  const float* Wl2 = (const float*)d_in[13];
  const float* bl2 = (const float*)d_in[14];
  const float* gl2 = (const float*)d_in[15];
  const float* bl2b= (const float*)d_in[16];
  const float* Ws2 = (const float*)d_in[17];
  const float* Wp2 = (const float*)d_in[18];
  const float* bp2 = (const float*)d_in[19];
  const float* gp2 = (const float*)d_in[20];
  const float* bp2b= (const float*)d_in[21];
  const float* W2  = (const float*)d_in[22];
  const float* b2  = (const float*)d_in[23];
  const float* Wsc = (const float*)d_in[24];
  const float* bsc = (const float*)d_in[25];
  const float* gsc = (const float*)d_in[26];
  const float* bscb= (const float*)d_in[27];

  float* wsF  = (float*)d_ws;
  int*   wsI  = (int*)d_ws;
  int*   idxp = wsI;
  float* x1p  = wsF + WS_X1;
  float* t2p  = wsF + WS_T2;
  float* t4p  = wsF + WS_T4;
  float* stat = wsF + WS_STAT;
  int*   gcnt = wsI + WS_GCNT;
  int*   gsta = wsI + WS_GSTART;
  int*   gcel = wsI + WS_CELLID;
  int*   sid  = wsI + WS_SORTID;
  float4* csrt = (float4*)(wsF + WS_CSORT);
  unsigned int* bbox = (unsigned int*)(wsI + WS_BBOX);
  int*   fcnt = wsI + WS_BBOX + 12;       // within bbox's 16-slot region
  int*   flist= wsI + WS_FAIL;            // aliases cellid (dead after scatter)
  int*   hist = wsI + WS_HIST;
  int*   strt = wsI + WS_STARTS;          // aliases hist (dead after k_edges)
  float* edge = wsF + WS_EDGE;
  float* prt  = wsF + WS_PART;            // lsestats/att partials alias csort (dead after k_knn_fb)
  float* prtA = wsF + WS_PARTA;           // mlp1 partials alias t2 (dead until k_att1)
  float* outp = (float*)d_out;

  hipLaunchKernelGGL(k_zero_all, dim3(48), dim3(256), 0, stream, stat, gcnt, hist, bbox, fcnt);
  hipLaunchKernelGGL(k_bbox,    dim3(NQ/256), dim3(256), 0, stream, coords, bbox);
  hipLaunchKernelGGL(k_hist,    dim3(NQ/256), dim3(256), 0, stream, coords, bbox, hist);
  hipLaunchKernelGGL(k_edges,   dim3(6), dim3(256), 0, stream, hist, bbox, edge);
  hipLaunchKernelGGL(k_bin,     dim3(NQ/256), dim3(256), 0, stream, coords, edge, gcel, gcnt);
  hipLaunchKernelGGL(k_alloc,   dim3(1), dim3(1024), 0, stream, gcnt, gsta, strt);
  hipLaunchKernelGGL(k_scatter, dim3(NQ/256), dim3(256), 0, stream, coords, gcel, gsta, csrt, sid);
  hipLaunchKernelGGL(k_cellknn, dim3(2*G3), dim3(256), 0, stream,
                     csrt, sid, strt, edge, idxp, flist, fcnt);
  hipLaunchKernelGGL(k_knn_fb,  dim3(2048), dim3(256), 0, stream,
                     csrt, sid, strt, edge, flist, fcnt, idxp);
  hipLaunchKernelGGL(k_stats, dim3(64 + (NQ*KK)/1024), dim3(256), 0, stream,
                     features, W1, b1, Wsc, bsc, x1p, prtA,
                     coords, idxp, Wl1, bl1, Wl2, bl2, prt);
  hipLaunchKernelGGL(k_pred2, dim3(192), dim3(256), 0, stream, prtA, prt, stat);
  hipLaunchKernelGGL(k_att1, dim3(NQ/16), dim3(256), 0, stream,
                     coords, idxp, x1p, Wl1, bl1, Ws1, Wp1, bp1, stat, gl1, bl1b, t2p, prt);
  hipLaunchKernelGGL(k_pred, dim3(32), dim3(256), 0, stream, prt, NQ/16, 32, stat, S_P1);
  hipLaunchKernelGGL(k_att2, dim3(NQ/16), dim3(256), 0, stream,
                     coords, idxp, t2p, Wl2, bl2, Ws2, Wp2, bp2, stat,
                     gl2, bl2b, gp1, bp1b, t4p, prt);
  hipLaunchKernelGGL(k_pred, dim3(64), dim3(256), 0, stream, prt, NQ/16, 64, stat, S_P2);
  hipLaunchKernelGGL(k_final, dim3(NQ/256), dim3(256), 0, stream,
                     t4p, features, W2, b2, Wsc, bsc, stat, gsc, bscb, gp2, bp2b, outp);
}

// Round 26
// 671.903 us; speedup vs baseline: 1.2763x; 1.0557x over previous
//
#include <hip/hip_runtime.h>
#include <math.h>

#define NPTS  32768
#define NB    2
#define NQ    (NB*NPTS)
#define KK    16
#define EPS   1e-6f
#define G     16
#define G3    (G*G*G)
#define HB    2048
#define SLOP  0.05f
#define TEPS  1e-3f
#define CAPC  512
#define CAP2  1408
#define INVQK (1.f/(float)((size_t)NQ*KK))
#define INVN  (1.f/(float)NQ)

// stats element offsets
#define S_L1 0
#define S_L2 32
#define S_P1 64
#define S_P2 96
#define S_SC 160

// workspace element offsets (4-byte units)
#define WS_X1     (NQ*16)
#define WS_T2     (NQ*32)
#define WS_T4     (NQ*48)
#define WS_STAT   (NQ*80)
#define WS_COEF   (WS_STAT + 512)
#define WS_GCNT   (WS_STAT + 1024)
#define WS_GSTART (WS_GCNT + 2*G3)
#define WS_CELLID (WS_GSTART + 2*G3)
#define WS_SORTID (WS_CELLID + NQ)
#define WS_CSORT  (WS_SORTID + NQ)      /* float4 x NQ (16B-aligned) */
#define WS_BBOX   (WS_CSORT + 4*NQ)
#define WS_HIST   (WS_BBOX + 16)
#define WS_EDGE   (WS_HIST + 6*HB)
#define WS_STARTS WS_HIST               /* starts aliases hist (dead after k_edges) */
#define WS_FAIL   WS_CELLID             /* fail list aliases cellid (dead after scatter) */
#define WS_PART   WS_CSORT              /* lsestats/att partials alias csort (dead after k_knn_fb) */
#define WS_PARTA  WS_T2                 /* mlp1 partials alias t2 (dead until k_att1) */

#define FB_BAD    (1 << 30)             /* faillist tag: bad -> unseeded full-batch scan */

__device__ __forceinline__ float wred64(float v) {
#pragma unroll
  for (int m = 32; m > 0; m >>= 1) v += __shfl_xor(v, m, 64);
  return v;
}

// order-preserving float <-> uint encoding for atomic min/max
__device__ __forceinline__ unsigned int encf(float f) {
  unsigned int u = __float_as_uint(f);
  return (u & 0x80000000u) ? ~u : (u | 0x80000000u);
}
__device__ __forceinline__ float decf(unsigned int u) {
  return (u & 0x80000000u) ? __uint_as_float(u & 0x7fffffffu) : __uint_as_float(~u);
}

// 4-step binary search over G=16 quantile edges; e[0] <= x guaranteed
__device__ __forceinline__ int bs16(const float* e, float x) {
  int c = (x >= e[8]) ? 8 : 0;
  c += (x >= e[c+4]) ? 4 : 0;
  c += (x >= e[c+2]) ? 2 : 0;
  c += (x >= e[c+1]) ? 1 : 0;
  return c;
}

// ---------------- zero stats + counters + hist + bbox + failcnt ----------------
__global__ void k_zero_all(float* __restrict__ stats, int* __restrict__ gcnt,
                           int* __restrict__ hist, unsigned int* __restrict__ bbox,
                           int* __restrict__ failcnt) {
  int i = blockIdx.x*256 + threadIdx.x;       // grid covers 12288
  if (i < 2*G3) gcnt[i] = 0;
  if (i < 6*HB) hist[i] = 0;
  if (i < 320)  stats[i] = 0.f;
  if (i < 12)   bbox[i] = ((i % 6) < 3) ? 0xFFFFFFFFu : 0u;
  if (i == 0)   failcnt[0] = 0;
}

// ---------------- deterministic partial reduction: stats[soff+c] = sum_blk part[blk][c] ----
__global__ void k_pred(const float* __restrict__ part, int nblk, int nch,
                       float* __restrict__ stats, int soff) {
  __shared__ float red[256];
  int c = blockIdx.x, tid = threadIdx.x;
  float s = 0.f;
  for (int i = tid; i < nblk; i += 256) s += part[(size_t)i*nch + c];
  red[tid] = s;
  __syncthreads();
  for (int off2 = 128; off2 > 0; off2 >>= 1) {
    if (tid < off2) red[tid] += red[tid + off2];
    __syncthreads();
  }
  if (tid == 0) stats[soff + c] = red[0];
}

// ---------------- fused dual partial reduction: SC (128ch from pa) + L1/L2 (64ch from pb) ----
__global__ void k_pred2(const float* __restrict__ pa, const float* __restrict__ pb,
                        float* __restrict__ stats) {
  __shared__ float red[256];
  int cb = blockIdx.x, tid = threadIdx.x;
  const float* part; int nblk, nch, soff, c;
  if (cb < 128) { part = pa; nblk = 64;   nch = 128; soff = S_SC; c = cb; }
  else          { part = pb; nblk = 1024; nch = 64;  soff = S_L1; c = cb - 128; }
  float s = 0.f;
  for (int i = tid; i < nblk; i += 256) s += part[(size_t)i*nch + c];
  red[tid] = s;
  __syncthreads();
  for (int off2 = 128; off2 > 0; off2 >>= 1) {
    if (tid < off2) red[tid] += red[tid + off2];
    __syncthreads();
  }
  if (tid == 0) stats[soff + c] = red[0];
}

// ---------------- per-batch exact bounding box ----------------
__global__ void k_bbox(const float* __restrict__ coords, unsigned int* __restrict__ bbox) {
  __shared__ unsigned int rmn[3][4], rmx[3][4];
  int tid = threadIdx.x;
  int t = blockIdx.x*256 + tid;
  int b = t >> 15, n = t & (NPTS-1);
  const float* cb = coords + (size_t)b*(NPTS*3);
  unsigned int e[3] = { encf(cb[n*3+0]), encf(cb[n*3+1]), encf(cb[n*3+2]) };
  unsigned int mn[3] = { e[0], e[1], e[2] }, mx[3] = { e[0], e[1], e[2] };
#pragma unroll
  for (int s = 32; s > 0; s >>= 1) {
#pragma unroll
    for (int a = 0; a < 3; ++a) {
      unsigned int o1 = (unsigned int)__shfl_xor((int)mn[a], s, 64);
      unsigned int o2 = (unsigned int)__shfl_xor((int)mx[a], s, 64);
      mn[a] = mn[a] < o1 ? mn[a] : o1;
      mx[a] = mx[a] > o2 ? mx[a] : o2;
    }
  }
  int wave = tid >> 6, lane = tid & 63;
  if (lane == 0) {
#pragma unroll
    for (int a = 0; a < 3; ++a) { rmn[a][wave] = mn[a]; rmx[a][wave] = mx[a]; }
  }
  __syncthreads();
  if (tid < 3) {
    unsigned int a0 = min(min(rmn[tid][0], rmn[tid][1]), min(rmn[tid][2], rmn[tid][3]));
    unsigned int A0 = max(max(rmx[tid][0], rmx[tid][1]), max(rmx[tid][2], rmx[tid][3]));
    atomicMin(&bbox[b*6 + tid], a0);
    atomicMax(&bbox[b*6 + 3 + tid], A0);
  }
}

// ---------------- per-axis fine histogram ----------------
__global__ void k_hist(const float* __restrict__ coords, const unsigned int* __restrict__ bbox,
                       int* __restrict__ hist) {
  int t = blockIdx.x*256 + threadIdx.x;
  int b = t >> 15, n = t & (NPTS-1);
  const float* cb = coords + (size_t)b*(NPTS*3);
#pragma unroll
  for (int a = 0; a < 3; ++a) {
    float l = decf(bbox[b*6+a]), h = decf(bbox[b*6+3+a]);
    float ex = (h - l)*(1.f + 4e-7f) + 1e-30f;
    float inv = (float)HB/ex;
    int bin = (int)((cb[n*3+a] - l)*inv);
    bin = min(HB-1, max(0, bin));
    atomicAdd(&hist[(b*3+a)*HB + bin], 1);
  }
}

// ---------------- equal-frequency edges from histogram cdf ----------------
__global__ void k_edges(const int* __restrict__ hist, const unsigned int* __restrict__ bbox,
                        float* __restrict__ edges) {
  __shared__ int part[256];
  int p = blockIdx.x;                 // pair = b*3 + a, 6 blocks
  int b = p/3, a = p - b*3;
  int tid = threadIdx.x;
  const int* h = hist + p*HB;
  int v[8]; int s = 0;
#pragma unroll
  for (int i = 0; i < 8; ++i) { v[i] = h[tid*8 + i]; s += v[i]; }
  part[tid] = s;
  __syncthreads();
  for (int off = 1; off < 256; off <<= 1) {
    int x = part[tid];
    int y = (tid >= off) ? part[tid-off] : 0;
    __syncthreads();
    part[tid] = x + y;
    __syncthreads();
  }
  float l = decf(bbox[b*6+a]), hi = decf(bbox[b*6+3+a]);
  float ex = (hi - l)*(1.f + 4e-7f) + 1e-30f;
  float bw = ex*(1.f/(float)HB);
  int c = part[tid] - s;              // exclusive base
#pragma unroll
  for (int i = 0; i < 8; ++i) {
    int lo_c = c; c += v[i];
#pragma unroll
    for (int g = 1; g < G; ++g) {
      int tq = g*(NPTS/G);
      if (lo_c < tq && c >= tq) edges[p*(G+1) + g] = l + bw*(float)(tid*8 + i + 1);
    }
  }
  if (tid == 0) { edges[p*(G+1)] = l; edges[p*(G+1) + G] = hi + fabsf(hi)*1e-6f + 1e-20f; }
}

// ---------------- bin points into quantile cells ----------------
__global__ void k_bin(const float* __restrict__ coords, const float* __restrict__ edges,
                      int* __restrict__ cellid, int* __restrict__ gcnt) {
  __shared__ float se[3][G+1];
  int tid = threadIdx.x;
  int t = blockIdx.x*256 + tid;
  int b = t >> 15, n = t & (NPTS-1);
  if (tid < 3*(G+1)) se[tid/(G+1)][tid%(G+1)] = edges[b*3*(G+1) + tid];
  __syncthreads();
  const float* cb = coords + (size_t)b*(NPTS*3);
  int c0 = bs16(se[0], cb[n*3+0]);
  int c1 = bs16(se[1], cb[n*3+1]);
  int c2 = bs16(se[2], cb[n*3+2]);
  int cid = b*G3 + (c2*G + c1)*G + c0;
  cellid[t] = cid;
  atomicAdd(&gcnt[cid], 1);
}

// ---------------- deterministic global scan over all 8192 cells ----------------
__global__ void k_alloc(const int* __restrict__ gcnt, int* __restrict__ gstart,
                        int* __restrict__ starts) {
  __shared__ int part[1024];
  int tid = threadIdx.x;
  int v[8]; int s = 0;
#pragma unroll
  for (int i = 0; i < 8; ++i) { v[i] = gcnt[tid*8 + i]; s += v[i]; }
  part[tid] = s;
  __syncthreads();
  for (int off = 1; off < 1024; off <<= 1) {
    int x = part[tid];
    int y = (tid >= off) ? part[tid-off] : 0;
    __syncthreads();
    part[tid] = x + y;
    __syncthreads();
  }
  int base = part[tid] - s;
#pragma unroll
  for (int i = 0; i < 8; ++i) { gstart[tid*8 + i] = base; starts[tid*8 + i] = base; base += v[i]; }
  if (tid == 1023) starts[2*G3] = NQ;
}

// ---------------- scatter: packed float4 + original id, cell-sorted ----------------
__global__ void k_scatter(const float* __restrict__ coords, const int* __restrict__ cellid,
                          int* __restrict__ gstart, float4* __restrict__ csort,
                          int* __restrict__ sortid) {
  int t = blockIdx.x*256 + threadIdx.x;
  int b = t >> 15, n = t & (NPTS-1);
  const float* cb = coords + (size_t)b*(NPTS*3);
  int cid = cellid[t];
  int pos = atomicAdd(&gstart[cid], 1);
  float x = cb[n*3+0], y = cb[n*3+1], z = cb[n*3+2];
  csort[pos] = make_float4(x, y, z, x*x + y*y + z*z);
  sortid[pos] = n;
}

// ---------------- cell-centric KNN: 3x3x3 phase + in-block 5x5x5 extension ----------------
// r21-proven config + guarded 32-wide second bitonic when cnt<=32 (E[cnt]~18 -> ~always).
__launch_bounds__(256)
__global__ void k_cellknn(const float4* __restrict__ csort, const int* __restrict__ sortid,
                          const int* __restrict__ starts, const float* __restrict__ edges,
                          int* __restrict__ oidx, int* __restrict__ faillist,
                          int* __restrict__ failcnt) {
  __shared__ float4 big[CAP2];        // phase1: region 3x3x3; phase2: region 5x5x5 (22.5 KB)
  __shared__ float  sbdA[4][64];      // per-wave compact dists (1 KB)
  __shared__ int    sbiA[4][64];      // per-wave compact cand indices (1 KB)
  __shared__ int    rs[9], rl[9], pre[10];
  __shared__ int    rs2[25], rl2[25], pre2[26];
  __shared__ int    nfl[4];
  __shared__ int    flq[4][16];
  __shared__ float  flT[4][16];
  int tid = threadIdx.x, lane = tid & 63, w = tid >> 6;
  int blk = blockIdx.x;
  int b = blk >> 12;                  // G3 = 4096 cells per batch
  int c = blk & (G3-1);
  int cxi = c & 15, cyi = (c >> 4) & 15, czi = c >> 8;
  const int* st = starts + b*G3;
  float* sbd = &sbdA[w][0];
  int*   sbi = &sbiA[w][0];
  if (tid < 4) nfl[tid] = 0;
  if (tid < 9) {
    int dz = tid/3 - 1, dy = tid%3 - 1;
    int z = czi + dz, y = cyi + dy;
    if (z < 0 || z > G-1 || y < 0 || y > G-1) { rs[tid] = 0; rl[tid] = 0; }
    else {
      int xa = max(cxi-1, 0), xb = min(cxi+1, G-1);
      int c0 = (z*G + y)*G + xa;
      int s0 = st[c0], e0 = st[c0 + (xb - xa) + 1];
      rs[tid] = s0; rl[tid] = e0 - s0;
    }
  }
  __syncthreads();
  if (tid == 0) {
    int acc = 0;
#pragma unroll
    for (int i = 0; i < 9; ++i) { pre[i] = acc; acc += rl[i]; }
    pre[9] = acc;
  }
  __syncthreads();
  int total = pre[9];
  int hs = st[c], he = st[c+1];
  int nq = he - hs;
  if (nq == 0) return;                           // uniform across block
  bool bad = (total > CAPC) || (total < KK);
  if (!bad) {
    for (int i = tid; i < total; i += 256) {
      int row = 0;
#pragma unroll
      for (int rr = 1; rr < 9; ++rr) row += (i >= pre[rr]);
      int gp = rs[row] + (i - pre[row]);
      big[i] = csort[gp];
    }
  }
  __syncthreads();
  int hoff = pre[4] + (hs - rs[4]);              // home cell offset inside big[]
  // 3x3x3 region boundary edges
  float blo[3], bhi[3]; bool blok[3], bhik[3];
  int cc3[3] = {cxi, cyi, czi};
#pragma unroll
  for (int a = 0; a < 3; ++a) {
    const float* e = edges + (b*3 + a)*(G+1);
    blok[a] = cc3[a] > 0;     blo[a] = blok[a] ? e[cc3[a]-1] : 0.f;
    bhik[a] = cc3[a] < G-1;   bhi[a] = bhik[a] ? e[cc3[a]+2] : 0.f;
  }
  for (int q0 = 0; q0 < nq; q0 += 4) {
    int qi = q0 + w;
    if (qi >= nq) continue;                      // uniform per wave
    int t = hs + qi;
    if (bad) {
      if (lane == 0) { int pos = atomicAdd(failcnt, 1); faillist[pos] = t | FB_BAD; }
      continue;
    }
    float4 qv = big[hoff + qi];
    float qx = qv.x, qy = qv.y, qz = qv.z, qsq = qv.w;
    // distances into registers (8 static slots), per-lane min
    float dreg[8];
#pragma unroll
    for (int s = 0; s < 8; ++s) {
      int i = s*64 + lane;
      float d = 1e30f;
      if (i < total) {
        float4 p = big[i];
        d = qsq + p.w - 2.f*(qx*p.x + qy*p.y + qz*p.z);  // == reference formula
      }
      dreg[s] = d;
    }
    float mnl = fminf(fminf(fminf(dreg[0],dreg[1]), fminf(dreg[2],dreg[3])),
                      fminf(fminf(dreg[4],dreg[5]), fminf(dreg[6],dreg[7])));
    // T' = 16th smallest of 64 lane minima (16 distinct candidates => d16_true <= T')
    float v = mnl;
#pragma unroll
    for (int k2 = 2; k2 <= 64; k2 <<= 1) {
#pragma unroll
      for (int j = k2 >> 1; j > 0; j >>= 1) {
        float o = __shfl_xor(v, j, 64);
        bool keepmin = (((lane & j) == 0) == ((lane & k2) == 0));
        v = keepmin ? fminf(v, o) : fmaxf(v, o);
      }
    }
    float Tp = __shfl(v, 15, 64);
    // compact d <= T' into sbd/sbi
    int cnt = 0;
#pragma unroll
    for (int s = 0; s < 8; ++s) {
      bool take = dreg[s] <= Tp;
      unsigned long long bal = __ballot(take);
      int pos = cnt + __popcll(bal & ((1ull << lane) - 1ull));
      if (take && pos < 64) { sbd[pos] = dreg[s]; sbi[pos] = s*64 + lane; }
      cnt += __popcll(bal);
    }
    if (cnt > 64) {                              // ~never (E[cnt]~18): exact BAD fallback
      if (lane == 0) { int pos = atomicAdd(failcnt, 1); faillist[pos] = t | FB_BAD; }
      continue;
    }
    float dv = (lane < cnt) ? sbd[lane] : 1e30f;
    int   iv = (lane < cnt) ? sbi[lane] : 0x7fffffff;
    if (cnt <= 32) {                             // 32-wide network (15 stages, ~always)
#pragma unroll
      for (int kk = 2; kk <= 32; kk <<= 1) {
#pragma unroll
        for (int j = kk >> 1; j > 0; j >>= 1) {
          float od = __shfl_xor(dv, j, 64);
          int   oi = __shfl_xor(iv, j, 64);
          bool keepmin = (((lane & j) == 0) == ((lane & kk) == 0));
          bool less = (od < dv) || (od == dv && oi < iv);
          bool take2 = keepmin ? less : !less;
          dv = take2 ? od : dv;
          iv = take2 ? oi : iv;
        }
      }
    } else {                                     // full 64-wide (21 stages)
#pragma unroll
      for (int kk = 2; kk <= 64; kk <<= 1) {
#pragma unroll
        for (int j = kk >> 1; j > 0; j >>= 1) {
          float od = __shfl_xor(dv, j, 64);
          int   oi = __shfl_xor(iv, j, 64);
          bool keepmin = (((lane & j) == 0) == ((lane & kk) == 0));
          bool less = (od < dv) || (od == dv && oi < iv);
          bool take2 = keepmin ? less : !less;
          dv = take2 ? od : dv;
          iv = take2 ? oi : iv;
        }
      }
    }
    float d16v = __shfl(dv, 15, 64);
    int resid = iv;                              // lane r holds r-th NN cand index
    float m = 1e30f;
    if (blok[0]) m = fminf(m, qx - blo[0]);
    if (bhik[0]) m = fminf(m, bhi[0] - qx);
    if (blok[1]) m = fminf(m, qy - blo[1]);
    if (bhik[1]) m = fminf(m, bhi[1] - qy);
    if (blok[2]) m = fminf(m, qz - blo[2]);
    if (bhik[2]) m = fminf(m, bhi[2] - qz);
    bool ok = (m > 0.f) && (m*m > d16v + SLOP);
    if (ok) {
      int qn = sortid[t];
      size_t row = ((size_t)(b*NPTS + qn))*KK;
      if (lane < KK) {
        int rowi = 0;                            // reconstruct csort position
#pragma unroll
        for (int rr = 1; rr < 9; ++rr) rowi += (resid >= pre[rr]);
        int gp = rs[rowi] + (resid - pre[rowi]);
        oidx[row + lane] = sortid[gp];
      }
    } else {
      if (lane == 0) {
        int k2 = nfl[w];
        if (k2 < 16) { flq[w][k2] = t; flT[w][k2] = d16v; nfl[w] = k2 + 1; }
        else { int pos = atomicAdd(failcnt, 1); faillist[pos] = t | FB_BAD; }
      }
    }
  }
  __syncthreads();
  if (bad) return;
  if (nfl[0] + nfl[1] + nfl[2] + nfl[3] == 0) return;

  // ---- phase 2: load 5x5x5 region once, resolve failed queries in LDS ----
  if (tid < 25) {
    int dz = tid/5 - 2, dy = tid%5 - 2;
    int z = czi + dz, y = cyi + dy;
    if (z < 0 || z > G-1 || y < 0 || y > G-1) { rs2[tid] = 0; rl2[tid] = 0; }
    else {
      int xa = max(cxi-2, 0), xb = min(cxi+2, G-1);
      int c0 = (z*G + y)*G + xa;
      int s0 = st[c0], e0 = st[c0 + (xb - xa) + 1];
      rs2[tid] = s0; rl2[tid] = e0 - s0;
    }
  }
  __syncthreads();
  if (tid == 0) {
    int acc = 0;
#pragma unroll
    for (int i = 0; i < 25; ++i) { pre2[i] = acc; acc += rl2[i]; }
    pre2[25] = acc;
  }
  __syncthreads();
  int total2 = pre2[25];
  if (total2 > CAP2) {                           // ~never: dump fails as BAD
    if (lane == 0) {
      for (int k2 = 0; k2 < nfl[w]; ++k2) {
        int pos = atomicAdd(failcnt, 1); faillist[pos] = flq[w][k2] | FB_BAD;
      }
    }
    return;
  }
  for (int i = tid; i < total2; i += 256) {
    int rowi = 0;
#pragma unroll
    for (int rr = 1; rr < 25; ++rr) rowi += (i >= pre2[rr]);
    int gp = rs2[rowi] + (i - pre2[rowi]);
    big[i] = csort[gp];
  }
  __syncthreads();
  // 5x5x5 region boundary edges
  float blo2[3], bhi2[3]; bool blok2[3], bhik2[3];
#pragma unroll
  for (int a = 0; a < 3; ++a) {
    const float* e = edges + (b*3 + a)*(G+1);
    blok2[a] = cc3[a] > 1;     blo2[a] = blok2[a] ? e[cc3[a]-2] : 0.f;
    bhik2[a] = cc3[a] < G-2;   bhi2[a] = bhik2[a] ? e[cc3[a]+3] : 0.f;
  }
  for (int k2 = 0; k2 < nfl[w]; ++k2) {          // wave-serial, no barriers
    int t = flq[w][k2];
    float T0 = flT[w][k2] + TEPS;                // T0 >= true d16 (3x3x3 superset bound)
    float4 qv = csort[t];
    float qx = qv.x, qy = qv.y, qz = qv.z, qsq = qv.w;
    int cnt = 0;
    for (int base2 = 0; base2 < total2; base2 += 64) {
      int i = base2 + lane;
      bool valid = i < total2;
      float d = 1e30f;
      if (valid) {
        float4 p = big[i];
        d = qsq + p.w - 2.f*(qx*p.x + qy*p.y + qz*p.z);
      }
      bool take = valid && (d <= T0);
      unsigned long long bal = __ballot(take);
      int pos = cnt + __popcll(bal & ((1ull << lane) - 1ull));
      if (take && pos < 64) { sbd[pos] = d; sbi[pos] = i; }
      cnt += __popcll(bal);
    }
    if (cnt > 64) {                              // ~never
      if (lane == 0) { int pos = atomicAdd(failcnt, 1); faillist[pos] = t | FB_BAD; }
      continue;
    }
    float dv = (lane < cnt) ? sbd[lane] : 1e30f;
    int   iv = (lane < cnt) ? sbi[lane] : 0x7fffffff;
#pragma unroll
    for (int kk = 2; kk <= 64; kk <<= 1) {       // bitonic sort (d, idx)
#pragma unroll
      for (int j = kk >> 1; j > 0; j >>= 1) {
        float od = __shfl_xor(dv, j, 64);
        int   oi = __shfl_xor(iv, j, 64);
        bool keepmin = (((lane & j) == 0) == ((lane & kk) == 0));
        bool less = (od < dv) || (od == dv && oi < iv);
        bool take2 = keepmin ? less : !less;
        dv = take2 ? od : dv;
        iv = take2 ? oi : iv;
      }
    }
    float d16b = __shfl(dv, 15, 64);
    float m = 1e30f;
    if (blok2[0]) m = fminf(m, qx - blo2[0]);
    if (bhik2[0]) m = fminf(m, bhi2[0] - qx);
    if (blok2[1]) m = fminf(m, qy - blo2[1]);
    if (bhik2[1]) m = fminf(m, bhi2[1] - qy);
    if (blok2[2]) m = fminf(m, qz - blo2[2]);
    if (bhik2[2]) m = fminf(m, bhi2[2] - qz);
    bool ok = (m > 0.f) && (m*m > d16b + SLOP);
    int qn = sortid[t];
    size_t row = ((size_t)(b*NPTS + qn))*KK;
    if (lane < KK) {
      int rowi = 0;                              // reconstruct csort position
#pragma unroll
      for (int rr = 1; rr < 25; ++rr) rowi += (iv >= pre2[rr]);
      int gp = rs2[rowi] + (iv - pre2[rowi]);
      oidx[row + lane] = ok ? sortid[gp] : gp;   // result, or seed positions
    }
    if (!ok && lane == 0) { int pos = atomicAdd(failcnt, 1); faillist[pos] = t; }
  }
}

// ---------------- residual fallback: ONE BLOCK PER QUERY (256-thread strided scan) ----
// Straggler fix: outlier queries with huge superset ranges get 4x the lanes.
// Exact: disjoint strided partition -> per-thread top-16 -> per-wave (d,pos)
// extraction -> wave0 64-wide bitonic merge of the 4x16 winners.
__launch_bounds__(256)
__global__ void k_knn_fb(const float4* __restrict__ csort, const int* __restrict__ sortid,
                         const int* __restrict__ starts, const float* __restrict__ edges,
                         const int* __restrict__ faillist, const int* __restrict__ failcnt,
                         int* __restrict__ oidx) {
  __shared__ float sT;
  __shared__ int   slo, shi;
  __shared__ float md[64];
  __shared__ int   mp[64];
  int tid = threadIdx.x, lane = tid & 63, w = tid >> 6;
  int nf = failcnt[0];
  for (int f = blockIdx.x; f < nf; f += gridDim.x) {
    int fv = faillist[f];                        // uniform per block
    bool seeded = (fv & FB_BAD) == 0;
    int t = fv & (FB_BAD - 1);
    int b = t >> 15;
    const int* st = starts + b*G3;
    float4 qv = csort[t];
    const float qx = qv.x, qy = qv.y, qz = qv.z, qsq = qv.w;
    int qn = sortid[t];
    size_t row = ((size_t)(b*NPTS + qn))*KK;
    // wave 0 computes T + contiguous superset range, broadcasts via LDS
    if (w == 0) {
      if (seeded) {
        const float* ex = edges + (b*3+0)*(G+1);
        const float* ey = edges + (b*3+1)*(G+1);
        const float* ez = edges + (b*3+2)*(G+1);
        float sd = -1e30f;
        if (lane < KK) {
          int pos = oidx[row + lane];
          float4 p = csort[pos];
          sd = qsq + p.w - 2.f*(qx*p.x + qy*p.y + qz*p.z);
        }
        float T = sd;
#pragma unroll
        for (int m = 32; m > 0; m >>= 1) T = fmaxf(T, __shfl_xor(T, m, 64));
        T += TEPS;                               // T >= true d16 (5x5x5 superset)
        float R = sqrtf(T)*1.0001f + 1e-12f;
        bool tk = (lane < G-1) && (ex[lane+1] < qx - R);
        int xl = __popcll(__ballot(tk));
        tk = (lane >= 1 && lane <= G-1) && (ex[lane] > qx + R);
        int xh = (G-1) - __popcll(__ballot(tk));
        tk = (lane < G-1) && (ey[lane+1] < qy - R);
        int yl = __popcll(__ballot(tk));
        tk = (lane >= 1 && lane <= G-1) && (ey[lane] > qy + R);
        int yh = (G-1) - __popcll(__ballot(tk));
        tk = (lane < G-1) && (ez[lane+1] < qz - R);
        int zl = __popcll(__ballot(tk));
        tk = (lane >= 1 && lane <= G-1) && (ez[lane] > qz + R);
        int zh = (G-1) - __popcll(__ballot(tk));
        if (lane == 0) {
          sT = T;
          slo = st[(zl*G + yl)*G + xl];
          shi = st[(zh*G + yh)*G + xh + 1];
        }
      } else {
        // ~never: full-batch scan, no threshold (per-thread lists are exact)
        if (lane == 0) { sT = 1e30f; slo = b*NPTS; shi = b*NPTS + NPTS; }
      }
    }
    __syncthreads();
    float T = sT;
    int lo_pos = slo, hi_pos = shi;
    // per-thread threshold top-16 insert over 256-strided range
    float dl[KK]; int il[KK];
#pragma unroll
    for (int i = 0; i < KK; ++i) { dl[i] = 1e30f; il[i] = 0x7fffffff; }
    for (int i = lo_pos + tid; i < hi_pos; i += 256) {
      float4 p = csort[i];
      float d = qsq + p.w - 2.f*(qx*p.x + qy*p.y + qz*p.z);
      if (d <= T && d < dl[KK-1]) {              // rare insert
        float cd = d; int ci = i;
#pragma unroll
        for (int i2 = 0; i2 < KK; ++i2) {
          bool sw = cd < dl[i2];
          float td = dl[i2]; int ti = il[i2];
          dl[i2] = sw ? cd : td; il[i2] = sw ? ci : ti;
          cd = sw ? td : cd;    ci = sw ? ti : ci;
        }
      }
    }
    // per-wave exact top-16: 16 argmin rounds by (d, csort pos); winner pops
    int res = 0x7fffffff; float rd = 1e30f;
#pragma unroll
    for (int r = 0; r < KK; ++r) {
      float v = dl[0]; int pi = il[0]; int l = lane;
#pragma unroll
      for (int m = 1; m < 64; m <<= 1) {
        float ov = __shfl_xor(v, m, 64);
        int   op = __shfl_xor(pi, m, 64);
        int   ol = __shfl_xor(l, m, 64);
        bool take = (ov < v) || (ov == v && op < pi);
        v = take ? ov : v; pi = take ? op : pi; l = take ? ol : l;
      }
      if (lane == r) { res = pi; rd = v; }
      bool win = (lane == l);
#pragma unroll
      for (int i = 0; i < KK-1; ++i) {
        dl[i] = win ? dl[i+1] : dl[i];
        il[i] = win ? il[i+1] : il[i];
      }
      dl[KK-1] = win ? 1e30f : dl[KK-1];
      il[KK-1] = win ? 0x7fffffff : il[KK-1];
    }
    if (lane < KK) { md[w*KK + lane] = rd; mp[w*KK + lane] = res; }
    __syncthreads();
    // wave 0: 64-wide bitonic merge of 4x16 wave winners by (d, pos)
    if (w == 0) {
      float dv = md[lane]; int iv = mp[lane];
#pragma unroll
      for (int kk = 2; kk <= 64; kk <<= 1) {
#pragma unroll
        for (int j = kk >> 1; j > 0; j >>= 1) {
          float od = __shfl_xor(dv, j, 64);
          int   oi = __shfl_xor(iv, j, 64);
          bool keepmin = (((lane & j) == 0) == ((lane & kk) == 0));
          bool less = (od < dv) || (od == dv && oi < iv);
          bool take2 = keepmin ? less : !less;
          dv = take2 ? od : dv;
          iv = take2 ? oi : iv;
        }
      }
      if (lane < KK) oidx[row + lane] = sortid[iv];
    }
    __syncthreads();                             // md/mp/sT reuse safety for next f
  }
}

// ---------------- FUSED: mlp1 (blocks 0..63, 4 pts/thread) + lsestats (blocks 64..1087, 4 el/thread) ----
__global__ void k_stats(const float* __restrict__ features,
                        const float* __restrict__ W1, const float* __restrict__ b1,
                        const float* __restrict__ Wsc, const float* __restrict__ bsc,
                        float* __restrict__ x1, float* __restrict__ ppa,
                        const float* __restrict__ coords, const int* __restrict__ idx,
                        const float* __restrict__ Wl1, const float* __restrict__ bl1,
                        const float* __restrict__ Wl2, const float* __restrict__ bl2,
                        float* __restrict__ ppb) {
  int tid = threadIdx.x;
  if (blockIdx.x < 64) {
    // ---- mlp1 (leaky 0.2) + shortcut BN partial sums; 4 points/thread ----
    __shared__ float sW1[128], sb1[16], sWsc[512], sbsc[64];
    __shared__ float part[128];
    if (tid < 128) { sW1[tid] = W1[tid]; part[tid] = 0.f; }
    if (tid < 16)  sb1[tid] = b1[tid];
    if (tid < 64)  sbsc[tid] = bsc[tid];
    for (int i = tid; i < 512; i += 256) sWsc[i] = Wsc[i];
    __syncthreads();
    int q0 = blockIdx.x*1024;
    float f[4][8];
#pragma unroll
    for (int p = 0; p < 4; ++p) {
      int q = q0 + p*256 + tid;
      int b = q >> 15, n = q & (NPTS-1);
#pragma unroll
      for (int c = 0; c < 8; ++c) f[p][c] = features[((size_t)b*8 + c)*NPTS + n];
#pragma unroll
      for (int co = 0; co < 16; ++co) {
        float a = sb1[co];
#pragma unroll
        for (int c = 0; c < 8; ++c) a += f[p][c]*sW1[co*8+c];
        x1[(size_t)q*16 + co] = a > 0.f ? a : 0.2f*a;
      }
    }
    int lane = tid & 63;
#pragma unroll
    for (int co = 0; co < 64; ++co) {
      float s = 0.f, ss = 0.f;
#pragma unroll
      for (int p = 0; p < 4; ++p) {
        float a = sbsc[co];
#pragma unroll
        for (int c = 0; c < 8; ++c) a += f[p][c]*sWsc[co*8+c];
        s += a; ss += a*a;
      }
      s = wred64(s); ss = wred64(ss);
      if (lane == 0) { atomicAdd(&part[co], s); atomicAdd(&part[64+co], ss); }
    }
    __syncthreads();
    if (tid < 128) ppa[(size_t)blockIdx.x*128 + tid] = part[tid];
  } else {
    // ---- BN partial sums for BOTH LSE geometric encodings; 4 elements/thread ----
    __shared__ float sW1[160], sb1[16], sW2[160], sb2[16];
    __shared__ float red[4][64];
    int blk = blockIdx.x - 64;          // 0..1023
    for (int i = tid; i < 160; i += 256) { sW1[i] = Wl1[i]; sW2[i] = Wl2[i]; }
    if (tid < 16) { sb1[tid] = bl1[tid]; sb2[tid] = bl2[tid]; }
    __syncthreads();
    float cat[4][10];
#pragma unroll
    for (int p = 0; p < 4; ++p) {
      int t = blk*1024 + p*256 + tid;   // (b,n,k) flat
      int q = t >> 4;
      int b = q >> 15, n = q & (NPTS-1);
      const float* cb = coords + (size_t)b*(NPTS*3);
      int j = idx[t];
      float cx = cb[n*3], cy = cb[n*3+1], cz = cb[n*3+2];
      float px = cb[j*3], py = cb[j*3+1], pz = cb[j*3+2];
      cat[p][0]=cx; cat[p][1]=cy; cat[p][2]=cz;
      cat[p][3]=px; cat[p][4]=py; cat[p][5]=pz;
      cat[p][6]=cx-px; cat[p][7]=cy-py; cat[p][8]=cz-pz; cat[p][9]=1.f;
    }
    int wave = tid >> 6, lane = tid & 63;
#pragma unroll
    for (int co = 0; co < 16; ++co) {
      float s1 = 0.f, q1 = 0.f, s2 = 0.f, q2 = 0.f;
#pragma unroll
      for (int p = 0; p < 4; ++p) {
        float a1 = sb1[co], a2 = sb2[co];
#pragma unroll
        for (int d0 = 0; d0 < 10; ++d0) { a1 += cat[p][d0]*sW1[co*10+d0]; a2 += cat[p][d0]*sW2[co*10+d0]; }
        s1 += a1; q1 += a1*a1; s2 += a2; q2 += a2*a2;
      }
      s1 = wred64(s1); q1 = wred64(q1);
      s2 = wred64(s2); q2 = wred64(q2);
      if (lane == 0) { red[wave][co]=s1; red[wave][16+co]=q1; red[wave][32+co]=s2; red[wave][48+co]=q2; }
    }
    __syncthreads();
    if (tid < 64) {
      float v = red[0][tid] + red[1][tid] + red[2][tid] + red[3][tid];
      ppb[(size_t)blk*64 + tid] = v;    // layout matches stats[S_L1..S_L2+32)
    }
  }
}

// ---------------- LSE1 + attentive pooling 1 (BN-L1 inline; softmax w/o max-sub) ----------------
__launch_bounds__(256)
__global__ void k_att1(const float* __restrict__ coords, const int* __restrict__ idx,
                       const float* __restrict__ x1ws,
                       const float* __restrict__ Wl1, const float* __restrict__ bl1,
                       const float* __restrict__ Ws1, const float* __restrict__ Wp1,
                       const float* __restrict__ bp1, const float* __restrict__ stats,
                       const float* __restrict__ gl1, const float* __restrict__ bl1b,
                       float* __restrict__ t2, float* __restrict__ ppart) {
  __shared__ float saL[16], scL[16];
  __shared__ float sWl[160], sbl[16];
  __shared__ float sWs[1024];
  __shared__ float sWpT[512], sbp[16];
  __shared__ float lsum[16], lsq[16];
  int tid = threadIdx.x;
  if (tid < 16) {
    float m = stats[S_L1 + tid]*INVQK;
    float v = stats[S_L1 + 16 + tid]*INVQK - m*m;
    float a = gl1[tid]*rsqrtf(v + EPS);
    saL[tid] = a; scL[tid] = bl1b[tid] - m*a;
  }
  __syncthreads();
  for (int i = tid; i < 160; i += 256) { int c = i/10; sWl[i] = Wl1[i]*saL[c]; }
  if (tid < 16) sbl[tid] = bl1[tid]*saL[tid] + scL[tid];
  for (int i = tid; i < 1024; i += 256) sWs[i] = Ws1[i];
  for (int i = tid; i < 512; i += 256) { int co = i >> 4, cp = i & 15; sWpT[i] = Wp1[cp*32 + co]; }
  if (tid < 16) { sbp[tid] = bp1[tid]; lsum[tid] = 0.f; lsq[tid] = 0.f; }
  __syncthreads();
  int gp = blockIdx.x*16 + (tid >> 4);
  int k  = tid & 15;
  int b = gp >> 15, n = gp & (NPTS-1);
  const float* cb = coords + (size_t)b*(NPTS*3);
  int j = idx[(size_t)gp*KK + k];
  float cx = cb[n*3], cy = cb[n*3+1], cz = cb[n*3+2];
  float px = cb[j*3], py = cb[j*3+1], pz = cb[j*3+2];
  float cat[10] = {cx,cy,cz,px,py,pz,cx-px,cy-py,cz-pz,1.f};
  float x[32];
#pragma unroll
  for (int co = 0; co < 16; ++co) {
    float a = sbl[co];
#pragma unroll
    for (int d0 = 0; d0 < 10; ++d0) a += cat[d0]*sWl[co*10+d0];
    x[co] = a > 0.f ? a : 0.f;
  }
  {
    const float4* xp = (const float4*)(x1ws + (size_t)gp*16);
    float4 u0 = xp[0], u1 = xp[1], u2 = xp[2], u3 = xp[3];
    x[16]=u0.x; x[17]=u0.y; x[18]=u0.z; x[19]=u0.w;
    x[20]=u1.x; x[21]=u1.y; x[22]=u1.z; x[23]=u1.w;
    x[24]=u2.x; x[25]=u2.y; x[26]=u2.z; x[27]=u2.w;
    x[28]=u3.x; x[29]=u3.y; x[30]=u3.z; x[31]=u3.w;
  }
  float tacc = sbp[k];
#pragma unroll
  for (int co = 0; co < 32; ++co) {
    float s = 0.f;
#pragma unroll
    for (int ci = 0; ci < 32; ++ci) s += x[ci]*sWs[co*32+ci];
    float e = __expf(s);                 // scores bounded: softmax w/o max-sub (identical ratio)
    float se = e;
#pragma unroll
    for (int msk = 8; msk > 0; msk >>= 1) se += __shfl_xor(se, msk, 16);
    float w = e/se;
    float fv = w*x[co];
#pragma unroll
    for (int msk = 8; msk > 0; msk >>= 1) fv += __shfl_xor(fv, msk, 16);
    tacc += fv*sWpT[co*16+k];
  }
  t2[(size_t)gp*16 + k] = tacc;
  atomicAdd(&lsum[k], tacc);
  atomicAdd(&lsq[k], tacc*tacc);
  __syncthreads();
  if (tid < 16) {
    ppart[(size_t)blockIdx.x*32 + tid]      = lsum[tid];
    ppart[(size_t)blockIdx.x*32 + 16 + tid] = lsq[tid];
  }
}

// ---------------- LSE2 + attentive pooling 2 (BN-L2 + BN-P1 inline; softmax w/o max-sub) ----
__launch_bounds__(256)
__global__ void k_att2(const float* __restrict__ coords, const int* __restrict__ idx,
                       const float* __restrict__ t2ws,
                       const float* __restrict__ Wl2, const float* __restrict__ bl2,
                       const float* __restrict__ Ws2, const float* __restrict__ Wp2,
                       const float* __restrict__ bp2, const float* __restrict__ stats,
                       const float* __restrict__ gl2, const float* __restrict__ bl2b,
                       const float* __restrict__ gp1, const float* __restrict__ bp1b,
                       float* __restrict__ t4, float* __restrict__ ppart) {
  __shared__ float saL[16], scL[16];
  __shared__ float sWl[160], sbl[16];
  __shared__ float sWs[1024];
  __shared__ float sWpT[1024], sbp[32];
  __shared__ float sa1[16], sc1[16];
  __shared__ float lsum[32], lsq[32];
  int tid = threadIdx.x;
  if (tid < 16) {
    float m = stats[S_L2 + tid]*INVQK;
    float v = stats[S_L2 + 16 + tid]*INVQK - m*m;
    float a = gl2[tid]*rsqrtf(v + EPS);
    saL[tid] = a; scL[tid] = bl2b[tid] - m*a;
    float m1 = stats[S_P1 + tid]*INVN;
    float v1 = stats[S_P1 + 16 + tid]*INVN - m1*m1;
    float a1 = gp1[tid]*rsqrtf(v1 + EPS);
    sa1[tid] = a1; sc1[tid] = bp1b[tid] - m1*a1;
  }
  __syncthreads();
  for (int i = tid; i < 160; i += 256) { int c = i/10; sWl[i] = Wl2[i]*saL[c]; }
  if (tid < 16) sbl[tid] = bl2[tid]*saL[tid] + scL[tid];
  for (int i = tid; i < 1024; i += 256) {
    sWs[i] = Ws2[i];
    int co = i >> 5, cp = i & 31; sWpT[i] = Wp2[cp*32 + co];
  }
  if (tid < 32) { sbp[tid] = bp2[tid]; lsum[tid]=0.f; lsq[tid]=0.f; }
  __syncthreads();
  int gp = blockIdx.x*16 + (tid >> 4);
  int k  = tid & 15;
  int b = gp >> 15, n = gp & (NPTS-1);
  const float* cb = coords + (size_t)b*(NPTS*3);
  int j = idx[(size_t)gp*KK + k];
  float cx = cb[n*3], cy = cb[n*3+1], cz = cb[n*3+2];
  float px = cb[j*3], py = cb[j*3+1], pz = cb[j*3+2];
  float cat[10] = {cx,cy,cz,px,py,pz,cx-px,cy-py,cz-pz,1.f};
  float x[32];
#pragma unroll
  for (int co = 0; co < 16; ++co) {
    float a = sbl[co];
#pragma unroll
    for (int d0 = 0; d0 < 10; ++d0) a += cat[d0]*sWl[co*10+d0];
    x[co] = a > 0.f ? a : 0.f;
  }
  {
    const float4* xp = (const float4*)(t2ws + (size_t)gp*16);
    float4 u0 = xp[0], u1 = xp[1], u2 = xp[2], u3 = xp[3];
    float xv[16] = {u0.x,u0.y,u0.z,u0.w, u1.x,u1.y,u1.z,u1.w,
                    u2.x,u2.y,u2.z,u2.w, u3.x,u3.y,u3.z,u3.w};
#pragma unroll
    for (int c = 0; c < 16; ++c) {
      float v = xv[c]*sa1[c] + sc1[c];
      x[16+c] = v > 0.f ? v : 0.f;
    }
  }
  float tacc0 = sbp[k], tacc1 = sbp[k+16];
#pragma unroll
  for (int co = 0; co < 32; ++co) {
    float s = 0.f;
#pragma unroll
    for (int ci = 0; ci < 32; ++ci) s += x[ci]*sWs[co*32+ci];
    float e = __expf(s);                 // scores bounded: softmax w/o max-sub (identical ratio)
    float se = e;
#pragma unroll
    for (int msk = 8; msk > 0; msk >>= 1) se += __shfl_xor(se, msk, 16);
    float w = e/se;
    float fv = w*x[co];
#pragma unroll
    for (int msk = 8; msk > 0; msk >>= 1) fv += __shfl_xor(fv, msk, 16);
    tacc0 += fv*sWpT[co*32+k];
    tacc1 += fv*sWpT[co*32+k+16];
  }
  t4[(size_t)gp*32 + k]      = tacc0;
  t4[(size_t)gp*32 + k + 16] = tacc1;
  atomicAdd(&lsum[k], tacc0);      atomicAdd(&lsq[k], tacc0*tacc0);
  atomicAdd(&lsum[k+16], tacc1);   atomicAdd(&lsq[k+16], tacc1*tacc1);
  __syncthreads();
  if (tid < 32) {
    ppart[(size_t)blockIdx.x*64 + tid]      = lsum[tid];
    ppart[(size_t)blockIdx.x*64 + 32 + tid] = lsq[tid];
  }
}

// ---------------- final: mlp2 + BN'd shortcut + leaky 0.01 (BN-SC + BN-P2 inline) ----------------
__global__ void k_final(const float* __restrict__ t4ws, const float* __restrict__ features,
                        const float* __restrict__ W2, const float* __restrict__ b2,
                        const float* __restrict__ Wsc, const float* __restrict__ bsc,
                        const float* __restrict__ stats,
                        const float* __restrict__ gsc, const float* __restrict__ bscb,
                        const float* __restrict__ gp2, const float* __restrict__ bp2b,
                        float* __restrict__ out) {
  __shared__ float saS[64], scS[64];
  __shared__ float sW2[2048], sb2[64], sWscF[512], sbscF[64], sa[32], scc[32];
  int tid = threadIdx.x;
  if (tid < 64) {
    float m = stats[S_SC + tid]*INVN;
    float v = stats[S_SC + 64 + tid]*INVN - m*m;
    float a = gsc[tid]*rsqrtf(v + EPS);
    saS[tid] = a; scS[tid] = bscb[tid] - m*a;
  }
  if (tid < 32) {
    float m = stats[S_P2 + tid]*INVN;
    float v = stats[S_P2 + 32 + tid]*INVN - m*m;
    float a = gp2[tid]*rsqrtf(v + EPS);
    sa[tid] = a; scc[tid] = bp2b[tid] - m*a;
  }
  __syncthreads();
  for (int i = tid; i < 2048; i += 256) sW2[i] = W2[i];
  if (tid < 64) sb2[tid] = b2[tid];
  for (int i = tid; i < 512; i += 256) { int c2 = i >> 3; sWscF[i] = Wsc[i]*saS[c2]; }
  if (tid < 64) sbscF[tid] = bsc[tid]*saS[tid] + scS[tid];
  __syncthreads();
  int q = blockIdx.x*256 + tid;
  int b = q >> 15, n = q & (NPTS-1);
  float x3[32];
  const float4* tp = (const float4*)(t4ws + (size_t)q*32);
#pragma unroll
  for (int i = 0; i < 8; ++i) {
    float4 u = tp[i];
    float v0 = u.x*sa[4*i+0] + scc[4*i+0];
    float v1 = u.y*sa[4*i+1] + scc[4*i+1];
    float v2 = u.z*sa[4*i+2] + scc[4*i+2];
    float v3 = u.w*sa[4*i+3] + scc[4*i+3];
    x3[4*i+0] = v0 > 0.f ? v0 : 0.f;
    x3[4*i+1] = v1 > 0.f ? v1 : 0.f;
    x3[4*i+2] = v2 > 0.f ? v2 : 0.f;
    x3[4*i+3] = v3 > 0.f ? v3 : 0.f;
  }
  float f[8];
#pragma unroll
  for (int c = 0; c < 8; ++c) f[c] = features[((size_t)b*8+c)*NPTS + n];
  for (int c2 = 0; c2 < 64; ++c2) {
    float acc = sb2[c2];
#pragma unroll
    for (int co = 0; co < 32; ++co) acc += x3[co]*sW2[c2*32+co];
    float sv = sbscF[c2];
#pragma unroll
    for (int c = 0; c < 8; ++c) sv += f[c]*sWscF[c2*8+c];
    float o = acc + sv;
    out[((size_t)b*64 + c2)*NPTS + n] = o > 0.f ? o : 0.01f*o;
  }
}

extern "C" void kernel_launch(void* const* d_in, const int* in_sizes, int n_in,
                              void* d_out, int out_size, void* d_ws, size_t ws_size,
                              hipStream_t stream) {
  const float* coords   = (const float*)d_in[0];
  const float* features = (const float*)d_in[1];
  const float* W1  = (const float*)d_in[2];
  const float* b1  = (const float*)d_in[3];
  const float* Wl1 = (const float*)d_in[4];
  const float* bl1 = (const float*)d_in[5];
  const float* gl1 = (const float*)d_in[6];
  const float* bl1b= (const float*)d_in[7];
  const float* Ws1 = (const float*)d_in[8];
  const float* Wp1 = (const float*)d_in[9];
  const float* bp1 = (const float*)d_in[10];
  const float* gp1 = (const float*)d_in[11];
  const float* bp1b= (const float*)d_in[12];
  const float* Wl2 = (const float*)d_in[13];
  const float* bl2 = (const float*)d_in[14];
  const float* gl2 = (const float*)d_in[15];
  const float* bl2b= (const float*)d_in[16];
  const float* Ws2 = (const float*)d_in[17];
  const float* Wp2 = (const float*)d_in[18];
  const float* bp2 = (const float*)d_in[19];
  const float* gp2 = (const float*)d_in[20];
  const float* bp2b= (const float*)d_in[21];
  const float* W2  = (const float*)d_in[22];
  const float* b2  = (const float*)d_in[23];
  const float* Wsc = (const float*)d_in[24];
  const float* bsc = (const float*)d_in[25];
  const float* gsc = (const float*)d_in[26];
  const float* bscb= (const float*)d_in[27];

  float* wsF  = (float*)d_ws;
  int*   wsI  = (int*)d_ws;
  int*   idxp = wsI;
  float* x1p  = wsF + WS_X1;
  float* t2p  = wsF + WS_T2;
  float* t4p  = wsF + WS_T4;
  float* stat = wsF + WS_STAT;
  int*   gcnt = wsI + WS_GCNT;
  int*   gsta = wsI + WS_GSTART;
  int*   gcel = wsI + WS_CELLID;
  int*   sid  = wsI + WS_SORTID;
  float4* csrt = (float4*)(wsF + WS_CSORT);
  unsigned int* bbox = (unsigned int*)(wsI + WS_BBOX);
  int*   fcnt = wsI + WS_BBOX + 12;       // within bbox's 16-slot region
  int*   flist= wsI + WS_FAIL;            // aliases cellid (dead after scatter)
  int*   hist = wsI + WS_HIST;
  int*   strt = wsI + WS_STARTS;          // aliases hist (dead after k_edges)
  float* edge = wsF + WS_EDGE;
  float* prt  = wsF + WS_PART;            // lsestats/att partials alias csort (dead after k_knn_fb)
  float* prtA = wsF + WS_PARTA;           // mlp1 partials alias t2 (dead until k_att1)
  float* outp = (float*)d_out;

  hipLaunchKernelGGL(k_zero_all, dim3(48), dim3(256), 0, stream, stat, gcnt, hist, bbox, fcnt);
  hipLaunchKernelGGL(k_bbox,    dim3(NQ/256), dim3(256), 0, stream, coords, bbox);
  hipLaunchKernelGGL(k_hist,    dim3(NQ/256), dim3(256), 0, stream, coords, bbox, hist);
  hipLaunchKernelGGL(k_edges,   dim3(6), dim3(256), 0, stream, hist, bbox, edge);
  hipLaunchKernelGGL(k_bin,     dim3(NQ/256), dim3(256), 0, stream, coords, edge, gcel, gcnt);
  hipLaunchKernelGGL(k_alloc,   dim3(1), dim3(1024), 0, stream, gcnt, gsta, strt);
  hipLaunchKernelGGL(k_scatter, dim3(NQ/256), dim3(256), 0, stream, coords, gcel, gsta, csrt, sid);
  hipLaunchKernelGGL(k_cellknn, dim3(2*G3), dim3(256), 0, stream,
                     csrt, sid, strt, edge, idxp, flist, fcnt);
  hipLaunchKernelGGL(k_knn_fb,  dim3(2048), dim3(256), 0, stream,
                     csrt, sid, strt, edge, flist, fcnt, idxp);
  hipLaunchKernelGGL(k_stats, dim3(64 + (NQ*KK)/1024), dim3(256), 0, stream,
                     features, W1, b1, Wsc, bsc, x1p, prtA,
                     coords, idxp, Wl1, bl1, Wl2, bl2, prt);
  hipLaunchKernelGGL(k_pred2, dim3(192), dim3(256), 0, stream, prtA, prt, stat);
  hipLaunchKernelGGL(k_att1, dim3(NQ/16), dim3(256), 0, stream,
                     coords, idxp, x1p, Wl1, bl1, Ws1, Wp1, bp1, stat, gl1, bl1b, t2p, prt);
  hipLaunchKernelGGL(k_pred, dim3(32), dim3(256), 0, stream, prt, NQ/16, 32, stat, S_P1);
  hipLaunchKernelGGL(k_att2, dim3(NQ/16), dim3(256), 0, stream,
                     coords, idxp, t2p, Wl2, bl2, Ws2, Wp2, bp2, stat,
                     gl2, bl2b, gp1, bp1b, t4p, prt);
  hipLaunchKernelGGL(k_pred, dim3(64), dim3(256), 0, stream, prt, NQ/16, 64, stat, S_P2);
  hipLaunchKernelGGL(k_final, dim3(NQ/256), dim3(256), 0, stream,
                     t4p, features, W2, b2, Wsc, bsc, stat, gsc, bscb, gp2, bp2b, outp);
}

// Round 27
// 661.499 us; speedup vs baseline: 1.2964x; 1.0157x over previous
//
#include <hip/hip_runtime.h>
#include <math.h>

#define NPTS  32768
#define NB    2
#define NQ    (NB*NPTS)
#define KK    16
#define EPS   1e-6f
#define G     16
#define G3    (G*G*G)
#define HB    2048
#define SLOP  0.05f
#define TEPS  1e-3f
#define CAPC  512
#define CAP2  1408
#define INVQK (1.f/(float)((size_t)NQ*KK))
#define INVN  (1.f/(float)NQ)

// stats element offsets
#define S_L1 0
#define S_L2 32
#define S_P1 64
#define S_P2 96
#define S_SC 160

// workspace element offsets (4-byte units)
#define WS_X1     (NQ*16)
#define WS_T2     (NQ*32)
#define WS_T4     (NQ*48)
#define WS_STAT   (NQ*80)
#define WS_COEF   (WS_STAT + 512)
#define WS_GCNT   (WS_STAT + 1024)
#define WS_GSTART (WS_GCNT + 2*G3)
#define WS_CELLID (WS_GSTART + 2*G3)
#define WS_SORTID (WS_CELLID + NQ)
#define WS_CSORT  (WS_SORTID + NQ)      /* float4 x NQ (16B-aligned) */
#define WS_BBOX   (WS_CSORT + 4*NQ)
#define WS_HIST   (WS_BBOX + 16)
#define WS_EDGE   (WS_HIST + 6*HB)
#define WS_STARTS WS_HIST               /* starts aliases hist (dead after k_edges) */
#define WS_FAIL   WS_CELLID             /* fail list aliases cellid (dead after scatter) */
#define WS_PART   WS_CSORT              /* lsestats/att partials alias csort (dead after k_knn_fb) */
#define WS_PARTA  WS_T2                 /* mlp1 partials alias t2 (dead until k_att1) */

#define FB_BAD    (1 << 30)             /* faillist tag: bad -> unseeded full-batch scan */

__device__ __forceinline__ float wred64(float v) {
#pragma unroll
  for (int m = 32; m > 0; m >>= 1) v += __shfl_xor(v, m, 64);
  return v;
}

// order-preserving float <-> uint encoding for atomic min/max
__device__ __forceinline__ unsigned int encf(float f) {
  unsigned int u = __float_as_uint(f);
  return (u & 0x80000000u) ? ~u : (u | 0x80000000u);
}
__device__ __forceinline__ float decf(unsigned int u) {
  return (u & 0x80000000u) ? __uint_as_float(u & 0x7fffffffu) : __uint_as_float(~u);
}

// 4-step binary search over G=16 quantile edges; e[0] <= x guaranteed
__device__ __forceinline__ int bs16(const float* e, float x) {
  int c = (x >= e[8]) ? 8 : 0;
  c += (x >= e[c+4]) ? 4 : 0;
  c += (x >= e[c+2]) ? 2 : 0;
  c += (x >= e[c+1]) ? 1 : 0;
  return c;
}

// ---------------- zero stats + counters + hist + bbox + failcnt ----------------
__global__ void k_zero_all(float* __restrict__ stats, int* __restrict__ gcnt,
                           int* __restrict__ hist, unsigned int* __restrict__ bbox,
                           int* __restrict__ failcnt) {
  int i = blockIdx.x*256 + threadIdx.x;       // grid covers 12288
  if (i < 2*G3) gcnt[i] = 0;
  if (i < 6*HB) hist[i] = 0;
  if (i < 320)  stats[i] = 0.f;
  if (i < 12)   bbox[i] = ((i % 6) < 3) ? 0xFFFFFFFFu : 0u;
  if (i == 0)   failcnt[0] = 0;
}

// ---------------- deterministic partial reduction: stats[soff+c] = sum_blk part[blk][c] ----
__global__ void k_pred(const float* __restrict__ part, int nblk, int nch,
                       float* __restrict__ stats, int soff) {
  __shared__ float red[256];
  int c = blockIdx.x, tid = threadIdx.x;
  float s = 0.f;
  for (int i = tid; i < nblk; i += 256) s += part[(size_t)i*nch + c];
  red[tid] = s;
  __syncthreads();
  for (int off2 = 128; off2 > 0; off2 >>= 1) {
    if (tid < off2) red[tid] += red[tid + off2];
    __syncthreads();
  }
  if (tid == 0) stats[soff + c] = red[0];
}

// ---------------- fused dual partial reduction: SC (128ch from pa) + L1/L2 (64ch from pb) ----
__global__ void k_pred2(const float* __restrict__ pa, const float* __restrict__ pb,
                        float* __restrict__ stats) {
  __shared__ float red[256];
  int cb = blockIdx.x, tid = threadIdx.x;
  const float* part; int nblk, nch, soff, c;
  if (cb < 128) { part = pa; nblk = 64;   nch = 128; soff = S_SC; c = cb; }
  else          { part = pb; nblk = 1024; nch = 64;  soff = S_L1; c = cb - 128; }
  float s = 0.f;
  for (int i = tid; i < nblk; i += 256) s += part[(size_t)i*nch + c];
  red[tid] = s;
  __syncthreads();
  for (int off2 = 128; off2 > 0; off2 >>= 1) {
    if (tid < off2) red[tid] += red[tid + off2];
    __syncthreads();
  }
  if (tid == 0) stats[soff + c] = red[0];
}

// ---------------- per-batch exact bounding box ----------------
__global__ void k_bbox(const float* __restrict__ coords, unsigned int* __restrict__ bbox) {
  __shared__ unsigned int rmn[3][4], rmx[3][4];
  int tid = threadIdx.x;
  int t = blockIdx.x*256 + tid;
  int b = t >> 15, n = t & (NPTS-1);
  const float* cb = coords + (size_t)b*(NPTS*3);
  unsigned int e[3] = { encf(cb[n*3+0]), encf(cb[n*3+1]), encf(cb[n*3+2]) };
  unsigned int mn[3] = { e[0], e[1], e[2] }, mx[3] = { e[0], e[1], e[2] };
#pragma unroll
  for (int s = 32; s > 0; s >>= 1) {
#pragma unroll
    for (int a = 0; a < 3; ++a) {
      unsigned int o1 = (unsigned int)__shfl_xor((int)mn[a], s, 64);
      unsigned int o2 = (unsigned int)__shfl_xor((int)mx[a], s, 64);
      mn[a] = mn[a] < o1 ? mn[a] : o1;
      mx[a] = mx[a] > o2 ? mx[a] : o2;
    }
  }
  int wave = tid >> 6, lane = tid & 63;
  if (lane == 0) {
#pragma unroll
    for (int a = 0; a < 3; ++a) { rmn[a][wave] = mn[a]; rmx[a][wave] = mx[a]; }
  }
  __syncthreads();
  if (tid < 3) {
    unsigned int a0 = min(min(rmn[tid][0], rmn[tid][1]), min(rmn[tid][2], rmn[tid][3]));
    unsigned int A0 = max(max(rmx[tid][0], rmx[tid][1]), max(rmx[tid][2], rmx[tid][3]));
    atomicMin(&bbox[b*6 + tid], a0);
    atomicMax(&bbox[b*6 + 3 + tid], A0);
  }
}

// ---------------- per-axis fine histogram ----------------
__global__ void k_hist(const float* __restrict__ coords, const unsigned int* __restrict__ bbox,
                       int* __restrict__ hist) {
  int t = blockIdx.x*256 + threadIdx.x;
  int b = t >> 15, n = t & (NPTS-1);
  const float* cb = coords + (size_t)b*(NPTS*3);
#pragma unroll
  for (int a = 0; a < 3; ++a) {
    float l = decf(bbox[b*6+a]), h = decf(bbox[b*6+3+a]);
    float ex = (h - l)*(1.f + 4e-7f) + 1e-30f;
    float inv = (float)HB/ex;
    int bin = (int)((cb[n*3+a] - l)*inv);
    bin = min(HB-1, max(0, bin));
    atomicAdd(&hist[(b*3+a)*HB + bin], 1);
  }
}

// ---------------- equal-frequency edges from histogram cdf ----------------
__global__ void k_edges(const int* __restrict__ hist, const unsigned int* __restrict__ bbox,
                        float* __restrict__ edges) {
  __shared__ int part[256];
  int p = blockIdx.x;                 // pair = b*3 + a, 6 blocks
  int b = p/3, a = p - b*3;
  int tid = threadIdx.x;
  const int* h = hist + p*HB;
  int v[8]; int s = 0;
#pragma unroll
  for (int i = 0; i < 8; ++i) { v[i] = h[tid*8 + i]; s += v[i]; }
  part[tid] = s;
  __syncthreads();
  for (int off = 1; off < 256; off <<= 1) {
    int x = part[tid];
    int y = (tid >= off) ? part[tid-off] : 0;
    __syncthreads();
    part[tid] = x + y;
    __syncthreads();
  }
  float l = decf(bbox[b*6+a]), hi = decf(bbox[b*6+3+a]);
  float ex = (hi - l)*(1.f + 4e-7f) + 1e-30f;
  float bw = ex*(1.f/(float)HB);
  int c = part[tid] - s;              // exclusive base
#pragma unroll
  for (int i = 0; i < 8; ++i) {
    int lo_c = c; c += v[i];
#pragma unroll
    for (int g = 1; g < G; ++g) {
      int tq = g*(NPTS/G);
      if (lo_c < tq && c >= tq) edges[p*(G+1) + g] = l + bw*(float)(tid*8 + i + 1);
    }
  }
  if (tid == 0) { edges[p*(G+1)] = l; edges[p*(G+1) + G] = hi + fabsf(hi)*1e-6f + 1e-20f; }
}

// ---------------- bin points into quantile cells ----------------
__global__ void k_bin(const float* __restrict__ coords, const float* __restrict__ edges,
                      int* __restrict__ cellid, int* __restrict__ gcnt) {
  __shared__ float se[3][G+1];
  int tid = threadIdx.x;
  int t = blockIdx.x*256 + tid;
  int b = t >> 15, n = t & (NPTS-1);
  if (tid < 3*(G+1)) se[tid/(G+1)][tid%(G+1)] = edges[b*3*(G+1) + tid];
  __syncthreads();
  const float* cb = coords + (size_t)b*(NPTS*3);
  int c0 = bs16(se[0], cb[n*3+0]);
  int c1 = bs16(se[1], cb[n*3+1]);
  int c2 = bs16(se[2], cb[n*3+2]);
  int cid = b*G3 + (c2*G + c1)*G + c0;
  cellid[t] = cid;
  atomicAdd(&gcnt[cid], 1);
}

// ---------------- deterministic global scan over all 8192 cells ----------------
__global__ void k_alloc(const int* __restrict__ gcnt, int* __restrict__ gstart,
                        int* __restrict__ starts) {
  __shared__ int part[1024];
  int tid = threadIdx.x;
  int v[8]; int s = 0;
#pragma unroll
  for (int i = 0; i < 8; ++i) { v[i] = gcnt[tid*8 + i]; s += v[i]; }
  part[tid] = s;
  __syncthreads();
  for (int off = 1; off < 1024; off <<= 1) {
    int x = part[tid];
    int y = (tid >= off) ? part[tid-off] : 0;
    __syncthreads();
    part[tid] = x + y;
    __syncthreads();
  }
  int base = part[tid] - s;
#pragma unroll
  for (int i = 0; i < 8; ++i) { gstart[tid*8 + i] = base; starts[tid*8 + i] = base; base += v[i]; }
  if (tid == 1023) starts[2*G3] = NQ;
}

// ---------------- scatter: packed float4 + original id, cell-sorted ----------------
__global__ void k_scatter(const float* __restrict__ coords, const int* __restrict__ cellid,
                          int* __restrict__ gstart, float4* __restrict__ csort,
                          int* __restrict__ sortid) {
  int t = blockIdx.x*256 + threadIdx.x;
  int b = t >> 15, n = t & (NPTS-1);
  const float* cb = coords + (size_t)b*(NPTS*3);
  int cid = cellid[t];
  int pos = atomicAdd(&gstart[cid], 1);
  float x = cb[n*3+0], y = cb[n*3+1], z = cb[n*3+2];
  csort[pos] = make_float4(x, y, z, x*x + y*y + z*z);
  sortid[pos] = n;
}

// ---------------- cell-centric KNN: 3x3x3 phase + in-block 5x5x5 extension ----------------
// r25-proven config + wave-uniform slot skip (total~216 of 512 capacity -> skip ~4.6/8
// slots entirely) + pair-min 32-wide Tp network (16 stages vs 21; Tp still >= d16_true).
__launch_bounds__(256)
__global__ void k_cellknn(const float4* __restrict__ csort, const int* __restrict__ sortid,
                          const int* __restrict__ starts, const float* __restrict__ edges,
                          int* __restrict__ oidx, int* __restrict__ faillist,
                          int* __restrict__ failcnt) {
  __shared__ float4 big[CAP2];        // phase1: region 3x3x3; phase2: region 5x5x5 (22.5 KB)
  __shared__ float  sbdA[4][64];      // per-wave compact dists (1 KB)
  __shared__ int    sbiA[4][64];      // per-wave compact cand indices (1 KB)
  __shared__ int    rs[9], rl[9], pre[10];
  __shared__ int    rs2[25], rl2[25], pre2[26];
  __shared__ int    nfl[4];
  __shared__ int    flq[4][16];
  __shared__ float  flT[4][16];
  int tid = threadIdx.x, lane = tid & 63, w = tid >> 6;
  int blk = blockIdx.x;
  int b = blk >> 12;                  // G3 = 4096 cells per batch
  int c = blk & (G3-1);
  int cxi = c & 15, cyi = (c >> 4) & 15, czi = c >> 8;
  const int* st = starts + b*G3;
  float* sbd = &sbdA[w][0];
  int*   sbi = &sbiA[w][0];
  if (tid < 4) nfl[tid] = 0;
  if (tid < 9) {
    int dz = tid/3 - 1, dy = tid%3 - 1;
    int z = czi + dz, y = cyi + dy;
    if (z < 0 || z > G-1 || y < 0 || y > G-1) { rs[tid] = 0; rl[tid] = 0; }
    else {
      int xa = max(cxi-1, 0), xb = min(cxi+1, G-1);
      int c0 = (z*G + y)*G + xa;
      int s0 = st[c0], e0 = st[c0 + (xb - xa) + 1];
      rs[tid] = s0; rl[tid] = e0 - s0;
    }
  }
  __syncthreads();
  if (tid == 0) {
    int acc = 0;
#pragma unroll
    for (int i = 0; i < 9; ++i) { pre[i] = acc; acc += rl[i]; }
    pre[9] = acc;
  }
  __syncthreads();
  int total = pre[9];
  int hs = st[c], he = st[c+1];
  int nq = he - hs;
  if (nq == 0) return;                           // uniform across block
  bool bad = (total > CAPC) || (total < KK);
  if (!bad) {
    for (int i = tid; i < total; i += 256) {
      int row = 0;
#pragma unroll
      for (int rr = 1; rr < 9; ++rr) row += (i >= pre[rr]);
      int gp = rs[row] + (i - pre[row]);
      big[i] = csort[gp];
    }
  }
  __syncthreads();
  int hoff = pre[4] + (hs - rs[4]);              // home cell offset inside big[]
  // 3x3x3 region boundary edges
  float blo[3], bhi[3]; bool blok[3], bhik[3];
  int cc3[3] = {cxi, cyi, czi};
#pragma unroll
  for (int a = 0; a < 3; ++a) {
    const float* e = edges + (b*3 + a)*(G+1);
    blok[a] = cc3[a] > 0;     blo[a] = blok[a] ? e[cc3[a]-1] : 0.f;
    bhik[a] = cc3[a] < G-1;   bhi[a] = bhik[a] ? e[cc3[a]+2] : 0.f;
  }
  for (int q0 = 0; q0 < nq; q0 += 4) {
    int qi = q0 + w;
    if (qi >= nq) continue;                      // uniform per wave
    int t = hs + qi;
    if (bad) {
      if (lane == 0) { int pos = atomicAdd(failcnt, 1); faillist[pos] = t | FB_BAD; }
      continue;
    }
    float4 qv = big[hoff + qi];
    float qx = qv.x, qy = qv.y, qz = qv.z, qsq = qv.w;
    // distances into registers (8 static slots), wave-uniform slot skip
    float dreg[8];
    float mnl = 1e30f;
#pragma unroll
    for (int s = 0; s < 8; ++s) {
      float d = 1e30f;
      if (s*64 < total) {                        // wave-uniform: skip empty slots
        int i = s*64 + lane;
        if (i < total) {
          float4 p = big[i];
          d = qsq + p.w - 2.f*(qx*p.x + qy*p.y + qz*p.z);  // == reference formula
        }
      }
      dreg[s] = d;
      mnl = fminf(mnl, d);
    }
    // Tp = 16th smallest of 32 PAIR minima (pairs = disjoint lanes => 16 distinct
    // candidates <= Tp => d16_true <= Tp). 1 shfl + 15-stage 32-wide bitonic.
    float v = fminf(mnl, __shfl_xor(mnl, 32, 64));
    int l5 = lane & 31;
#pragma unroll
    for (int k2 = 2; k2 <= 32; k2 <<= 1) {
#pragma unroll
      for (int j = k2 >> 1; j > 0; j >>= 1) {
        float o = __shfl_xor(v, j, 64);
        bool keepmin = (((l5 & j) == 0) == ((l5 & k2) == 0));
        v = keepmin ? fminf(v, o) : fmaxf(v, o);
      }
    }
    float Tp = __shfl(v, 15, 64);
    // compact d <= Tp into sbd/sbi (wave-uniform slot skip)
    int cnt = 0;
#pragma unroll
    for (int s = 0; s < 8; ++s) {
      if (s*64 < total) {                        // uniform: whole wave enters or skips
        bool take = dreg[s] <= Tp;
        unsigned long long bal = __ballot(take);
        int pos = cnt + __popcll(bal & ((1ull << lane) - 1ull));
        if (take && pos < 64) { sbd[pos] = dreg[s]; sbi[pos] = s*64 + lane; }
        cnt += __popcll(bal);
      }
    }
    if (cnt > 64) {                              // ~never: exact BAD fallback
      if (lane == 0) { int pos = atomicAdd(failcnt, 1); faillist[pos] = t | FB_BAD; }
      continue;
    }
    float dv = (lane < cnt) ? sbd[lane] : 1e30f;
    int   iv = (lane < cnt) ? sbi[lane] : 0x7fffffff;
    if (cnt <= 32) {                             // 32-wide network (15 stages, ~always)
#pragma unroll
      for (int kk = 2; kk <= 32; kk <<= 1) {
#pragma unroll
        for (int j = kk >> 1; j > 0; j >>= 1) {
          float od = __shfl_xor(dv, j, 64);
          int   oi = __shfl_xor(iv, j, 64);
          bool keepmin = (((lane & j) == 0) == ((lane & kk) == 0));
          bool less = (od < dv) || (od == dv && oi < iv);
          bool take2 = keepmin ? less : !less;
          dv = take2 ? od : dv;
          iv = take2 ? oi : iv;
        }
      }
    } else {                                     // full 64-wide (21 stages)
#pragma unroll
      for (int kk = 2; kk <= 64; kk <<= 1) {
#pragma unroll
        for (int j = kk >> 1; j > 0; j >>= 1) {
          float od = __shfl_xor(dv, j, 64);
          int   oi = __shfl_xor(iv, j, 64);
          bool keepmin = (((lane & j) == 0) == ((lane & kk) == 0));
          bool less = (od < dv) || (od == dv && oi < iv);
          bool take2 = keepmin ? less : !less;
          dv = take2 ? od : dv;
          iv = take2 ? oi : iv;
        }
      }
    }
    float d16v = __shfl(dv, 15, 64);
    int resid = iv;                              // lane r holds r-th NN cand index
    float m = 1e30f;
    if (blok[0]) m = fminf(m, qx - blo[0]);
    if (bhik[0]) m = fminf(m, bhi[0] - qx);
    if (blok[1]) m = fminf(m, qy - blo[1]);
    if (bhik[1]) m = fminf(m, bhi[1] - qy);
    if (blok[2]) m = fminf(m, qz - blo[2]);
    if (bhik[2]) m = fminf(m, bhi[2] - qz);
    bool ok = (m > 0.f) && (m*m > d16v + SLOP);
    if (ok) {
      int qn = sortid[t];
      size_t row = ((size_t)(b*NPTS + qn))*KK;
      if (lane < KK) {
        int rowi = 0;                            // reconstruct csort position
#pragma unroll
        for (int rr = 1; rr < 9; ++rr) rowi += (resid >= pre[rr]);
        int gp = rs[rowi] + (resid - pre[rowi]);
        oidx[row + lane] = sortid[gp];
      }
    } else {
      if (lane == 0) {
        int k2 = nfl[w];
        if (k2 < 16) { flq[w][k2] = t; flT[w][k2] = d16v; nfl[w] = k2 + 1; }
        else { int pos = atomicAdd(failcnt, 1); faillist[pos] = t | FB_BAD; }
      }
    }
  }
  __syncthreads();
  if (bad) return;
  if (nfl[0] + nfl[1] + nfl[2] + nfl[3] == 0) return;

  // ---- phase 2: load 5x5x5 region once, resolve failed queries in LDS ----
  if (tid < 25) {
    int dz = tid/5 - 2, dy = tid%5 - 2;
    int z = czi + dz, y = cyi + dy;
    if (z < 0 || z > G-1 || y < 0 || y > G-1) { rs2[tid] = 0; rl2[tid] = 0; }
    else {
      int xa = max(cxi-2, 0), xb = min(cxi+2, G-1);
      int c0 = (z*G + y)*G + xa;
      int s0 = st[c0], e0 = st[c0 + (xb - xa) + 1];
      rs2[tid] = s0; rl2[tid] = e0 - s0;
    }
  }
  __syncthreads();
  if (tid == 0) {
    int acc = 0;
#pragma unroll
    for (int i = 0; i < 25; ++i) { pre2[i] = acc; acc += rl2[i]; }
    pre2[25] = acc;
  }
  __syncthreads();
  int total2 = pre2[25];
  if (total2 > CAP2) {                           // ~never: dump fails as BAD
    if (lane == 0) {
      for (int k2 = 0; k2 < nfl[w]; ++k2) {
        int pos = atomicAdd(failcnt, 1); faillist[pos] = flq[w][k2] | FB_BAD;
      }
    }
    return;
  }
  for (int i = tid; i < total2; i += 256) {
    int rowi = 0;
#pragma unroll
    for (int rr = 1; rr < 25; ++rr) rowi += (i >= pre2[rr]);
    int gp = rs2[rowi] + (i - pre2[rowi]);
    big[i] = csort[gp];
  }
  __syncthreads();
  // 5x5x5 region boundary edges
  float blo2[3], bhi2[3]; bool blok2[3], bhik2[3];
#pragma unroll
  for (int a = 0; a < 3; ++a) {
    const float* e = edges + (b*3 + a)*(G+1);
    blok2[a] = cc3[a] > 1;     blo2[a] = blok2[a] ? e[cc3[a]-2] : 0.f;
    bhik2[a] = cc3[a] < G-2;   bhi2[a] = bhik2[a] ? e[cc3[a]+3] : 0.f;
  }
  for (int k2 = 0; k2 < nfl[w]; ++k2) {          // wave-serial, no barriers
    int t = flq[w][k2];
    float T0 = flT[w][k2] + TEPS;                // T0 >= true d16 (3x3x3 superset bound)
    float4 qv = csort[t];
    float qx = qv.x, qy = qv.y, qz = qv.z, qsq = qv.w;
    int cnt = 0;
    for (int base2 = 0; base2 < total2; base2 += 64) {
      int i = base2 + lane;
      bool valid = i < total2;
      float d = 1e30f;
      if (valid) {
        float4 p = big[i];
        d = qsq + p.w - 2.f*(qx*p.x + qy*p.y + qz*p.z);
      }
      bool take = valid && (d <= T0);
      unsigned long long bal = __ballot(take);
      int pos = cnt + __popcll(bal & ((1ull << lane) - 1ull));
      if (take && pos < 64) { sbd[pos] = d; sbi[pos] = i; }
      cnt += __popcll(bal);
    }
    if (cnt > 64) {                              // ~never
      if (lane == 0) { int pos = atomicAdd(failcnt, 1); faillist[pos] = t | FB_BAD; }
      continue;
    }
    float dv = (lane < cnt) ? sbd[lane] : 1e30f;
    int   iv = (lane < cnt) ? sbi[lane] : 0x7fffffff;
#pragma unroll
    for (int kk = 2; kk <= 64; kk <<= 1) {       // bitonic sort (d, idx)
#pragma unroll
      for (int j = kk >> 1; j > 0; j >>= 1) {
        float od = __shfl_xor(dv, j, 64);
        int   oi = __shfl_xor(iv, j, 64);
        bool keepmin = (((lane & j) == 0) == ((lane & kk) == 0));
        bool less = (od < dv) || (od == dv && oi < iv);
        bool take2 = keepmin ? less : !less;
        dv = take2 ? od : dv;
        iv = take2 ? oi : iv;
      }
    }
    float d16b = __shfl(dv, 15, 64);
    float m = 1e30f;
    if (blok2[0]) m = fminf(m, qx - blo2[0]);
    if (bhik2[0]) m = fminf(m, bhi2[0] - qx);
    if (blok2[1]) m = fminf(m, qy - blo2[1]);
    if (bhik2[1]) m = fminf(m, bhi2[1] - qy);
    if (blok2[2]) m = fminf(m, qz - blo2[2]);
    if (bhik2[2]) m = fminf(m, bhi2[2] - qz);
    bool ok = (m > 0.f) && (m*m > d16b + SLOP);
    int qn = sortid[t];
    size_t row = ((size_t)(b*NPTS + qn))*KK;
    if (lane < KK) {
      int rowi = 0;                              // reconstruct csort position
#pragma unroll
      for (int rr = 1; rr < 25; ++rr) rowi += (iv >= pre2[rr]);
      int gp = rs2[rowi] + (iv - pre2[rowi]);
      oidx[row + lane] = ok ? sortid[gp] : gp;   // result, or seed positions
    }
    if (!ok && lane == 0) { int pos = atomicAdd(failcnt, 1); faillist[pos] = t; }
  }
}

// ---------------- residual fallback: ONE BLOCK PER QUERY (256-thread strided scan) ----
__launch_bounds__(256)
__global__ void k_knn_fb(const float4* __restrict__ csort, const int* __restrict__ sortid,
                         const int* __restrict__ starts, const float* __restrict__ edges,
                         const int* __restrict__ faillist, const int* __restrict__ failcnt,
                         int* __restrict__ oidx) {
  __shared__ float sT;
  __shared__ int   slo, shi;
  __shared__ float md[64];
  __shared__ int   mp[64];
  int tid = threadIdx.x, lane = tid & 63, w = tid >> 6;
  int nf = failcnt[0];
  for (int f = blockIdx.x; f < nf; f += gridDim.x) {
    int fv = faillist[f];                        // uniform per block
    bool seeded = (fv & FB_BAD) == 0;
    int t = fv & (FB_BAD - 1);
    int b = t >> 15;
    const int* st = starts + b*G3;
    float4 qv = csort[t];
    const float qx = qv.x, qy = qv.y, qz = qv.z, qsq = qv.w;
    int qn = sortid[t];
    size_t row = ((size_t)(b*NPTS + qn))*KK;
    // wave 0 computes T + contiguous superset range, broadcasts via LDS
    if (w == 0) {
      if (seeded) {
        const float* ex = edges + (b*3+0)*(G+1);
        const float* ey = edges + (b*3+1)*(G+1);
        const float* ez = edges + (b*3+2)*(G+1);
        float sd = -1e30f;
        if (lane < KK) {
          int pos = oidx[row + lane];
          float4 p = csort[pos];
          sd = qsq + p.w - 2.f*(qx*p.x + qy*p.y + qz*p.z);
        }
        float T = sd;
#pragma unroll
        for (int m = 32; m > 0; m >>= 1) T = fmaxf(T, __shfl_xor(T, m, 64));
        T += TEPS;                               // T >= true d16 (5x5x5 superset)
        float R = sqrtf(T)*1.0001f + 1e-12f;
        bool tk = (lane < G-1) && (ex[lane+1] < qx - R);
        int xl = __popcll(__ballot(tk));
        tk = (lane >= 1 && lane <= G-1) && (ex[lane] > qx + R);
        int xh = (G-1) - __popcll(__ballot(tk));
        tk = (lane < G-1) && (ey[lane+1] < qy - R);
        int yl = __popcll(__ballot(tk));
        tk = (lane >= 1 && lane <= G-1) && (ey[lane] > qy + R);
        int yh = (G-1) - __popcll(__ballot(tk));
        tk = (lane < G-1) && (ez[lane+1] < qz - R);
        int zl = __popcll(__ballot(tk));
        tk = (lane >= 1 && lane <= G-1) && (ez[lane] > qz + R);
        int zh = (G-1) - __popcll(__ballot(tk));
        if (lane == 0) {
          sT = T;
          slo = st[(zl*G + yl)*G + xl];
          shi = st[(zh*G + yh)*G + xh + 1];
        }
      } else {
        // ~never: full-batch scan, no threshold (per-thread lists are exact)
        if (lane == 0) { sT = 1e30f; slo = b*NPTS; shi = b*NPTS + NPTS; }
      }
    }
    __syncthreads();
    float T = sT;
    int lo_pos = slo, hi_pos = shi;
    // per-thread threshold top-16 insert over 256-strided range
    float dl[KK]; int il[KK];
#pragma unroll
    for (int i = 0; i < KK; ++i) { dl[i] = 1e30f; il[i] = 0x7fffffff; }
    for (int i = lo_pos + tid; i < hi_pos; i += 256) {
      float4 p = csort[i];
      float d = qsq + p.w - 2.f*(qx*p.x + qy*p.y + qz*p.z);
      if (d <= T && d < dl[KK-1]) {              // rare insert
        float cd = d; int ci = i;
#pragma unroll
        for (int i2 = 0; i2 < KK; ++i2) {
          bool sw = cd < dl[i2];
          float td = dl[i2]; int ti = il[i2];
          dl[i2] = sw ? cd : td; il[i2] = sw ? ci : ti;
          cd = sw ? td : cd;    ci = sw ? ti : ci;
        }
      }
    }
    // per-wave exact top-16: 16 argmin rounds by (d, csort pos); winner pops
    int res = 0x7fffffff; float rd = 1e30f;
#pragma unroll
    for (int r = 0; r < KK; ++r) {
      float v = dl[0]; int pi = il[0]; int l = lane;
#pragma unroll
      for (int m = 1; m < 64; m <<= 1) {
        float ov = __shfl_xor(v, m, 64);
        int   op = __shfl_xor(pi, m, 64);
        int   ol = __shfl_xor(l, m, 64);
        bool take = (ov < v) || (ov == v && op < pi);
        v = take ? ov : v; pi = take ? op : pi; l = take ? ol : l;
      }
      if (lane == r) { res = pi; rd = v; }
      bool win = (lane == l);
#pragma unroll
      for (int i = 0; i < KK-1; ++i) {
        dl[i] = win ? dl[i+1] : dl[i];
        il[i] = win ? il[i+1] : il[i];
      }
      dl[KK-1] = win ? 1e30f : dl[KK-1];
      il[KK-1] = win ? 0x7fffffff : il[KK-1];
    }
    if (lane < KK) { md[w*KK + lane] = rd; mp[w*KK + lane] = res; }
    __syncthreads();
    // wave 0: 64-wide bitonic merge of 4x16 wave winners by (d, pos)
    if (w == 0) {
      float dv = md[lane]; int iv = mp[lane];
#pragma unroll
      for (int kk = 2; kk <= 64; kk <<= 1) {
#pragma unroll
        for (int j = kk >> 1; j > 0; j >>= 1) {
          float od = __shfl_xor(dv, j, 64);
          int   oi = __shfl_xor(iv, j, 64);
          bool keepmin = (((lane & j) == 0) == ((lane & kk) == 0));
          bool less = (od < dv) || (od == dv && oi < iv);
          bool take2 = keepmin ? less : !less;
          dv = take2 ? od : dv;
          iv = take2 ? oi : iv;
        }
      }
      if (lane < KK) oidx[row + lane] = sortid[iv];
    }
    __syncthreads();                             // md/mp/sT reuse safety for next f
  }
}

// ---------------- FUSED: mlp1 (blocks 0..63, 4 pts/thread) + lsestats (blocks 64..1087, 4 el/thread) ----
__global__ void k_stats(const float* __restrict__ features,
                        const float* __restrict__ W1, const float* __restrict__ b1,
                        const float* __restrict__ Wsc, const float* __restrict__ bsc,
                        float* __restrict__ x1, float* __restrict__ ppa,
                        const float* __restrict__ coords, const int* __restrict__ idx,
                        const float* __restrict__ Wl1, const float* __restrict__ bl1,
                        const float* __restrict__ Wl2, const float* __restrict__ bl2,
                        float* __restrict__ ppb) {
  int tid = threadIdx.x;
  if (blockIdx.x < 64) {
    // ---- mlp1 (leaky 0.2) + shortcut BN partial sums; 4 points/thread ----
    __shared__ float sW1[128], sb1[16], sWsc[512], sbsc[64];
    __shared__ float part[128];
    if (tid < 128) { sW1[tid] = W1[tid]; part[tid] = 0.f; }
    if (tid < 16)  sb1[tid] = b1[tid];
    if (tid < 64)  sbsc[tid] = bsc[tid];
    for (int i = tid; i < 512; i += 256) sWsc[i] = Wsc[i];
    __syncthreads();
    int q0 = blockIdx.x*1024;
    float f[4][8];
#pragma unroll
    for (int p = 0; p < 4; ++p) {
      int q = q0 + p*256 + tid;
      int b = q >> 15, n = q & (NPTS-1);
#pragma unroll
      for (int c = 0; c < 8; ++c) f[p][c] = features[((size_t)b*8 + c)*NPTS + n];
#pragma unroll
      for (int co = 0; co < 16; ++co) {
        float a = sb1[co];
#pragma unroll
        for (int c = 0; c < 8; ++c) a += f[p][c]*sW1[co*8+c];
        x1[(size_t)q*16 + co] = a > 0.f ? a : 0.2f*a;
      }
    }
    int lane = tid & 63;
#pragma unroll
    for (int co = 0; co < 64; ++co) {
      float s = 0.f, ss = 0.f;
#pragma unroll
      for (int p = 0; p < 4; ++p) {
        float a = sbsc[co];
#pragma unroll
        for (int c = 0; c < 8; ++c) a += f[p][c]*sWsc[co*8+c];
        s += a; ss += a*a;
      }
      s = wred64(s); ss = wred64(ss);
      if (lane == 0) { atomicAdd(&part[co], s); atomicAdd(&part[64+co], ss); }
    }
    __syncthreads();
    if (tid < 128) ppa[(size_t)blockIdx.x*128 + tid] = part[tid];
  } else {
    // ---- BN partial sums for BOTH LSE geometric encodings; 4 elements/thread ----
    __shared__ float sW1[160], sb1[16], sW2[160], sb2[16];
    __shared__ float red[4][64];
    int blk = blockIdx.x - 64;          // 0..1023
    for (int i = tid; i < 160; i += 256) { sW1[i] = Wl1[i]; sW2[i] = Wl2[i]; }
    if (tid < 16) { sb1[tid] = bl1[tid]; sb2[tid] = bl2[tid]; }
    __syncthreads();
    float cat[4][10];
#pragma unroll
    for (int p = 0; p < 4; ++p) {
      int t = blk*1024 + p*256 + tid;   // (b,n,k) flat
      int q = t >> 4;
      int b = q >> 15, n = q & (NPTS-1);
      const float* cb = coords + (size_t)b*(NPTS*3);
      int j = idx[t];
      float cx = cb[n*3], cy = cb[n*3+1], cz = cb[n*3+2];
      float px = cb[j*3], py = cb[j*3+1], pz = cb[j*3+2];
      cat[p][0]=cx; cat[p][1]=cy; cat[p][2]=cz;
      cat[p][3]=px; cat[p][4]=py; cat[p][5]=pz;
      cat[p][6]=cx-px; cat[p][7]=cy-py; cat[p][8]=cz-pz; cat[p][9]=1.f;
    }
    int wave = tid >> 6, lane = tid & 63;
#pragma unroll
    for (int co = 0; co < 16; ++co) {
      float s1 = 0.f, q1 = 0.f, s2 = 0.f, q2 = 0.f;
#pragma unroll
      for (int p = 0; p < 4; ++p) {
        float a1 = sb1[co], a2 = sb2[co];
#pragma unroll
        for (int d0 = 0; d0 < 10; ++d0) { a1 += cat[p][d0]*sW1[co*10+d0]; a2 += cat[p][d0]*sW2[co*10+d0]; }
        s1 += a1; q1 += a1*a1; s2 += a2; q2 += a2*a2;
      }
      s1 = wred64(s1); q1 = wred64(q1);
      s2 = wred64(s2); q2 = wred64(q2);
      if (lane == 0) { red[wave][co]=s1; red[wave][16+co]=q1; red[wave][32+co]=s2; red[wave][48+co]=q2; }
    }
    __syncthreads();
    if (tid < 64) {
      float v = red[0][tid] + red[1][tid] + red[2][tid] + red[3][tid];
      ppb[(size_t)blk*64 + tid] = v;    // layout matches stats[S_L1..S_L2+32)
    }
  }
}

// ---------------- LSE1 + attentive pooling 1 (BN-L1 inline; softmax w/o max-sub) ----------------
__launch_bounds__(256)
__global__ void k_att1(const float* __restrict__ coords, const int* __restrict__ idx,
                       const float* __restrict__ x1ws,
                       const float* __restrict__ Wl1, const float* __restrict__ bl1,
                       const float* __restrict__ Ws1, const float* __restrict__ Wp1,
                       const float* __restrict__ bp1, const float* __restrict__ stats,
                       const float* __restrict__ gl1, const float* __restrict__ bl1b,
                       float* __restrict__ t2, float* __restrict__ ppart) {
  __shared__ float saL[16], scL[16];
  __shared__ float sWl[160], sbl[16];
  __shared__ float sWs[1024];
  __shared__ float sWpT[512], sbp[16];
  __shared__ float lsum[16], lsq[16];
  int tid = threadIdx.x;
  if (tid < 16) {
    float m = stats[S_L1 + tid]*INVQK;
    float v = stats[S_L1 + 16 + tid]*INVQK - m*m;
    float a = gl1[tid]*rsqrtf(v + EPS);
    saL[tid] = a; scL[tid] = bl1b[tid] - m*a;
  }
  __syncthreads();
  for (int i = tid; i < 160; i += 256) { int c = i/10; sWl[i] = Wl1[i]*saL[c]; }
  if (tid < 16) sbl[tid] = bl1[tid]*saL[tid] + scL[tid];
  for (int i = tid; i < 1024; i += 256) sWs[i] = Ws1[i];
  for (int i = tid; i < 512; i += 256) { int co = i >> 4, cp = i & 15; sWpT[i] = Wp1[cp*32 + co]; }
  if (tid < 16) { sbp[tid] = bp1[tid]; lsum[tid] = 0.f; lsq[tid] = 0.f; }
  __syncthreads();
  int gp = blockIdx.x*16 + (tid >> 4);
  int k  = tid & 15;
  int b = gp >> 15, n = gp & (NPTS-1);
  const float* cb = coords + (size_t)b*(NPTS*3);
  int j = idx[(size_t)gp*KK + k];
  float cx = cb[n*3], cy = cb[n*3+1], cz = cb[n*3+2];
  float px = cb[j*3], py = cb[j*3+1], pz = cb[j*3+2];
  float cat[10] = {cx,cy,cz,px,py,pz,cx-px,cy-py,cz-pz,1.f};
  float x[32];
#pragma unroll
  for (int co = 0; co < 16; ++co) {
    float a = sbl[co];
#pragma unroll
    for (int d0 = 0; d0 < 10; ++d0) a += cat[d0]*sWl[co*10+d0];
    x[co] = a > 0.f ? a : 0.f;
  }
  {
    const float4* xp = (const float4*)(x1ws + (size_t)gp*16);
    float4 u0 = xp[0], u1 = xp[1], u2 = xp[2], u3 = xp[3];
    x[16]=u0.x; x[17]=u0.y; x[18]=u0.z; x[19]=u0.w;
    x[20]=u1.x; x[21]=u1.y; x[22]=u1.z; x[23]=u1.w;
    x[24]=u2.x; x[25]=u2.y; x[26]=u2.z; x[27]=u2.w;
    x[28]=u3.x; x[29]=u3.y; x[30]=u3.z; x[31]=u3.w;
  }
  float tacc = sbp[k];
#pragma unroll
  for (int co = 0; co < 32; ++co) {
    float s = 0.f;
#pragma unroll
    for (int ci = 0; ci < 32; ++ci) s += x[ci]*sWs[co*32+ci];
    float e = __expf(s);                 // scores bounded: softmax w/o max-sub (identical ratio)
    float se = e;
#pragma unroll
    for (int msk = 8; msk > 0; msk >>= 1) se += __shfl_xor(se, msk, 16);
    float w = e/se;
    float fv = w*x[co];
#pragma unroll
    for (int msk = 8; msk > 0; msk >>= 1) fv += __shfl_xor(fv, msk, 16);
    tacc += fv*sWpT[co*16+k];
  }
  t2[(size_t)gp*16 + k] = tacc;
  atomicAdd(&lsum[k], tacc);
  atomicAdd(&lsq[k], tacc*tacc);
  __syncthreads();
  if (tid < 16) {
    ppart[(size_t)blockIdx.x*32 + tid]      = lsum[tid];
    ppart[(size_t)blockIdx.x*32 + 16 + tid] = lsq[tid];
  }
}

// ---------------- LSE2 + attentive pooling 2 (BN-L2 + BN-P1 inline; softmax w/o max-sub) ----
__launch_bounds__(256)
__global__ void k_att2(const float* __restrict__ coords, const int* __restrict__ idx,
                       const float* __restrict__ t2ws,
                       const float* __restrict__ Wl2, const float* __restrict__ bl2,
                       const float* __restrict__ Ws2, const float* __restrict__ Wp2,
                       const float* __restrict__ bp2, const float* __restrict__ stats,
                       const float* __restrict__ gl2, const float* __restrict__ bl2b,
                       const float* __restrict__ gp1, const float* __restrict__ bp1b,
                       float* __restrict__ t4, float* __restrict__ ppart) {
  __shared__ float saL[16], scL[16];
  __shared__ float sWl[160], sbl[16];
  __shared__ float sWs[1024];
  __shared__ float sWpT[1024], sbp[32];
  __shared__ float sa1[16], sc1[16];
  __shared__ float lsum[32], lsq[32];
  int tid = threadIdx.x;
  if (tid < 16) {
    float m = stats[S_L2 + tid]*INVQK;
    float v = stats[S_L2 + 16 + tid]*INVQK - m*m;
    float a = gl2[tid]*rsqrtf(v + EPS);
    saL[tid] = a; scL[tid] = bl2b[tid] - m*a;
    float m1 = stats[S_P1 + tid]*INVN;
    float v1 = stats[S_P1 + 16 + tid]*INVN - m1*m1;
    float a1 = gp1[tid]*rsqrtf(v1 + EPS);
    sa1[tid] = a1; sc1[tid] = bp1b[tid] - m1*a1;
  }
  __syncthreads();
  for (int i = tid; i < 160; i += 256) { int c = i/10; sWl[i] = Wl2[i]*saL[c]; }
  if (tid < 16) sbl[tid] = bl2[tid]*saL[tid] + scL[tid];
  for (int i = tid; i < 1024; i += 256) {
    sWs[i] = Ws2[i];
    int co = i >> 5, cp = i & 31; sWpT[i] = Wp2[cp*32 + co];
  }
  if (tid < 32) { sbp[tid] = bp2[tid]; lsum[tid]=0.f; lsq[tid]=0.f; }
  __syncthreads();
  int gp = blockIdx.x*16 + (tid >> 4);
  int k  = tid & 15;
  int b = gp >> 15, n = gp & (NPTS-1);
  const float* cb = coords + (size_t)b*(NPTS*3);
  int j = idx[(size_t)gp*KK + k];
  float cx = cb[n*3], cy = cb[n*3+1], cz = cb[n*3+2];
  float px = cb[j*3], py = cb[j*3+1], pz = cb[j*3+2];
  float cat[10] = {cx,cy,cz,px,py,pz,cx-px,cy-py,cz-pz,1.f};
  float x[32];
#pragma unroll
  for (int co = 0; co < 16; ++co) {
    float a = sbl[co];
#pragma unroll
    for (int d0 = 0; d0 < 10; ++d0) a += cat[d0]*sWl[co*10+d0];
    x[co] = a > 0.f ? a : 0.f;
  }
  {
    const float4* xp = (const float4*)(t2ws + (size_t)gp*16);
    float4 u0 = xp[0], u1 = xp[1], u2 = xp[2], u3 = xp[3];
    float xv[16] = {u0.x,u0.y,u0.z,u0.w, u1.x,u1.y,u1.z,u1.w,
                    u2.x,u2.y,u2.z,u2.w, u3.x,u3.y,u3.z,u3.w};
#pragma unroll
    for (int c = 0; c < 16; ++c) {
      float v = xv[c]*sa1[c] + sc1[c];
      x[16+c] = v > 0.f ? v : 0.f;
    }
  }
  float tacc0 = sbp[k], tacc1 = sbp[k+16];
#pragma unroll
  for (int co = 0; co < 32; ++co) {
    float s = 0.f;
#pragma unroll
    for (int ci = 0; ci < 32; ++ci) s += x[ci]*sWs[co*32+ci];
    float e = __expf(s);                 // scores bounded: softmax w/o max-sub (identical ratio)
    float se = e;
#pragma unroll
    for (int msk = 8; msk > 0; msk >>= 1) se += __shfl_xor(se, msk, 16);
    float w = e/se;
    float fv = w*x[co];
#pragma unroll
    for (int msk = 8; msk > 0; msk >>= 1) fv += __shfl_xor(fv, msk, 16);
    tacc0 += fv*sWpT[co*32+k];
    tacc1 += fv*sWpT[co*32+k+16];
  }
  t4[(size_t)gp*32 + k]      = tacc0;
  t4[(size_t)gp*32 + k + 16] = tacc1;
  atomicAdd(&lsum[k], tacc0);      atomicAdd(&lsq[k], tacc0*tacc0);
  atomicAdd(&lsum[k+16], tacc1);   atomicAdd(&lsq[k+16], tacc1*tacc1);
  __syncthreads();
  if (tid < 32) {
    ppart[(size_t)blockIdx.x*64 + tid]      = lsum[tid];
    ppart[(size_t)blockIdx.x*64 + 32 + tid] = lsq[tid];
  }
}

// ---------------- final: mlp2 + BN'd shortcut + leaky 0.01 (BN-SC + BN-P2 inline) ----------------
__global__ void k_final(const float* __restrict__ t4ws, const float* __restrict__ features,
                        const float* __restrict__ W2, const float* __restrict__ b2,
                        const float* __restrict__ Wsc, const float* __restrict__ bsc,
                        const float* __restrict__ stats,
                        const float* __restrict__ gsc, const float* __restrict__ bscb,
                        const float* __restrict__ gp2, const float* __restrict__ bp2b,
                        float* __restrict__ out) {
  __shared__ float saS[64], scS[64];
  __shared__ float sW2[2048], sb2[64], sWscF[512], sbscF[64], sa[32], scc[32];
  int tid = threadIdx.x;
  if (tid < 64) {
    float m = stats[S_SC + tid]*INVN;
    float v = stats[S_SC + 64 + tid]*INVN - m*m;
    float a = gsc[tid]*rsqrtf(v + EPS);
    saS[tid] = a; scS[tid] = bscb[tid] - m*a;
  }
  if (tid < 32) {
    float m = stats[S_P2 + tid]*INVN;
    float v = stats[S_P2 + 32 + tid]*INVN - m*m;
    float a = gp2[tid]*rsqrtf(v + EPS);
    sa[tid] = a; scc[tid] = bp2b[tid] - m*a;
  }
  __syncthreads();
  for (int i = tid; i < 2048; i += 256) sW2[i] = W2[i];
  if (tid < 64) sb2[tid] = b2[tid];
  for (int i = tid; i < 512; i += 256) { int c2 = i >> 3; sWscF[i] = Wsc[i]*saS[c2]; }
  if (tid < 64) sbscF[tid] = bsc[tid]*saS[tid] + scS[tid];
  __syncthreads();
  int q = blockIdx.x*256 + tid;
  int b = q >> 15, n = q & (NPTS-1);
  float x3[32];
  const float4* tp = (const float4*)(t4ws + (size_t)q*32);
#pragma unroll
  for (int i = 0; i < 8; ++i) {
    float4 u = tp[i];
    float v0 = u.x*sa[4*i+0] + scc[4*i+0];
    float v1 = u.y*sa[4*i+1] + scc[4*i+1];
    float v2 = u.z*sa[4*i+2] + scc[4*i+2];
    float v3 = u.w*sa[4*i+3] + scc[4*i+3];
    x3[4*i+0] = v0 > 0.f ? v0 : 0.f;
    x3[4*i+1] = v1 > 0.f ? v1 : 0.f;
    x3[4*i+2] = v2 > 0.f ? v2 : 0.f;
    x3[4*i+3] = v3 > 0.f ? v3 : 0.f;
  }
  float f[8];
#pragma unroll
  for (int c = 0; c < 8; ++c) f[c] = features[((size_t)b*8+c)*NPTS + n];
  for (int c2 = 0; c2 < 64; ++c2) {
    float acc = sb2[c2];
#pragma unroll
    for (int co = 0; co < 32; ++co) acc += x3[co]*sW2[c2*32+co];
    float sv = sbscF[c2];
#pragma unroll
    for (int c = 0; c < 8; ++c) sv += f[c]*sWscF[c2*8+c];
    float o = acc + sv;
    out[((size_t)b*64 + c2)*NPTS + n] = o > 0.f ? o : 0.01f*o;
  }
}

extern "C" void kernel_launch(void* const* d_in, const int* in_sizes, int n_in,
                              void* d_out, int out_size, void* d_ws, size_t ws_size,
                              hipStream_t stream) {
  const float* coords   = (const float*)d_in[0];
  const float* features = (const float*)d_in[1];
  const float* W1  = (const float*)d_in[2];
  const float* b1  = (const float*)d_in[3];
  const float* Wl1 = (const float*)d_in[4];
  const float* bl1 = (const float*)d_in[5];
  const float* gl1 = (const float*)d_in[6];
  const float* bl1b= (const float*)d_in[7];
  const float* Ws1 = (const float*)d_in[8];
  const float* Wp1 = (const float*)d_in[9];
  const float* bp1 = (const float*)d_in[10];
  const float* gp1 = (const float*)d_in[11];
  const float* bp1b= (const float*)d_in[12];
  const float* Wl2 = (const float*)d_in[13];
  const float* bl2 = (const float*)d_in[14];
  const float* gl2 = (const float*)d_in[15];
  const float* bl2b= (const float*)d_in[16];
  const float* Ws2 = (const float*)d_in[17];
  const float* Wp2 = (const float*)d_in[18];
  const float* bp2 = (const float*)d_in[19];
  const float* gp2 = (const float*)d_in[20];
  const float* bp2b= (const float*)d_in[21];
  const float* W2  = (const float*)d_in[22];
  const float* b2  = (const float*)d_in[23];
  const float* Wsc = (const float*)d_in[24];
  const float* bsc = (const float*)d_in[25];
  const float* gsc = (const float*)d_in[26];
  const float* bscb= (const float*)d_in[27];

  float* wsF  = (float*)d_ws;
  int*   wsI  = (int*)d_ws;
  int*   idxp = wsI;
  float* x1p  = wsF + WS_X1;
  float* t2p  = wsF + WS_T2;
  float* t4p  = wsF + WS_T4;
  float* stat = wsF + WS_STAT;
  int*   gcnt = wsI + WS_GCNT;
  int*   gsta = wsI + WS_GSTART;
  int*   gcel = wsI + WS_CELLID;
  int*   sid  = wsI + WS_SORTID;
  float4* csrt = (float4*)(wsF + WS_CSORT);
  unsigned int* bbox = (unsigned int*)(wsI + WS_BBOX);
  int*   fcnt = wsI + WS_BBOX + 12;       // within bbox's 16-slot region
  int*   flist= wsI + WS_FAIL;            // aliases cellid (dead after scatter)
  int*   hist = wsI + WS_HIST;
  int*   strt = wsI + WS_STARTS;          // aliases hist (dead after k_edges)
  float* edge = wsF + WS_EDGE;
  float* prt  = wsF + WS_PART;            // lsestats/att partials alias csort (dead after k_knn_fb)
  float* prtA = wsF + WS_PARTA;           // mlp1 partials alias t2 (dead until k_att1)
  float* outp = (float*)d_out;

  hipLaunchKernelGGL(k_zero_all, dim3(48), dim3(256), 0, stream, stat, gcnt, hist, bbox, fcnt);
  hipLaunchKernelGGL(k_bbox,    dim3(NQ/256), dim3(256), 0, stream, coords, bbox);
  hipLaunchKernelGGL(k_hist,    dim3(NQ/256), dim3(256), 0, stream, coords, bbox, hist);
  hipLaunchKernelGGL(k_edges,   dim3(6), dim3(256), 0, stream, hist, bbox, edge);
  hipLaunchKernelGGL(k_bin,     dim3(NQ/256), dim3(256), 0, stream, coords, edge, gcel, gcnt);
  hipLaunchKernelGGL(k_alloc,   dim3(1), dim3(1024), 0, stream, gcnt, gsta, strt);
  hipLaunchKernelGGL(k_scatter, dim3(NQ/256), dim3(256), 0, stream, coords, gcel, gsta, csrt, sid);
  hipLaunchKernelGGL(k_cellknn, dim3(2*G3), dim3(256), 0, stream,
                     csrt, sid, strt, edge, idxp, flist, fcnt);
  hipLaunchKernelGGL(k_knn_fb,  dim3(2048), dim3(256), 0, stream,
                     csrt, sid, strt, edge, flist, fcnt, idxp);
  hipLaunchKernelGGL(k_stats, dim3(64 + (NQ*KK)/1024), dim3(256), 0, stream,
                     features, W1, b1, Wsc, bsc, x1p, prtA,
                     coords, idxp, Wl1, bl1, Wl2, bl2, prt);
  hipLaunchKernelGGL(k_pred2, dim3(192), dim3(256), 0, stream, prtA, prt, stat);
  hipLaunchKernelGGL(k_att1, dim3(NQ/16), dim3(256), 0, stream,
                     coords, idxp, x1p, Wl1, bl1, Ws1, Wp1, bp1, stat, gl1, bl1b, t2p, prt);
  hipLaunchKernelGGL(k_pred, dim3(32), dim3(256), 0, stream, prt, NQ/16, 32, stat, S_P1);
  hipLaunchKernelGGL(k_att2, dim3(NQ/16), dim3(256), 0, stream,
                     coords, idxp, t2p, Wl2, bl2, Ws2, Wp2, bp2, stat,
                     gl2, bl2b, gp1, bp1b, t4p, prt);
  hipLaunchKernelGGL(k_pred, dim3(64), dim3(256), 0, stream, prt, NQ/16, 64, stat, S_P2);
  hipLaunchKernelGGL(k_final, dim3(NQ/256), dim3(256), 0, stream,
                     t4p, features, W2, b2, Wsc, bsc, stat, gsc, bscb, gp2, bp2b, outp);
}